// Round 2
// baseline (1580.604 us; speedup 1.0000x reference)
//
#include <hip/hip_runtime.h>
#include <math.h>

#define NODES   100000
#define EDGES   1200000
#define GRAPHS  512
#define DIM     64
#define NT      10
#define KTOT    576   // 64 base + 64*8 spline features
#define NBLK    ((NODES + 255) / 256)   // 391 scan blocks

// ---------------------------------------------------------------------------
// Uniform cubic B-spline bases matching the reference Cox-de Boor recursion.
// ---------------------------------------------------------------------------
__device__ __forceinline__ void spline_bases(float x, float* b) {
    float tt  = fmaf(x, 2.5f, 5.5f);
    float fm  = floorf(tt);
    int   m   = (int)fm;
    float u   = tt - fm;
    float um1 = 1.f - u;
    float v3  = u * u * u * (1.f / 6.f);
    float v0  = um1 * um1 * um1 * (1.f / 6.f);
    float B2m1 = 0.5f * ((u + 1.f) * um1 + (2.f - u) * u);
    float v1  = ((u + 2.f) * um1 * um1 * 0.5f + (2.f - u) * B2m1) * (1.f / 3.f);
    float v2  = ((u + 1.f) * B2m1 + (3.f - u) * u * u * 0.5f) * (1.f / 3.f);
    bool inr  = (m >= 0) && (m <= 10);
#pragma unroll
    for (int j = 0; j < 8; ++j) {
        float bv = 0.f;
        bv = (j == m - 3) ? v0 : bv;
        bv = (j == m - 2) ? v1 : bv;
        bv = (j == m - 1) ? v2 : bv;
        bv = (j == m)     ? v3 : bv;
        b[j] = inr ? bv : 0.f;
    }
}

__device__ __forceinline__ float silu(float x) {
    return x / (1.f + __expf(-x));
}

// ---------------------------------------------------------------------------
// Combine base_w (transposed) and spline_w*scaler into Wc[k][o], k=0..575.
// ---------------------------------------------------------------------------
__global__ void prep_w(const float* __restrict__ bw, const float* __restrict__ sw,
                       const float* __restrict__ sc, float* __restrict__ Wc) {
    int idx = blockIdx.x * 256 + threadIdx.x;
    if (idx >= KTOT * DIM) return;
    int k = idx >> 6, o = idx & 63;
    float v;
    if (k < DIM) {
        v = bw[o * DIM + k];
    } else {
        int i = (k - DIM) >> 3, g = (k - DIM) & 7;
        v = sw[(o * DIM + i) * 8 + g] * sc[o * DIM + i];
    }
    Wc[idx] = v;
}

// ===========================================================================
// CSR build: histogram -> 2-level exclusive scan -> fill (built once per call,
// reused by both GIN layers).
// ===========================================================================
__global__ void hist_kernel(const int* __restrict__ ei, int* __restrict__ deg) {
    int e = blockIdx.x * 256 + threadIdx.x;
    if (e >= EDGES) return;
    atomicAdd(&deg[ei[EDGES + e]], 1);
}

__global__ void scan1(const int* __restrict__ deg, int* __restrict__ part,
                      int* __restrict__ incl) {
    __shared__ int s[256];
    int i = blockIdx.x * 256 + threadIdx.x;
    int v = (i < NODES) ? deg[i] : 0;
    s[threadIdx.x] = v;
    __syncthreads();
    for (int off = 1; off < 256; off <<= 1) {
        int t = (threadIdx.x >= off) ? s[threadIdx.x - off] : 0;
        __syncthreads();
        s[threadIdx.x] += t;
        __syncthreads();
    }
    if (i < NODES) incl[i] = s[threadIdx.x];
    if (threadIdx.x == 255) part[blockIdx.x] = s[255];
}

__global__ void scan2(int* __restrict__ part) {
    __shared__ int s[512];
    int i = threadIdx.x;
    s[i] = (i < NBLK) ? part[i] : 0;
    __syncthreads();
    for (int off = 1; off < 512; off <<= 1) {
        int t = (i >= off) ? s[i - off] : 0;
        __syncthreads();
        s[i] += t;
        __syncthreads();
    }
    if (i < NBLK) part[i] = s[i];
}

__global__ void scan3(const int* __restrict__ incl, const int* __restrict__ part,
                      const int* __restrict__ deg, int* __restrict__ rowptr,
                      int* __restrict__ cursor) {
    int i = blockIdx.x * 256 + threadIdx.x;
    if (i >= NODES) return;
    int add = (blockIdx.x > 0) ? part[blockIdx.x - 1] : 0;
    int v = incl[i] + add;          // inclusive prefix sum of deg
    rowptr[i + 1] = v;
    cursor[i] = v - deg[i];         // exclusive start = fill cursor
    if (i == 0) rowptr[0] = 0;
}

__global__ void fill_csr(const int* __restrict__ ei, int* __restrict__ cursor,
                         int* __restrict__ col) {
    int e = blockIdx.x * 256 + threadIdx.x;
    if (e >= EDGES) return;
    int src = ei[e];
    int dst = ei[EDGES + e];
    int p = atomicAdd(&cursor[dst], 1);
    col[p] = src;
}

// ---------------------------------------------------------------------------
// v[n] = x[n] + sum_{src in N(n)} x[src].  One wave per node, lane = feature:
// each edge is one fully-coalesced 256B row read (mostly L2/L3-resident).
// ---------------------------------------------------------------------------
__global__ __launch_bounds__(256) void gather_agg(const float* __restrict__ x,
                                                  const int* __restrict__ rowptr,
                                                  const int* __restrict__ col,
                                                  float* __restrict__ v) {
    int n = blockIdx.x * 4 + (threadIdx.x >> 6);
    int f = threadIdx.x & 63;
    if (n >= NODES) return;
    int beg = rowptr[n], end = rowptr[n + 1];
    float s = x[n * DIM + f];
    for (int p = beg; p < end; ++p) {
        int src = col[p];                 // wave-uniform -> scalar load
        s += x[src * DIM + f];
    }
    v[n * DIM + f] = s;
}

// ---------------------------------------------------------------------------
// h[n] = KAN(v[n]).  256 threads / 128 nodes per block; threads 0..127 compute
// outputs 0..31 for their node, threads 128..255 outputs 32..63 -> weight
// addresses stay wave-uniform (scalar loads) and acc halves to 32 VGPRs.
// LDS 33 KB -> 4 blocks/CU -> 16 waves/CU.
// ---------------------------------------------------------------------------
__global__ __launch_bounds__(256) void kan_layer(const float* __restrict__ vin,
                                                 const float* __restrict__ Wc,
                                                 float* __restrict__ out) {
    __shared__ float v[128][65];
    const int t = threadIdx.x;
    const int base = blockIdx.x * 128 * DIM;

    // coalesced load of this block's 128 node rows
#pragma unroll 4
    for (int j = 0; j < 32; ++j) {
        int idx = base + t + j * 256;
        if (idx < NODES * DIM) {
            int off = t + j * 256;
            v[off >> 6][off & 63] = vin[idx];
        }
    }
    __syncthreads();

    const int node  = t & 127;
    const int obase = (t >> 7) * 32;       // wave-uniform
    const int n = blockIdx.x * 128 + node;
    float acc[32];
#pragma unroll
    for (int o = 0; o < 32; ++o) acc[o] = 0.f;

    if (n < NODES) {
#pragma unroll 1
        for (int i = 0; i < DIM; ++i) {
            float xv = v[node][i];
            float s  = silu(xv);
            float b[8];
            spline_bases(xv, b);
            const float* wb = Wc + i * DIM + obase;
            const float* ws = Wc + (DIM + i * 8) * DIM + obase;
#pragma unroll
            for (int o = 0; o < 32; ++o) {
                float a = fmaf(s, wb[o], acc[o]);
                a = fmaf(b[0], ws[o], a);
                a = fmaf(b[1], ws[DIM + o], a);
                a = fmaf(b[2], ws[2 * DIM + o], a);
                a = fmaf(b[3], ws[3 * DIM + o], a);
                a = fmaf(b[4], ws[4 * DIM + o], a);
                a = fmaf(b[5], ws[5 * DIM + o], a);
                a = fmaf(b[6], ws[6 * DIM + o], a);
                a = fmaf(b[7], ws[7 * DIM + o], a);
                acc[o] = a;
            }
        }
    }
    __syncthreads();   // all reads of v done before results overwrite it

    if (n < NODES) {
#pragma unroll
        for (int o = 0; o < 32; ++o) v[node][obase + o] = acc[o];
    }
    __syncthreads();

#pragma unroll 4
    for (int j = 0; j < 32; ++j) {
        int idx = base + t + j * 256;
        if (idx < NODES * DIM) {
            int off = t + j * 256;
            out[idx] = v[off >> 6][off & 63];
        }
    }
}

// ---------------------------------------------------------------------------
// pooled[batch[n]] += h[n].  Sorted batch -> run-length local accumulation.
// ---------------------------------------------------------------------------
__global__ void pool_kernel(const float* __restrict__ h, const int* __restrict__ batch,
                            float* __restrict__ pooled) {
    int f  = threadIdx.x & 63;
    int g4 = threadIdx.x >> 6;
    int n0 = blockIdx.x * 64 + g4 * 16;
    float sum = 0.f;
    int cur = -1;
    for (int k = 0; k < 16; ++k) {
        int n = n0 + k;
        if (n >= NODES) break;
        int bb = batch[n];
        if (bb != cur) {
            if (cur >= 0) atomicAdd(&pooled[cur * DIM + f], sum);
            cur = bb;
            sum = 0.f;
        }
        sum += h[n * DIM + f];
    }
    if (cur >= 0) atomicAdd(&pooled[cur * DIM + f], sum);
}

// ---------------------------------------------------------------------------
// out[g][o] = KAN_head(pooled[g]) for 512 graphs, 10 targets.
// ---------------------------------------------------------------------------
__global__ __launch_bounds__(64) void head_kernel(const float* __restrict__ pooled,
                                                  const float* __restrict__ bwh,
                                                  const float* __restrict__ swh,
                                                  const float* __restrict__ sch,
                                                  float* __restrict__ out) {
    __shared__ float v[64][65];
    const int t = threadIdx.x;
    const int base = blockIdx.x * 64 * DIM;
#pragma unroll 4
    for (int j = 0; j < 64; ++j) {
        int off = t + j * 64;
        v[off >> 6][off & 63] = pooled[base + off];
    }
    __syncthreads();

    const int g = blockIdx.x * 64 + t;
    float acc[NT];
#pragma unroll
    for (int o = 0; o < NT; ++o) acc[o] = 0.f;

#pragma unroll 1
    for (int i = 0; i < DIM; ++i) {
        float xv = v[t][i];
        float s  = silu(xv);
        float b[8];
        spline_bases(xv, b);
#pragma unroll
        for (int o = 0; o < NT; ++o) {
            float a = fmaf(s, bwh[o * DIM + i], acc[o]);
            float wsc = sch[o * DIM + i];
            const float* sp = swh + (o * DIM + i) * 8;
            float sb = 0.f;
#pragma unroll
            for (int q = 0; q < 8; ++q) sb = fmaf(b[q], sp[q], sb);
            acc[o] = fmaf(sb, wsc, a);
        }
    }
#pragma unroll
    for (int o = 0; o < NT; ++o) out[g * NT + o] = acc[o];
}

// ---------------------------------------------------------------------------
extern "C" void kernel_launch(void* const* d_in, const int* in_sizes, int n_in,
                              void* d_out, int out_size, void* d_ws, size_t ws_size,
                              hipStream_t stream) {
    const float* x   = (const float*)d_in[0];
    const int*   ei  = (const int*)d_in[1];
    const int*   bat = (const int*)d_in[2];
    const float* bw0 = (const float*)d_in[3];
    const float* sw0 = (const float*)d_in[4];
    const float* sc0 = (const float*)d_in[5];
    const float* bw1 = (const float*)d_in[6];
    const float* sw1 = (const float*)d_in[7];
    const float* sc1 = (const float*)d_in[8];
    const float* bwh = (const float*)d_in[9];
    const float* swh = (const float*)d_in[10];
    const float* sch = (const float*)d_in[11];
    float* out = (float*)d_out;

    // ---- workspace layout ----
    float* ws = (float*)d_ws;
    float* Wc0    = ws;                         // 36864 f
    float* Wc1    = Wc0 + KTOT * DIM;           // 36864 f
    float* vbuf   = Wc1 + KTOT * DIM;           // 6.4M f
    float* h      = vbuf + NODES * DIM;         // 6.4M f
    float* pooled = h + NODES * DIM;            // 32768 f
    int* ip       = (int*)(pooled + GRAPHS * DIM);
    int* deg      = ip;                         // 100000 i
    int* incl     = deg + NODES;                // 100000 i
    int* part     = incl + NODES;               // 512 i
    int* rowptr   = part + 512;                 // 100001 i
    int* cursor   = rowptr + NODES + 1;         // 100000 i
    int* col      = cursor + NODES;             // 1200000 i

    // weight prep
    prep_w<<<(KTOT * DIM + 255) / 256, 256, 0, stream>>>(bw0, sw0, sc0, Wc0);
    prep_w<<<(KTOT * DIM + 255) / 256, 256, 0, stream>>>(bw1, sw1, sc1, Wc1);

    // ---- CSR build (once, reused by both layers) ----
    hipMemsetAsync(deg, 0, NODES * sizeof(int), stream);
    hist_kernel<<<(EDGES + 255) / 256, 256, 0, stream>>>(ei, deg);
    scan1<<<NBLK, 256, 0, stream>>>(deg, part, incl);
    scan2<<<1, 512, 0, stream>>>(part);
    scan3<<<NBLK, 256, 0, stream>>>(incl, part, deg, rowptr, cursor);
    fill_csr<<<(EDGES + 255) / 256, 256, 0, stream>>>(ei, cursor, col);

    const int agg_blocks   = (NODES + 3) / 4;        // wave per node
    const int layer_blocks = (NODES + 127) / 128;

    // layer 0
    gather_agg<<<agg_blocks, 256, 0, stream>>>(x, rowptr, col, vbuf);
    kan_layer<<<layer_blocks, 256, 0, stream>>>(vbuf, Wc0, h);

    // layer 1
    gather_agg<<<agg_blocks, 256, 0, stream>>>(h, rowptr, col, vbuf);
    kan_layer<<<layer_blocks, 256, 0, stream>>>(vbuf, Wc1, h);

    // pool + head
    hipMemsetAsync(pooled, 0, (size_t)GRAPHS * DIM * sizeof(float), stream);
    pool_kernel<<<(NODES + 63) / 64, 256, 0, stream>>>(h, bat, pooled);
    head_kernel<<<GRAPHS / 64, 64, 0, stream>>>(pooled, bwh, swh, sch, out);
}

// Round 3
// 690.658 us; speedup vs baseline: 2.2885x; 2.2885x over previous
//
#include <hip/hip_runtime.h>
#include <math.h>

#define NODES   100000
#define EDGES   1200000
#define GRAPHS  512
#define DIM     64
#define NT      10
#define KTOT    576   // 64 base + 64*8 spline features
#define NBLK    ((NODES + 255) / 256)   // 391 scan blocks

#define WT_STRIDE 584   // padded bf16 row stride for W_T in LDS (16B-aligned, banks spread)
#define V_STRIDE  66    // padded bf16 row stride for v in LDS

typedef __attribute__((ext_vector_type(8))) short  frag_ab;  // 8 bf16 (4 VGPRs)
typedef __attribute__((ext_vector_type(4))) float  frag_cd;  // 4 fp32 acc

// ---------------------------------------------------------------------------
// Uniform cubic B-spline bases matching the reference Cox-de Boor recursion.
// grid g[j] = (j-3)*0.4 - 1. Out-of-range x -> all zero.
// ---------------------------------------------------------------------------
__device__ __forceinline__ void spline_bases(float x, float* b) {
    float tt  = fmaf(x, 2.5f, 5.5f);
    float fm  = floorf(tt);
    int   m   = (int)fm;
    float u   = tt - fm;
    float um1 = 1.f - u;
    float v3  = u * u * u * (1.f / 6.f);
    float v0  = um1 * um1 * um1 * (1.f / 6.f);
    float B2m1 = 0.5f * ((u + 1.f) * um1 + (2.f - u) * u);
    float v1  = ((u + 2.f) * um1 * um1 * 0.5f + (2.f - u) * B2m1) * (1.f / 3.f);
    float v2  = ((u + 1.f) * B2m1 + (3.f - u) * u * u * 0.5f) * (1.f / 3.f);
    bool inr  = (m >= 0) && (m <= 10);
#pragma unroll
    for (int j = 0; j < 8; ++j) {
        float bv = 0.f;
        bv = (j == m - 3) ? v0 : bv;
        bv = (j == m - 2) ? v1 : bv;
        bv = (j == m - 1) ? v2 : bv;
        bv = (j == m)     ? v3 : bv;
        b[j] = inr ? bv : 0.f;
    }
}

__device__ __forceinline__ float silu(float x) {
    return x / (1.f + __expf(-x));
}

__device__ __forceinline__ unsigned short f2bf(float f) {   // RNE round
    unsigned x = __builtin_bit_cast(unsigned, f);
    x += 0x7fffu + ((x >> 16) & 1u);
    return (unsigned short)(x >> 16);
}

__device__ __forceinline__ float bf2f(unsigned short u) {
    return __builtin_bit_cast(float, ((unsigned)u) << 16);
}

__device__ __forceinline__ frag_ab pack8(const float* f) {
    union { frag_ab v; unsigned short u[8]; } r;
#pragma unroll
    for (int j = 0; j < 8; ++j) r.u[j] = f2bf(f[j]);
    return r.v;
}

// ---------------------------------------------------------------------------
// Fused weight prep -> bf16 W_T[o][k]:  k<64: base_w[o][k];
// k=64+8i+g: spline_w[o][i][g]*scaler[o][i].
// ---------------------------------------------------------------------------
__global__ void prep_wt(const float* __restrict__ bw, const float* __restrict__ sw,
                        const float* __restrict__ sc, unsigned short* __restrict__ wt) {
    int idx = blockIdx.x * 256 + threadIdx.x;
    if (idx >= DIM * KTOT) return;
    int o = idx / KTOT, k = idx % KTOT;
    float v;
    if (k < DIM) {
        v = bw[o * DIM + k];
    } else {
        int i = (k - DIM) >> 3, g = (k - DIM) & 7;
        v = sw[(o * DIM + i) * 8 + g] * sc[o * DIM + i];
    }
    wt[idx] = f2bf(v);
}

// ===========================================================================
// CSR build: histogram -> 2-level scan -> fill (once per call, both layers).
// ===========================================================================
__global__ void hist_kernel(const int* __restrict__ ei, int* __restrict__ deg) {
    int e = blockIdx.x * 256 + threadIdx.x;
    if (e >= EDGES) return;
    atomicAdd(&deg[ei[EDGES + e]], 1);
}

__global__ void scan1(const int* __restrict__ deg, int* __restrict__ part,
                      int* __restrict__ incl) {
    __shared__ int s[256];
    int i = blockIdx.x * 256 + threadIdx.x;
    int v = (i < NODES) ? deg[i] : 0;
    s[threadIdx.x] = v;
    __syncthreads();
    for (int off = 1; off < 256; off <<= 1) {
        int t = (threadIdx.x >= off) ? s[threadIdx.x - off] : 0;
        __syncthreads();
        s[threadIdx.x] += t;
        __syncthreads();
    }
    if (i < NODES) incl[i] = s[threadIdx.x];
    if (threadIdx.x == 255) part[blockIdx.x] = s[255];
}

__global__ void scan2(int* __restrict__ part) {
    __shared__ int s[512];
    int i = threadIdx.x;
    s[i] = (i < NBLK) ? part[i] : 0;
    __syncthreads();
    for (int off = 1; off < 512; off <<= 1) {
        int t = (i >= off) ? s[i - off] : 0;
        __syncthreads();
        s[i] += t;
        __syncthreads();
    }
    if (i < NBLK) part[i] = s[i];
}

__global__ void scan3(const int* __restrict__ incl, const int* __restrict__ part,
                      const int* __restrict__ deg, int* __restrict__ rowptr,
                      int* __restrict__ cursor) {
    int i = blockIdx.x * 256 + threadIdx.x;
    if (i >= NODES) return;
    int add = (blockIdx.x > 0) ? part[blockIdx.x - 1] : 0;
    int v = incl[i] + add;
    rowptr[i + 1] = v;
    cursor[i] = v - deg[i];
    if (i == 0) rowptr[0] = 0;
}

__global__ void fill_csr(const int* __restrict__ ei, int* __restrict__ cursor,
                         int* __restrict__ col) {
    int e = blockIdx.x * 256 + threadIdx.x;
    if (e >= EDGES) return;
    int src = ei[e];
    int dst = ei[EDGES + e];
    int p = atomicAdd(&cursor[dst], 1);
    col[p] = src;
}

// ---------------------------------------------------------------------------
// v[n] = x[n] + sum_{src in N(n)} x[src].  One wave per node, lane = feature.
// ---------------------------------------------------------------------------
__global__ __launch_bounds__(256) void gather_agg(const float* __restrict__ x,
                                                  const int* __restrict__ rowptr,
                                                  const int* __restrict__ col,
                                                  float* __restrict__ v) {
    int n = blockIdx.x * 4 + (threadIdx.x >> 6);
    int f = threadIdx.x & 63;
    if (n >= NODES) return;
    int beg = rowptr[n], end = rowptr[n + 1];
    float s = x[n * DIM + f];
    for (int p = beg; p < end; ++p) {
        int src = col[p];                 // wave-uniform -> scalar load
        s += x[src * DIM + f];
    }
    v[n * DIM + f] = s;
}

// ---------------------------------------------------------------------------
// MFMA KAN layer.  Grid.x = 2 * ceil(NODES/128); block bx covers nodes
// (bx>>1)*128..+127 and output half (bx&1)*32..+31.
// Block = 512 threads = 8 waves; wave w computes nodes 16w..16w+15 x 32 outs
// as two 16x16x(K=576) MFMA chains.  A-fragments are built in-register from
// bf16 v rows in LDS (one basis-eval per (node,dim), no F matrix anywhere);
// B comes from W_T staged in LDS (broadcast across waves).
// LDS: 32*584*2 + 128*66*2 = 54272 B -> 2 blocks/CU.
// ---------------------------------------------------------------------------
__global__ __launch_bounds__(512) void kan_layer_mfma(const float* __restrict__ vin,
                                                      const unsigned short* __restrict__ wt,
                                                      float* __restrict__ out) {
    __shared__ unsigned short wt_lds[32 * WT_STRIDE];   // 37376 B
    __shared__ unsigned short v_lds[128 * V_STRIDE];    // 16896 B

    const int t      = threadIdx.x;
    const int grp    = blockIdx.x >> 1;       // node group
    const int ohalf  = blockIdx.x & 1;        // output half
    const int nodeg0 = grp * 128;

    // stage this half's 32 W_T rows: 32 rows x 72 16B-chunks
    for (int ci = t; ci < 32 * 72; ci += 512) {
        int o = ci / 72, ch = ci % 72;
        uint4 val = *(const uint4*)(wt + (size_t)(ohalf * 32 + o) * KTOT + ch * 8);
        *(uint4*)(wt_lds + o * WT_STRIDE + ch * 8) = val;
    }
    // stage 128 node rows of v as bf16
    const size_t gbase = (size_t)nodeg0 * DIM;
#pragma unroll
    for (int j = 0; j < 16; ++j) {
        int idx = t + j * 512;
        int node = idx >> 6, dim = idx & 63;
        size_t g = gbase + idx;
        float val = (g < (size_t)NODES * DIM) ? vin[g] : 0.f;
        v_lds[node * V_STRIDE + dim] = f2bf(val);
    }
    __syncthreads();

    const int w  = t >> 6;           // wave 0..7
    const int l  = t & 63;
    const int q  = l >> 4;           // quad
    const int c  = l & 15;
    const unsigned short* vrow = v_lds + ((w << 4) + c) * V_STRIDE;  // A-side node
    const unsigned short* wrow = wt_lds + c * WT_STRIDE;             // B-side out row

    frag_cd acc0 = {0.f, 0.f, 0.f, 0.f};
    frag_cd acc1 = {0.f, 0.f, 0.f, 0.f};

    // ---- base branch: K-steps s=0,1 (k = 32s+8q+j -> silu of 8 dims) ----
#pragma unroll
    for (int s = 0; s < 2; ++s) {
        float f[8];
#pragma unroll
        for (int j = 0; j < 8; ++j) {
            float xv = bf2f(vrow[32 * s + 8 * q + j]);
            f[j] = silu(xv);
        }
        frag_ab a  = pack8(f);
        frag_ab b0 = *(const frag_ab*)(wrow + 32 * s + 8 * q);
        frag_ab b1 = *(const frag_ab*)(wrow + 16 * WT_STRIDE + 32 * s + 8 * q);
        acc0 = __builtin_amdgcn_mfma_f32_16x16x32_bf16(a, b0, acc0, 0, 0, 0);
        acc1 = __builtin_amdgcn_mfma_f32_16x16x32_bf16(a, b1, acc1, 0, 0, 0);
    }

    // ---- spline branch: K-steps s=2..17; lane's 8 k's = the 8 bases of
    //      dim i = 4s+q-8, built in-register ----
#pragma unroll 1
    for (int s = 2; s < 18; ++s) {
        int i = 4 * s + q - 8;
        float xv = bf2f(vrow[i]);
        float bb[8];
        spline_bases(xv, bb);
        frag_ab a  = pack8(bb);
        frag_ab b0 = *(const frag_ab*)(wrow + 32 * s + 8 * q);
        frag_ab b1 = *(const frag_ab*)(wrow + 16 * WT_STRIDE + 32 * s + 8 * q);
        acc0 = __builtin_amdgcn_mfma_f32_16x16x32_bf16(a, b0, acc0, 0, 0, 0);
        acc1 = __builtin_amdgcn_mfma_f32_16x16x32_bf16(a, b1, acc1, 0, 0, 0);
    }

    // ---- store: C/D layout col=lane&15, row=(lane>>4)*4+reg ----
    const int n0   = nodeg0 + (w << 4) + (q << 2);
    const int ocol = (ohalf << 5) + c;
#pragma unroll
    for (int r = 0; r < 4; ++r) {
        int n = n0 + r;
        if (n < NODES) {
            out[(size_t)n * DIM + ocol]      = acc0[r];
            out[(size_t)n * DIM + ocol + 16] = acc1[r];
        }
    }
}

// ---------------------------------------------------------------------------
// pooled[batch[n]] += h[n].  Sorted batch -> run-length local accumulation.
// ---------------------------------------------------------------------------
__global__ void pool_kernel(const float* __restrict__ h, const int* __restrict__ batch,
                            float* __restrict__ pooled) {
    int f  = threadIdx.x & 63;
    int g4 = threadIdx.x >> 6;
    int n0 = blockIdx.x * 64 + g4 * 16;
    float sum = 0.f;
    int cur = -1;
    for (int k = 0; k < 16; ++k) {
        int n = n0 + k;
        if (n >= NODES) break;
        int bb = batch[n];
        if (bb != cur) {
            if (cur >= 0) atomicAdd(&pooled[cur * DIM + f], sum);
            cur = bb;
            sum = 0.f;
        }
        sum += h[n * DIM + f];
    }
    if (cur >= 0) atomicAdd(&pooled[cur * DIM + f], sum);
}

// ---------------------------------------------------------------------------
// out[g][o] = KAN_head(pooled[g]) for 512 graphs, 10 targets (fp32 VALU).
// ---------------------------------------------------------------------------
__global__ __launch_bounds__(64) void head_kernel(const float* __restrict__ pooled,
                                                  const float* __restrict__ bwh,
                                                  const float* __restrict__ swh,
                                                  const float* __restrict__ sch,
                                                  float* __restrict__ out) {
    __shared__ float v[64][65];
    const int t = threadIdx.x;
    const int base = blockIdx.x * 64 * DIM;
#pragma unroll 4
    for (int j = 0; j < 64; ++j) {
        int off = t + j * 64;
        v[off >> 6][off & 63] = pooled[base + off];
    }
    __syncthreads();

    const int g = blockIdx.x * 64 + t;
    float acc[NT];
#pragma unroll
    for (int o = 0; o < NT; ++o) acc[o] = 0.f;

#pragma unroll 1
    for (int i = 0; i < DIM; ++i) {
        float xv = v[t][i];
        float s  = silu(xv);
        float b[8];
        spline_bases(xv, b);
#pragma unroll
        for (int o = 0; o < NT; ++o) {
            float a = fmaf(s, bwh[o * DIM + i], acc[o]);
            float wsc = sch[o * DIM + i];
            const float* sp = swh + (o * DIM + i) * 8;
            float sb = 0.f;
#pragma unroll
            for (int qq = 0; qq < 8; ++qq) sb = fmaf(b[qq], sp[qq], sb);
            acc[o] = fmaf(sb, wsc, a);
        }
    }
#pragma unroll
    for (int o = 0; o < NT; ++o) out[g * NT + o] = acc[o];
}

// ---------------------------------------------------------------------------
extern "C" void kernel_launch(void* const* d_in, const int* in_sizes, int n_in,
                              void* d_out, int out_size, void* d_ws, size_t ws_size,
                              hipStream_t stream) {
    const float* x   = (const float*)d_in[0];
    const int*   ei  = (const int*)d_in[1];
    const int*   bat = (const int*)d_in[2];
    const float* bw0 = (const float*)d_in[3];
    const float* sw0 = (const float*)d_in[4];
    const float* sc0 = (const float*)d_in[5];
    const float* bw1 = (const float*)d_in[6];
    const float* sw1 = (const float*)d_in[7];
    const float* sc1 = (const float*)d_in[8];
    const float* bwh = (const float*)d_in[9];
    const float* swh = (const float*)d_in[10];
    const float* sch = (const float*)d_in[11];
    float* out = (float*)d_out;

    // ---- workspace layout (16B-aligned sections) ----
    char* wsb = (char*)d_ws;
    unsigned short* wt0 = (unsigned short*)wsb;                  // 36864 bf16
    unsigned short* wt1 = wt0 + DIM * KTOT;                      // 36864 bf16
    float* vbuf   = (float*)(wsb + 2 * DIM * KTOT * 2);          // 6.4M f
    float* h      = vbuf + (size_t)NODES * DIM;                  // 6.4M f
    float* pooled = h + (size_t)NODES * DIM;                     // 32768 f
    int* deg      = (int*)(pooled + GRAPHS * DIM);               // 100000 i
    int* incl     = deg + NODES;
    int* part     = incl + NODES;                                // 512 i
    int* rowptr   = part + 512;                                  // 100001 i
    int* cursor   = rowptr + NODES + 1;
    int* col      = cursor + NODES;                              // 1200000 i

    // weight prep (fused scaler, transposed, bf16)
    prep_wt<<<(DIM * KTOT + 255) / 256, 256, 0, stream>>>(bw0, sw0, sc0, wt0);
    prep_wt<<<(DIM * KTOT + 255) / 256, 256, 0, stream>>>(bw1, sw1, sc1, wt1);

    // ---- CSR build (once, reused by both layers) ----
    hipMemsetAsync(deg, 0, NODES * sizeof(int), stream);
    hist_kernel<<<(EDGES + 255) / 256, 256, 0, stream>>>(ei, deg);
    scan1<<<NBLK, 256, 0, stream>>>(deg, part, incl);
    scan2<<<1, 512, 0, stream>>>(part);
    scan3<<<NBLK, 256, 0, stream>>>(incl, part, deg, rowptr, cursor);
    fill_csr<<<(EDGES + 255) / 256, 256, 0, stream>>>(ei, cursor, col);

    const int agg_blocks = (NODES + 3) / 4;
    const int kan_blocks = 2 * ((NODES + 127) / 128);   // x2 output halves

    // layer 0
    gather_agg<<<agg_blocks, 256, 0, stream>>>(x, rowptr, col, vbuf);
    kan_layer_mfma<<<kan_blocks, 512, 0, stream>>>(vbuf, wt0, h);

    // layer 1
    gather_agg<<<agg_blocks, 256, 0, stream>>>(h, rowptr, col, vbuf);
    kan_layer_mfma<<<kan_blocks, 512, 0, stream>>>(vbuf, wt1, h);

    // pool + head
    hipMemsetAsync(pooled, 0, (size_t)GRAPHS * DIM * sizeof(float), stream);
    pool_kernel<<<(NODES + 63) / 64, 256, 0, stream>>>(h, bat, pooled);
    head_kernel<<<GRAPHS / 64, 64, 0, stream>>>(pooled, bwh, swh, sch, out);
}

// Round 4
// 564.653 us; speedup vs baseline: 2.7992x; 1.2232x over previous
//
#include <hip/hip_runtime.h>
#include <math.h>

#define NODES   100000
#define EDGES   1200000
#define GRAPHS  512
#define DIM     64
#define NT      10
#define KTOT    576   // 64 base + 64*8 spline features
#define NBLK    ((NODES + 255) / 256)   // 391 scan blocks

#define WT_STRIDE 584   // padded bf16 row stride for W_T in LDS
#define V_STRIDE  66    // padded bf16 row stride for v in LDS

typedef __attribute__((ext_vector_type(8))) short  frag_ab;  // 8 bf16 (4 VGPRs)
typedef __attribute__((ext_vector_type(4))) float  frag_cd;  // 4 fp32 acc

// ---------------------------------------------------------------------------
// Uniform cubic B-spline bases matching the reference Cox-de Boor recursion.
// ---------------------------------------------------------------------------
__device__ __forceinline__ void spline_bases(float x, float* b) {
    float tt  = fmaf(x, 2.5f, 5.5f);
    float fm  = floorf(tt);
    int   m   = (int)fm;
    float u   = tt - fm;
    float um1 = 1.f - u;
    float v3  = u * u * u * (1.f / 6.f);
    float v0  = um1 * um1 * um1 * (1.f / 6.f);
    float B2m1 = 0.5f * ((u + 1.f) * um1 + (2.f - u) * u);
    float v1  = ((u + 2.f) * um1 * um1 * 0.5f + (2.f - u) * B2m1) * (1.f / 3.f);
    float v2  = ((u + 1.f) * B2m1 + (3.f - u) * u * u * 0.5f) * (1.f / 3.f);
    bool inr  = (m >= 0) && (m <= 10);
#pragma unroll
    for (int j = 0; j < 8; ++j) {
        float bv = 0.f;
        bv = (j == m - 3) ? v0 : bv;
        bv = (j == m - 2) ? v1 : bv;
        bv = (j == m - 1) ? v2 : bv;
        bv = (j == m)     ? v3 : bv;
        b[j] = inr ? bv : 0.f;
    }
}

__device__ __forceinline__ float silu(float x) {
    return x / (1.f + __expf(-x));
}

__device__ __forceinline__ unsigned short f2bf(float f) {   // RNE round
    unsigned x = __builtin_bit_cast(unsigned, f);
    x += 0x7fffu + ((x >> 16) & 1u);
    return (unsigned short)(x >> 16);
}

__device__ __forceinline__ float bf2f(unsigned short u) {
    return __builtin_bit_cast(float, ((unsigned)u) << 16);
}

__device__ __forceinline__ frag_ab pack8(const float* f) {
    union { frag_ab v; unsigned short u[8]; } r;
#pragma unroll
    for (int j = 0; j < 8; ++j) r.u[j] = f2bf(f[j]);
    return r.v;
}

__device__ __forceinline__ void add4(float4& a, const float4 b) {
    a.x += b.x; a.y += b.y; a.z += b.z; a.w += b.w;
}

// ---------------------------------------------------------------------------
// Fused weight prep for BOTH layers -> bf16 W_T[o][k].
// ---------------------------------------------------------------------------
__global__ void prep_wt2(const float* __restrict__ bw0, const float* __restrict__ sw0,
                         const float* __restrict__ sc0,
                         const float* __restrict__ bw1, const float* __restrict__ sw1,
                         const float* __restrict__ sc1,
                         unsigned short* __restrict__ wt0,
                         unsigned short* __restrict__ wt1) {
    int idx = blockIdx.x * 256 + threadIdx.x;
    if (idx >= 2 * DIM * KTOT) return;
    int layer = idx >= DIM * KTOT;
    int li = layer ? idx - DIM * KTOT : idx;
    const float* bw = layer ? bw1 : bw0;
    const float* sw = layer ? sw1 : sw0;
    const float* sc = layer ? sc1 : sc0;
    unsigned short* wt = layer ? wt1 : wt0;
    int o = li / KTOT, k = li % KTOT;
    float v;
    if (k < DIM) {
        v = bw[o * DIM + k];
    } else {
        int i = (k - DIM) >> 3, g = (k - DIM) & 7;
        v = sw[(o * DIM + i) * 8 + g] * sc[o * DIM + i];
    }
    wt[li] = f2bf(v);
}

// ===========================================================================
// CSR build: histogram -> 2-level scan -> fill (once per call, both layers).
// ===========================================================================
__global__ void hist_kernel(const int* __restrict__ ei, int* __restrict__ deg) {
    int e = blockIdx.x * 256 + threadIdx.x;
    if (e >= EDGES) return;
    atomicAdd(&deg[ei[EDGES + e]], 1);
}

__global__ void scan1(const int* __restrict__ deg, int* __restrict__ part,
                      int* __restrict__ incl) {
    __shared__ int s[256];
    int i = blockIdx.x * 256 + threadIdx.x;
    int v = (i < NODES) ? deg[i] : 0;
    s[threadIdx.x] = v;
    __syncthreads();
    for (int off = 1; off < 256; off <<= 1) {
        int t = (threadIdx.x >= off) ? s[threadIdx.x - off] : 0;
        __syncthreads();
        s[threadIdx.x] += t;
        __syncthreads();
    }
    if (i < NODES) incl[i] = s[threadIdx.x];
    if (threadIdx.x == 255) part[blockIdx.x] = s[255];
}

__global__ void scan2(int* __restrict__ part) {
    __shared__ int s[512];
    int i = threadIdx.x;
    s[i] = (i < NBLK) ? part[i] : 0;
    __syncthreads();
    for (int off = 1; off < 512; off <<= 1) {
        int t = (i >= off) ? s[i - off] : 0;
        __syncthreads();
        s[i] += t;
        __syncthreads();
    }
    if (i < NBLK) part[i] = s[i];
}

__global__ void scan3(const int* __restrict__ incl, const int* __restrict__ part,
                      const int* __restrict__ deg, int* __restrict__ rowptr,
                      int* __restrict__ cursor) {
    int i = blockIdx.x * 256 + threadIdx.x;
    if (i >= NODES) return;
    int add = (blockIdx.x > 0) ? part[blockIdx.x - 1] : 0;
    int v = incl[i] + add;
    rowptr[i + 1] = v;
    cursor[i] = v - deg[i];
    if (i == 0) rowptr[0] = 0;
}

__global__ void fill_csr(const int* __restrict__ ei, int* __restrict__ cursor,
                         int* __restrict__ col) {
    int e = blockIdx.x * 256 + threadIdx.x;
    if (e >= EDGES) return;
    int src = ei[e];
    int dst = ei[EDGES + e];
    int p = atomicAdd(&cursor[dst], 1);
    col[p] = src;
}

// ---------------------------------------------------------------------------
// v[n] = x[n] + sum_{src in N(n)} x[src].
// ILP version: 16 lanes per node (float4/lane), 4 nodes per wave, edge loop
// unrolled x4 into 4 independent partial sums -> up to 16 outstanding 16B
// loads per wave instead of a single serial chain.
// ---------------------------------------------------------------------------
__global__ __launch_bounds__(256) void gather_agg(const float* __restrict__ x,
                                                  const int* __restrict__ rowptr,
                                                  const int* __restrict__ col,
                                                  float* __restrict__ v) {
    const int n  = blockIdx.x * 16 + (threadIdx.x >> 4);
    const int fq = threadIdx.x & 15;
    if (n >= NODES) return;
    const float4* x4 = (const float4*)x;
    const int beg = rowptr[n], end = rowptr[n + 1];
    float4 s0 = x4[(size_t)n * 16 + fq];
    float4 s1 = {0.f, 0.f, 0.f, 0.f};
    float4 s2 = {0.f, 0.f, 0.f, 0.f};
    float4 s3 = {0.f, 0.f, 0.f, 0.f};
    int p = beg;
    for (; p + 3 < end; p += 4) {
        int c0 = col[p];
        int c1 = col[p + 1];
        int c2 = col[p + 2];
        int c3 = col[p + 3];
        add4(s0, x4[(size_t)c0 * 16 + fq]);
        add4(s1, x4[(size_t)c1 * 16 + fq]);
        add4(s2, x4[(size_t)c2 * 16 + fq]);
        add4(s3, x4[(size_t)c3 * 16 + fq]);
    }
    for (; p < end; ++p) add4(s0, x4[(size_t)col[p] * 16 + fq]);
    add4(s0, s1); add4(s2, s3); add4(s0, s2);
    ((float4*)v)[(size_t)n * 16 + fq] = s0;
}

// ---------------------------------------------------------------------------
// MFMA KAN layer (unchanged from round 3; see comments there).
// ---------------------------------------------------------------------------
__global__ __launch_bounds__(512) void kan_layer_mfma(const float* __restrict__ vin,
                                                      const unsigned short* __restrict__ wt,
                                                      float* __restrict__ out) {
    __shared__ unsigned short wt_lds[32 * WT_STRIDE];   // 37376 B
    __shared__ unsigned short v_lds[128 * V_STRIDE];    // 16896 B

    const int t      = threadIdx.x;
    const int grp    = blockIdx.x >> 1;
    const int ohalf  = blockIdx.x & 1;
    const int nodeg0 = grp * 128;

    for (int ci = t; ci < 32 * 72; ci += 512) {
        int o = ci / 72, ch = ci % 72;
        uint4 val = *(const uint4*)(wt + (size_t)(ohalf * 32 + o) * KTOT + ch * 8);
        *(uint4*)(wt_lds + o * WT_STRIDE + ch * 8) = val;
    }
    const size_t gbase = (size_t)nodeg0 * DIM;
#pragma unroll
    for (int j = 0; j < 16; ++j) {
        int idx = t + j * 512;
        int node = idx >> 6, dim = idx & 63;
        size_t g = gbase + idx;
        float val = (g < (size_t)NODES * DIM) ? vin[g] : 0.f;
        v_lds[node * V_STRIDE + dim] = f2bf(val);
    }
    __syncthreads();

    const int w  = t >> 6;
    const int l  = t & 63;
    const int q  = l >> 4;
    const int c  = l & 15;
    const unsigned short* vrow = v_lds + ((w << 4) + c) * V_STRIDE;
    const unsigned short* wrow = wt_lds + c * WT_STRIDE;

    frag_cd acc0 = {0.f, 0.f, 0.f, 0.f};
    frag_cd acc1 = {0.f, 0.f, 0.f, 0.f};

#pragma unroll
    for (int s = 0; s < 2; ++s) {
        float f[8];
#pragma unroll
        for (int j = 0; j < 8; ++j) {
            float xv = bf2f(vrow[32 * s + 8 * q + j]);
            f[j] = silu(xv);
        }
        frag_ab a  = pack8(f);
        frag_ab b0 = *(const frag_ab*)(wrow + 32 * s + 8 * q);
        frag_ab b1 = *(const frag_ab*)(wrow + 16 * WT_STRIDE + 32 * s + 8 * q);
        acc0 = __builtin_amdgcn_mfma_f32_16x16x32_bf16(a, b0, acc0, 0, 0, 0);
        acc1 = __builtin_amdgcn_mfma_f32_16x16x32_bf16(a, b1, acc1, 0, 0, 0);
    }

#pragma unroll 1
    for (int s = 2; s < 18; ++s) {
        int i = 4 * s + q - 8;
        float xv = bf2f(vrow[i]);
        float bb[8];
        spline_bases(xv, bb);
        frag_ab a  = pack8(bb);
        frag_ab b0 = *(const frag_ab*)(wrow + 32 * s + 8 * q);
        frag_ab b1 = *(const frag_ab*)(wrow + 16 * WT_STRIDE + 32 * s + 8 * q);
        acc0 = __builtin_amdgcn_mfma_f32_16x16x32_bf16(a, b0, acc0, 0, 0, 0);
        acc1 = __builtin_amdgcn_mfma_f32_16x16x32_bf16(a, b1, acc1, 0, 0, 0);
    }

    const int n0   = nodeg0 + (w << 4) + (q << 2);
    const int ocol = (ohalf << 5) + c;
#pragma unroll
    for (int r = 0; r < 4; ++r) {
        int n = n0 + r;
        if (n < NODES) {
            out[(size_t)n * DIM + ocol]      = acc0[r];
            out[(size_t)n * DIM + ocol + 16] = acc1[r];
        }
    }
}

// ---------------------------------------------------------------------------
// pooled[batch[n]] += h[n].  Sorted batch -> run-length local accumulation.
// ---------------------------------------------------------------------------
__global__ void pool_kernel(const float* __restrict__ h, const int* __restrict__ batch,
                            float* __restrict__ pooled) {
    int f  = threadIdx.x & 63;
    int g4 = threadIdx.x >> 6;
    int n0 = blockIdx.x * 64 + g4 * 16;
    float sum = 0.f;
    int cur = -1;
    for (int k = 0; k < 16; ++k) {
        int n = n0 + k;
        if (n >= NODES) break;
        int bb = batch[n];
        if (bb != cur) {
            if (cur >= 0) atomicAdd(&pooled[cur * DIM + f], sum);
            cur = bb;
            sum = 0.f;
        }
        sum += h[n * DIM + f];
    }
    if (cur >= 0) atomicAdd(&pooled[cur * DIM + f], sum);
}

// ---------------------------------------------------------------------------
// out[g][o] = KAN_head(pooled[g]) for 512 graphs, 10 targets (fp32 VALU).
// ---------------------------------------------------------------------------
__global__ __launch_bounds__(64) void head_kernel(const float* __restrict__ pooled,
                                                  const float* __restrict__ bwh,
                                                  const float* __restrict__ swh,
                                                  const float* __restrict__ sch,
                                                  float* __restrict__ out) {
    __shared__ float v[64][65];
    const int t = threadIdx.x;
    const int base = blockIdx.x * 64 * DIM;
#pragma unroll 4
    for (int j = 0; j < 64; ++j) {
        int off = t + j * 64;
        v[off >> 6][off & 63] = pooled[base + off];
    }
    __syncthreads();

    const int g = blockIdx.x * 64 + t;
    float acc[NT];
#pragma unroll
    for (int o = 0; o < NT; ++o) acc[o] = 0.f;

#pragma unroll 1
    for (int i = 0; i < DIM; ++i) {
        float xv = v[t][i];
        float s  = silu(xv);
        float b[8];
        spline_bases(xv, b);
#pragma unroll
        for (int o = 0; o < NT; ++o) {
            float a = fmaf(s, bwh[o * DIM + i], acc[o]);
            float wsc = sch[o * DIM + i];
            const float* sp = swh + (o * DIM + i) * 8;
            float sb = 0.f;
#pragma unroll
            for (int qq = 0; qq < 8; ++qq) sb = fmaf(b[qq], sp[qq], sb);
            acc[o] = fmaf(sb, wsc, a);
        }
    }
#pragma unroll
    for (int o = 0; o < NT; ++o) out[g * NT + o] = acc[o];
}

// ---------------------------------------------------------------------------
extern "C" void kernel_launch(void* const* d_in, const int* in_sizes, int n_in,
                              void* d_out, int out_size, void* d_ws, size_t ws_size,
                              hipStream_t stream) {
    const float* x   = (const float*)d_in[0];
    const int*   ei  = (const int*)d_in[1];
    const int*   bat = (const int*)d_in[2];
    const float* bw0 = (const float*)d_in[3];
    const float* sw0 = (const float*)d_in[4];
    const float* sc0 = (const float*)d_in[5];
    const float* bw1 = (const float*)d_in[6];
    const float* sw1 = (const float*)d_in[7];
    const float* sc1 = (const float*)d_in[8];
    const float* bwh = (const float*)d_in[9];
    const float* swh = (const float*)d_in[10];
    const float* sch = (const float*)d_in[11];
    float* out = (float*)d_out;

    // ---- workspace layout (16B-aligned sections) ----
    char* wsb = (char*)d_ws;
    unsigned short* wt0 = (unsigned short*)wsb;                  // 36864 bf16
    unsigned short* wt1 = wt0 + DIM * KTOT;                      // 36864 bf16
    float* vbuf   = (float*)(wsb + 2 * DIM * KTOT * 2);          // 6.4M f
    float* h      = vbuf + (size_t)NODES * DIM;                  // 6.4M f
    float* pooled = h + (size_t)NODES * DIM;                     // 32768 f
    int* deg      = (int*)(pooled + GRAPHS * DIM);               // 100000 i
    int* incl     = deg + NODES;
    int* part     = incl + NODES;                                // 512 i
    int* rowptr   = part + 512;                                  // 100001 i
    int* cursor   = rowptr + NODES + 1;
    int* col      = cursor + NODES;                              // 1200000 i

    // weight prep (both layers, one launch)
    prep_wt2<<<(2 * DIM * KTOT + 255) / 256, 256, 0, stream>>>(
        bw0, sw0, sc0, bw1, sw1, sc1, wt0, wt1);

    // ---- CSR build (once, reused by both layers) ----
    hipMemsetAsync(deg, 0, NODES * sizeof(int), stream);
    hist_kernel<<<(EDGES + 255) / 256, 256, 0, stream>>>(ei, deg);
    scan1<<<NBLK, 256, 0, stream>>>(deg, part, incl);
    scan2<<<1, 512, 0, stream>>>(part);
    scan3<<<NBLK, 256, 0, stream>>>(incl, part, deg, rowptr, cursor);
    fill_csr<<<(EDGES + 255) / 256, 256, 0, stream>>>(ei, cursor, col);

    const int agg_blocks = (NODES + 15) / 16;           // 16 nodes per block
    const int kan_blocks = 2 * ((NODES + 127) / 128);   // x2 output halves

    // layer 0
    gather_agg<<<agg_blocks, 256, 0, stream>>>(x, rowptr, col, vbuf);
    kan_layer_mfma<<<kan_blocks, 512, 0, stream>>>(vbuf, wt0, h);

    // layer 1
    gather_agg<<<agg_blocks, 256, 0, stream>>>(h, rowptr, col, vbuf);
    kan_layer_mfma<<<kan_blocks, 512, 0, stream>>>(vbuf, wt1, h);

    // pool + head
    hipMemsetAsync(pooled, 0, (size_t)GRAPHS * DIM * sizeof(float), stream);
    pool_kernel<<<(NODES + 63) / 64, 256, 0, stream>>>(h, bat, pooled);
    head_kernel<<<GRAPHS / 64, 64, 0, stream>>>(pooled, bwh, swh, sch, out);
}

// Round 5
// 411.073 us; speedup vs baseline: 3.8451x; 1.3736x over previous
//
#include <hip/hip_runtime.h>
#include <math.h>

#define NODES   100000
#define EDGES   1200000
#define GRAPHS  512
#define DIM     64
#define NT      10
#define KTOT    576     // 64 base + 64*8 spline features

#define NB      512     // sort buckets: bucket = dst >> 8 (256 nodes each)
#define EPB     4096    // edges per partition block

#define WT_STRIDE 584   // padded bf16 row stride for W_T in LDS (16B-aligned)
#define V_STRIDE  72    // padded bf16 row stride for v in LDS (16B-aligned)

typedef __attribute__((ext_vector_type(8))) short  frag_ab;  // 8 bf16
typedef __attribute__((ext_vector_type(4))) float  frag_cd;  // 4 fp32 acc

// ---------------------------------------------------------------------------
// Uniform cubic B-spline bases matching the reference Cox-de Boor recursion.
// ---------------------------------------------------------------------------
__device__ __forceinline__ void spline_bases(float x, float* b) {
    float tt  = fmaf(x, 2.5f, 5.5f);
    float fm  = floorf(tt);
    int   m   = (int)fm;
    float u   = tt - fm;
    float um1 = 1.f - u;
    float v3  = u * u * u * (1.f / 6.f);
    float v0  = um1 * um1 * um1 * (1.f / 6.f);
    float B2m1 = 0.5f * ((u + 1.f) * um1 + (2.f - u) * u);
    float v1  = ((u + 2.f) * um1 * um1 * 0.5f + (2.f - u) * B2m1) * (1.f / 3.f);
    float v2  = ((u + 1.f) * B2m1 + (3.f - u) * u * u * 0.5f) * (1.f / 3.f);
    bool inr  = (m >= 0) && (m <= 10);
#pragma unroll
    for (int j = 0; j < 8; ++j) {
        float bv = 0.f;
        bv = (j == m - 3) ? v0 : bv;
        bv = (j == m - 2) ? v1 : bv;
        bv = (j == m - 1) ? v2 : bv;
        bv = (j == m)     ? v3 : bv;
        b[j] = inr ? bv : 0.f;
    }
}

__device__ __forceinline__ float silu(float x) {
    return x / (1.f + __expf(-x));
}

__device__ __forceinline__ unsigned short f2bf(float f) {   // RNE round
    unsigned x = __builtin_bit_cast(unsigned, f);
    x += 0x7fffu + ((x >> 16) & 1u);
    return (unsigned short)(x >> 16);
}

__device__ __forceinline__ float bf2f(unsigned short u) {
    return __builtin_bit_cast(float, ((unsigned)u) << 16);
}

__device__ __forceinline__ frag_ab pack8(const float* f) {
    union { frag_ab v; unsigned short u[8]; } r;
#pragma unroll
    for (int j = 0; j < 8; ++j) r.u[j] = f2bf(f[j]);
    return r.v;
}

// add 8 bf16 (one uint4) into float acc[8]: low half via <<16, high via mask
__device__ __forceinline__ void acc_bf8(float* a, uint4 p) {
    unsigned w0 = p.x, w1 = p.y, w2 = p.z, w3 = p.w;
    a[0] += __builtin_bit_cast(float, w0 << 16);
    a[1] += __builtin_bit_cast(float, w0 & 0xffff0000u);
    a[2] += __builtin_bit_cast(float, w1 << 16);
    a[3] += __builtin_bit_cast(float, w1 & 0xffff0000u);
    a[4] += __builtin_bit_cast(float, w2 << 16);
    a[5] += __builtin_bit_cast(float, w2 & 0xffff0000u);
    a[6] += __builtin_bit_cast(float, w3 << 16);
    a[7] += __builtin_bit_cast(float, w3 & 0xffff0000u);
}

// ---------------------------------------------------------------------------
// Fused weight prep for BOTH layers -> bf16 W_T[o][k].
// ---------------------------------------------------------------------------
__global__ void prep_wt2(const float* __restrict__ bw0, const float* __restrict__ sw0,
                         const float* __restrict__ sc0,
                         const float* __restrict__ bw1, const float* __restrict__ sw1,
                         const float* __restrict__ sc1,
                         unsigned short* __restrict__ wt0,
                         unsigned short* __restrict__ wt1) {
    int idx = blockIdx.x * 256 + threadIdx.x;
    if (idx >= 2 * DIM * KTOT) return;
    int layer = idx >= DIM * KTOT;
    int li = layer ? idx - DIM * KTOT : idx;
    const float* bw = layer ? bw1 : bw0;
    const float* sw = layer ? sw1 : sw0;
    const float* sc = layer ? sc1 : sc0;
    unsigned short* wt = layer ? wt1 : wt0;
    int o = li / KTOT, k = li % KTOT;
    float v;
    if (k < DIM) {
        v = bw[o * DIM + k];
    } else {
        int i = (k - DIM) >> 3, g = (k - DIM) & 7;
        v = sw[(o * DIM + i) * 8 + g] * sc[o * DIM + i];
    }
    wt[li] = f2bf(v);
}

// ---------------------------------------------------------------------------
// x (fp32) -> xbf (bf16), 4 elements per thread.
// ---------------------------------------------------------------------------
__global__ void conv_bf16(const float* __restrict__ x, unsigned short* __restrict__ xb) {
    int i = blockIdx.x * 256 + threadIdx.x;
    if (i >= NODES * DIM / 4) return;
    float4 v = ((const float4*)x)[i];
    unsigned lo = (unsigned)f2bf(v.x) | ((unsigned)f2bf(v.y) << 16);
    unsigned hi = (unsigned)f2bf(v.z) | ((unsigned)f2bf(v.w) << 16);
    ((uint2*)xb)[i] = make_uint2(lo, hi);
}

// ===========================================================================
// Bucketed counting sort of edges by dst -> CSR (rowptr, col).
// ===========================================================================
// S1: per-block LDS histogram over 512 buckets -> global bucket counts.
__global__ __launch_bounds__(256) void s1_count(const int* __restrict__ ei,
                                                int* __restrict__ bcnt) {
    __shared__ int hist[NB];
    int t = threadIdx.x;
    hist[t] = 0; hist[t + 256] = 0;
    __syncthreads();
    int e0 = blockIdx.x * EPB;
#pragma unroll
    for (int k = 0; k < 16; ++k) {
        int e = e0 + t + k * 256;
        if (e < EDGES) atomicAdd(&hist[ei[EDGES + e] >> 8], 1);
    }
    __syncthreads();
    int c0 = hist[t];       if (c0) atomicAdd(&bcnt[t], c0);
    int c1 = hist[t + 256]; if (c1) atomicAdd(&bcnt[t + 256], c1);
}

// S2: exclusive scan of 512 bucket counts (one block); init bucket cursors.
__global__ __launch_bounds__(512) void s2_scan(const int* __restrict__ bcnt,
                                               int* __restrict__ bbase,
                                               int* __restrict__ bcur) {
    __shared__ int s[NB];
    int t = threadIdx.x;
    int v = bcnt[t];
    s[t] = v;
    __syncthreads();
    int run = v;
    for (int d = 1; d < NB; d <<= 1) {
        int a = (t >= d) ? s[t - d] : 0;
        __syncthreads();
        run += a; s[t] = run;
        __syncthreads();
    }
    int excl = run - v;
    bbase[t] = excl;
    bcur[t]  = excl;
}

// S3: partition edges into bucket-contiguous (src,dst) pairs. Per-block LDS
// histogram + one global reservation per (block,bucket) -> block-private
// contiguous chunks (~64B) instead of fully random 4B writes.
__global__ __launch_bounds__(256) void s3_partition(const int* __restrict__ ei,
                                                    int* __restrict__ bcur,
                                                    int2* __restrict__ tmp2) {
    __shared__ int hist[NB], gbase[NB], cur[NB];
    int t = threadIdx.x;
    hist[t] = 0; hist[t + 256] = 0;
    cur[t]  = 0; cur[t + 256]  = 0;
    __syncthreads();
    int e0 = blockIdx.x * EPB;
#pragma unroll
    for (int k = 0; k < 16; ++k) {
        int e = e0 + t + k * 256;
        if (e < EDGES) atomicAdd(&hist[ei[EDGES + e] >> 8], 1);
    }
    __syncthreads();
    {
        int c0 = hist[t];       if (c0) gbase[t]       = atomicAdd(&bcur[t], c0);
        int c1 = hist[t + 256]; if (c1) gbase[t + 256] = atomicAdd(&bcur[t + 256], c1);
    }
    __syncthreads();
#pragma unroll
    for (int k = 0; k < 16; ++k) {
        int e = e0 + t + k * 256;
        if (e < EDGES) {
            int src = ei[e];
            int dst = ei[EDGES + e];
            int b = dst >> 8;
            int slot = atomicAdd(&cur[b], 1);
            tmp2[gbase[b] + slot] = make_int2(src, dst);
        }
    }
}

// S4: one block per bucket: local node histogram -> local scan -> rowptr;
// then scatter col within the bucket's private contiguous region.
__global__ __launch_bounds__(256) void s4_fill(const int2* __restrict__ tmp2,
                                               const int* __restrict__ bcnt,
                                               const int* __restrict__ bbase,
                                               int* __restrict__ rowptr,
                                               int* __restrict__ col) {
    __shared__ int hist[256], scan[256];
    int b = blockIdx.x, t = threadIdx.x;
    int cnt = bcnt[b], base = bbase[b];
    hist[t] = 0;
    __syncthreads();
    for (int i = t; i < cnt; i += 256)
        atomicAdd(&hist[tmp2[base + i].y & 255], 1);
    __syncthreads();
    int v = hist[t];
    scan[t] = v;
    __syncthreads();
    int run = v;
    for (int d = 1; d < 256; d <<= 1) {
        int a = (t >= d) ? scan[t - d] : 0;
        __syncthreads();
        run += a; scan[t] = run;
        __syncthreads();
    }
    int excl = run - v;
    int ng = b * 256 + t;
    if (ng <= NODES) rowptr[ng] = base + excl;
    __syncthreads();
    scan[t] = excl;            // reuse as cursor
    __syncthreads();
    for (int i = t; i < cnt; i += 256) {
        int2 p = tmp2[base + i];
        int pos = atomicAdd(&scan[p.y & 255], 1);
        col[base + pos] = p.x;
    }
}

// ---------------------------------------------------------------------------
// v[n] = x[n] + sum_{src in N(n)} x[src], all bf16 rows (128B), fp32 accum.
// 8 lanes per node (uint4 = 8 bf16 per lane), edge loop unrolled x4 into
// independent partial sums for memory-level parallelism.
// ---------------------------------------------------------------------------
__global__ __launch_bounds__(256) void gather_agg_bf(const unsigned short* __restrict__ xbf,
                                                     const int* __restrict__ rowptr,
                                                     const int* __restrict__ col,
                                                     unsigned short* __restrict__ vbf) {
    const int n  = blockIdx.x * 32 + (threadIdx.x >> 3);   // grid covers exactly NODES
    const int fq = threadIdx.x & 7;
    const uint4* x4 = (const uint4*)xbf;
    const int beg = rowptr[n], end = rowptr[n + 1];
    float a0[8], a1[8], a2[8], a3[8];
#pragma unroll
    for (int j = 0; j < 8; ++j) { a0[j] = 0.f; a1[j] = 0.f; a2[j] = 0.f; a3[j] = 0.f; }
    acc_bf8(a0, x4[(size_t)n * 8 + fq]);                   // self term
    int p = beg;
    for (; p + 3 < end; p += 4) {
        int c0 = col[p], c1 = col[p + 1], c2 = col[p + 2], c3 = col[p + 3];
        uint4 r0 = x4[(size_t)c0 * 8 + fq];
        uint4 r1 = x4[(size_t)c1 * 8 + fq];
        uint4 r2 = x4[(size_t)c2 * 8 + fq];
        uint4 r3 = x4[(size_t)c3 * 8 + fq];
        acc_bf8(a0, r0); acc_bf8(a1, r1); acc_bf8(a2, r2); acc_bf8(a3, r3);
    }
    for (; p < end; ++p) acc_bf8(a0, x4[(size_t)col[p] * 8 + fq]);
    union { uint4 u; unsigned short s[8]; } r;
#pragma unroll
    for (int j = 0; j < 8; ++j) r.s[j] = f2bf(a0[j] + a1[j] + a2[j] + a3[j]);
    ((uint4*)vbf)[(size_t)n * 8 + fq] = r.u;
}

// ---------------------------------------------------------------------------
// MFMA KAN layer: h[n] = KAN(v[n]).  bf16 in (vbf), bf16 out (hbf).
// Block bx: nodes (bx>>1)*128..+127, output half (bx&1)*32..+31.
// 8 waves; wave w: nodes 16w..16w+15 x 32 outs, two 16x16x(K=576) chains.
// A-fragments built in-register (silu / spline bases), B = W_T from LDS.
// ---------------------------------------------------------------------------
__global__ __launch_bounds__(512) void kan_layer_mfma(const unsigned short* __restrict__ vin,
                                                      const unsigned short* __restrict__ wt,
                                                      unsigned short* __restrict__ out) {
    __shared__ unsigned short wt_lds[32 * WT_STRIDE];   // 37376 B
    __shared__ unsigned short v_lds[128 * V_STRIDE];    // 18432 B

    const int t      = threadIdx.x;
    const int grp    = blockIdx.x >> 1;
    const int ohalf  = blockIdx.x & 1;
    const int nodeg0 = grp * 128;

    for (int ci = t; ci < 32 * 72; ci += 512) {
        int o = ci / 72, ch = ci % 72;
        uint4 val = *(const uint4*)(wt + (size_t)(ohalf * 32 + o) * KTOT + ch * 8);
        *(uint4*)(wt_lds + o * WT_STRIDE + ch * 8) = val;
    }
    const uint4* v4 = (const uint4*)vin;
#pragma unroll
    for (int it = 0; it < 2; ++it) {
        int ci = t + it * 512;
        int node = ci >> 3, c8 = ci & 7;
        int gnode = nodeg0 + node;
        uint4 val = make_uint4(0, 0, 0, 0);
        if (gnode < NODES) val = v4[(size_t)gnode * 8 + c8];
        *(uint4*)(v_lds + node * V_STRIDE + c8 * 8) = val;
    }
    __syncthreads();

    const int w  = t >> 6;
    const int l  = t & 63;
    const int q  = l >> 4;
    const int c  = l & 15;
    const unsigned short* vrow = v_lds + ((w << 4) + c) * V_STRIDE;
    const unsigned short* wrow = wt_lds + c * WT_STRIDE;

    frag_cd acc0 = {0.f, 0.f, 0.f, 0.f};
    frag_cd acc1 = {0.f, 0.f, 0.f, 0.f};

#pragma unroll
    for (int s = 0; s < 2; ++s) {
        float f[8];
#pragma unroll
        for (int j = 0; j < 8; ++j) {
            float xv = bf2f(vrow[32 * s + 8 * q + j]);
            f[j] = silu(xv);
        }
        frag_ab a  = pack8(f);
        frag_ab b0 = *(const frag_ab*)(wrow + 32 * s + 8 * q);
        frag_ab b1 = *(const frag_ab*)(wrow + 16 * WT_STRIDE + 32 * s + 8 * q);
        acc0 = __builtin_amdgcn_mfma_f32_16x16x32_bf16(a, b0, acc0, 0, 0, 0);
        acc1 = __builtin_amdgcn_mfma_f32_16x16x32_bf16(a, b1, acc1, 0, 0, 0);
    }

#pragma unroll 1
    for (int s = 2; s < 18; ++s) {
        int i = 4 * s + q - 8;
        float xv = bf2f(vrow[i]);
        float bb[8];
        spline_bases(xv, bb);
        frag_ab a  = pack8(bb);
        frag_ab b0 = *(const frag_ab*)(wrow + 32 * s + 8 * q);
        frag_ab b1 = *(const frag_ab*)(wrow + 16 * WT_STRIDE + 32 * s + 8 * q);
        acc0 = __builtin_amdgcn_mfma_f32_16x16x32_bf16(a, b0, acc0, 0, 0, 0);
        acc1 = __builtin_amdgcn_mfma_f32_16x16x32_bf16(a, b1, acc1, 0, 0, 0);
    }

    const int n0   = nodeg0 + (w << 4) + (q << 2);
    const int ocol = (ohalf << 5) + c;
#pragma unroll
    for (int r = 0; r < 4; ++r) {
        int n = n0 + r;
        if (n < NODES) {
            out[(size_t)n * DIM + ocol]      = f2bf(acc0[r]);
            out[(size_t)n * DIM + ocol + 16] = f2bf(acc1[r]);
        }
    }
}

// ---------------------------------------------------------------------------
// pooled[batch[n]] += h[n] (bf16 h, fp32 accum/output). Sorted batch ->
// run-length local accumulation, ~1 atomic per thread-segment.
// ---------------------------------------------------------------------------
__global__ void pool_bf(const unsigned short* __restrict__ h, const int* __restrict__ batch,
                        float* __restrict__ pooled) {
    int f  = threadIdx.x & 63;
    int g4 = threadIdx.x >> 6;
    int n0 = blockIdx.x * 64 + g4 * 16;
    float sum = 0.f;
    int cur = -1;
    for (int k = 0; k < 16; ++k) {
        int n = n0 + k;
        if (n >= NODES) break;
        int bb = batch[n];
        if (bb != cur) {
            if (cur >= 0) atomicAdd(&pooled[cur * DIM + f], sum);
            cur = bb;
            sum = 0.f;
        }
        sum += bf2f(h[(size_t)n * DIM + f]);
    }
    if (cur >= 0) atomicAdd(&pooled[cur * DIM + f], sum);
}

// ---------------------------------------------------------------------------
// out[g][o] = KAN_head(pooled[g]) for 512 graphs, 10 targets (fp32 VALU).
// ---------------------------------------------------------------------------
__global__ __launch_bounds__(64) void head_kernel(const float* __restrict__ pooled,
                                                  const float* __restrict__ bwh,
                                                  const float* __restrict__ swh,
                                                  const float* __restrict__ sch,
                                                  float* __restrict__ out) {
    __shared__ float v[64][65];
    const int t = threadIdx.x;
    const int base = blockIdx.x * 64 * DIM;
#pragma unroll 4
    for (int j = 0; j < 64; ++j) {
        int off = t + j * 64;
        v[off >> 6][off & 63] = pooled[base + off];
    }
    __syncthreads();

    const int g = blockIdx.x * 64 + t;
    float acc[NT];
#pragma unroll
    for (int o = 0; o < NT; ++o) acc[o] = 0.f;

#pragma unroll 1
    for (int i = 0; i < DIM; ++i) {
        float xv = v[t][i];
        float s  = silu(xv);
        float b[8];
        spline_bases(xv, b);
#pragma unroll
        for (int o = 0; o < NT; ++o) {
            float a = fmaf(s, bwh[o * DIM + i], acc[o]);
            float wsc = sch[o * DIM + i];
            const float* sp = swh + (o * DIM + i) * 8;
            float sb = 0.f;
#pragma unroll
            for (int qq = 0; qq < 8; ++qq) sb = fmaf(b[qq], sp[qq], sb);
            acc[o] = fmaf(sb, wsc, a);
        }
    }
#pragma unroll
    for (int o = 0; o < NT; ++o) out[g * NT + o] = acc[o];
}

// ---------------------------------------------------------------------------
extern "C" void kernel_launch(void* const* d_in, const int* in_sizes, int n_in,
                              void* d_out, int out_size, void* d_ws, size_t ws_size,
                              hipStream_t stream) {
    const float* x   = (const float*)d_in[0];
    const int*   ei  = (const int*)d_in[1];
    const int*   bat = (const int*)d_in[2];
    const float* bw0 = (const float*)d_in[3];
    const float* sw0 = (const float*)d_in[4];
    const float* sc0 = (const float*)d_in[5];
    const float* bw1 = (const float*)d_in[6];
    const float* sw1 = (const float*)d_in[7];
    const float* sc1 = (const float*)d_in[8];
    const float* bwh = (const float*)d_in[9];
    const float* swh = (const float*)d_in[10];
    const float* sch = (const float*)d_in[11];
    float* out = (float*)d_out;

    // ---- workspace layout (all sections 16B-aligned) ----
    unsigned short* wt0 = (unsigned short*)d_ws;                 // 36864
    unsigned short* wt1 = wt0 + DIM * KTOT;                      // 36864
    unsigned short* xbf = wt1 + DIM * KTOT;                      // 6.4M
    unsigned short* vbf = xbf + (size_t)NODES * DIM;             // 6.4M
    unsigned short* hbf = vbf + (size_t)NODES * DIM;             // 6.4M
    float* pooled = (float*)(hbf + (size_t)NODES * DIM);         // 32768 f
    int* rowptr   = (int*)(pooled + GRAPHS * DIM);               // 100004 i (padded)
    int* col      = rowptr + NODES + 4;                          // 1200000 i
    int* bcnt     = col + EDGES;                                 // 512 i
    int* bbase    = bcnt + NB;                                   // 512 i
    int* bcur     = bbase + NB;                                  // 512 i
    int2* tmp2    = (int2*)(bcur + NB);                          // 1.2M int2 (9.6MB)

    // weight prep + x -> bf16
    prep_wt2<<<(2 * DIM * KTOT + 255) / 256, 256, 0, stream>>>(
        bw0, sw0, sc0, bw1, sw1, sc1, wt0, wt1);
    conv_bf16<<<(NODES * DIM / 4 + 255) / 256, 256, 0, stream>>>(x, xbf);

    // ---- CSR via bucketed counting sort ----
    hipMemsetAsync(bcnt, 0, NB * sizeof(int), stream);
    const int part_blocks = (EDGES + EPB - 1) / EPB;   // 293
    s1_count<<<part_blocks, 256, 0, stream>>>(ei, bcnt);
    s2_scan<<<1, 512, 0, stream>>>(bcnt, bbase, bcur);
    s3_partition<<<part_blocks, 256, 0, stream>>>(ei, bcur, tmp2);
    s4_fill<<<NB, 256, 0, stream>>>(tmp2, bcnt, bbase, rowptr, col);

    const int agg_blocks = NODES / 32;                  // 3125 (exact)
    const int kan_blocks = 2 * ((NODES + 127) / 128);   // 1564

    // layer 0
    gather_agg_bf<<<agg_blocks, 256, 0, stream>>>(xbf, rowptr, col, vbf);
    kan_layer_mfma<<<kan_blocks, 512, 0, stream>>>(vbf, wt0, hbf);

    // layer 1
    gather_agg_bf<<<agg_blocks, 256, 0, stream>>>(hbf, rowptr, col, vbf);
    kan_layer_mfma<<<kan_blocks, 512, 0, stream>>>(vbf, wt1, hbf);

    // pool + head
    hipMemsetAsync(pooled, 0, (size_t)GRAPHS * DIM * sizeof(float), stream);
    pool_bf<<<(NODES + 63) / 64, 256, 0, stream>>>(hbf, bat, pooled);
    head_kernel<<<GRAPHS / 64, 64, 0, stream>>>(pooled, bwh, swh, sch, out);
}

// Round 6
// 338.936 us; speedup vs baseline: 4.6634x; 1.2128x over previous
//
#include <hip/hip_runtime.h>
#include <math.h>

#define NODES   100000
#define EDGES   1200000
#define GRAPHS  512
#define DIM     64
#define NT      10
#define KTOT    576     // 64 base + 64*8 spline features

#define NB      512     // sort buckets: bucket = dst >> 8 (256 nodes each)
#define EPB     4096    // edges per partition block

#define WT_STRIDE 584   // padded bf16 row stride for W_T in LDS (16B-aligned)
#define V_STRIDE  72    // padded bf16 row stride for v in LDS (16B-aligned)

typedef __attribute__((ext_vector_type(8))) short  frag_ab;  // 8 bf16
typedef __attribute__((ext_vector_type(4))) float  frag_cd;  // 4 fp32 acc

// ---------------------------------------------------------------------------
// Uniform cubic B-spline bases matching the reference Cox-de Boor recursion.
// ---------------------------------------------------------------------------
__device__ __forceinline__ void spline_bases(float x, float* b) {
    float tt  = fmaf(x, 2.5f, 5.5f);
    float fm  = floorf(tt);
    int   m   = (int)fm;
    float u   = tt - fm;
    float um1 = 1.f - u;
    float v3  = u * u * u * (1.f / 6.f);
    float v0  = um1 * um1 * um1 * (1.f / 6.f);
    float B2m1 = 0.5f * ((u + 1.f) * um1 + (2.f - u) * u);
    float v1  = ((u + 2.f) * um1 * um1 * 0.5f + (2.f - u) * B2m1) * (1.f / 3.f);
    float v2  = ((u + 1.f) * B2m1 + (3.f - u) * u * u * 0.5f) * (1.f / 3.f);
    bool inr  = (m >= 0) && (m <= 10);
#pragma unroll
    for (int j = 0; j < 8; ++j) {
        float bv = 0.f;
        bv = (j == m - 3) ? v0 : bv;
        bv = (j == m - 2) ? v1 : bv;
        bv = (j == m - 1) ? v2 : bv;
        bv = (j == m)     ? v3 : bv;
        b[j] = inr ? bv : 0.f;
    }
}

__device__ __forceinline__ float silu(float x) {
    return x / (1.f + __expf(-x));
}

__device__ __forceinline__ unsigned short f2bf(float f) {   // RNE round
    unsigned x = __builtin_bit_cast(unsigned, f);
    x += 0x7fffu + ((x >> 16) & 1u);
    return (unsigned short)(x >> 16);
}

__device__ __forceinline__ float bf2f(unsigned short u) {
    return __builtin_bit_cast(float, ((unsigned)u) << 16);
}

__device__ __forceinline__ frag_ab pack8(const float* f) {
    union { frag_ab v; unsigned short u[8]; } r;
#pragma unroll
    for (int j = 0; j < 8; ++j) r.u[j] = f2bf(f[j]);
    return r.v;
}

// add 8 bf16 (one uint4) into float acc[8]
__device__ __forceinline__ void acc_bf8(float* a, uint4 p) {
    unsigned w0 = p.x, w1 = p.y, w2 = p.z, w3 = p.w;
    a[0] += __builtin_bit_cast(float, w0 << 16);
    a[1] += __builtin_bit_cast(float, w0 & 0xffff0000u);
    a[2] += __builtin_bit_cast(float, w1 << 16);
    a[3] += __builtin_bit_cast(float, w1 & 0xffff0000u);
    a[4] += __builtin_bit_cast(float, w2 << 16);
    a[5] += __builtin_bit_cast(float, w2 & 0xffff0000u);
    a[6] += __builtin_bit_cast(float, w3 << 16);
    a[7] += __builtin_bit_cast(float, w3 & 0xffff0000u);
}

// ---------------------------------------------------------------------------
// Fused weight prep for BOTH layers -> bf16 W_T[o][k].
// ---------------------------------------------------------------------------
__global__ void prep_wt2(const float* __restrict__ bw0, const float* __restrict__ sw0,
                         const float* __restrict__ sc0,
                         const float* __restrict__ bw1, const float* __restrict__ sw1,
                         const float* __restrict__ sc1,
                         unsigned short* __restrict__ wt0,
                         unsigned short* __restrict__ wt1) {
    int idx = blockIdx.x * 256 + threadIdx.x;
    if (idx >= 2 * DIM * KTOT) return;
    int layer = idx >= DIM * KTOT;
    int li = layer ? idx - DIM * KTOT : idx;
    const float* bw = layer ? bw1 : bw0;
    const float* sw = layer ? sw1 : sw0;
    const float* sc = layer ? sc1 : sc0;
    unsigned short* wt = layer ? wt1 : wt0;
    int o = li / KTOT, k = li % KTOT;
    float v;
    if (k < DIM) {
        v = bw[o * DIM + k];
    } else {
        int i = (k - DIM) >> 3, g = (k - DIM) & 7;
        v = sw[(o * DIM + i) * 8 + g] * sc[o * DIM + i];
    }
    wt[li] = f2bf(v);
}

// ---------------------------------------------------------------------------
// x (fp32) -> xbf (bf16), 4 elements per thread.
// ---------------------------------------------------------------------------
__global__ void conv_bf16(const float* __restrict__ x, unsigned short* __restrict__ xb) {
    int i = blockIdx.x * 256 + threadIdx.x;
    if (i >= NODES * DIM / 4) return;
    float4 v = ((const float4*)x)[i];
    unsigned lo = (unsigned)f2bf(v.x) | ((unsigned)f2bf(v.y) << 16);
    unsigned hi = (unsigned)f2bf(v.z) | ((unsigned)f2bf(v.w) << 16);
    ((uint2*)xb)[i] = make_uint2(lo, hi);
}

// ===========================================================================
// Bucketed counting sort of edges by dst -> CSR (rowptr, col).
// ===========================================================================
__global__ __launch_bounds__(256) void s1_count(const int* __restrict__ ei,
                                                int* __restrict__ bcnt) {
    __shared__ int hist[NB];
    int t = threadIdx.x;
    hist[t] = 0; hist[t + 256] = 0;
    __syncthreads();
    int e0 = blockIdx.x * EPB;
#pragma unroll
    for (int k = 0; k < 16; ++k) {
        int e = e0 + t + k * 256;
        if (e < EDGES) atomicAdd(&hist[ei[EDGES + e] >> 8], 1);
    }
    __syncthreads();
    int c0 = hist[t];       if (c0) atomicAdd(&bcnt[t], c0);
    int c1 = hist[t + 256]; if (c1) atomicAdd(&bcnt[t + 256], c1);
}

__global__ __launch_bounds__(512) void s2_scan(const int* __restrict__ bcnt,
                                               int* __restrict__ bbase,
                                               int* __restrict__ bcur) {
    __shared__ int s[NB];
    int t = threadIdx.x;
    int v = bcnt[t];
    s[t] = v;
    __syncthreads();
    int run = v;
    for (int d = 1; d < NB; d <<= 1) {
        int a = (t >= d) ? s[t - d] : 0;
        __syncthreads();
        run += a; s[t] = run;
        __syncthreads();
    }
    int excl = run - v;
    bbase[t] = excl;
    bcur[t]  = excl;
}

__global__ __launch_bounds__(256) void s3_partition(const int* __restrict__ ei,
                                                    int* __restrict__ bcur,
                                                    int2* __restrict__ tmp2) {
    __shared__ int hist[NB], gbase[NB], cur[NB];
    int t = threadIdx.x;
    hist[t] = 0; hist[t + 256] = 0;
    cur[t]  = 0; cur[t + 256]  = 0;
    __syncthreads();
    int e0 = blockIdx.x * EPB;
#pragma unroll
    for (int k = 0; k < 16; ++k) {
        int e = e0 + t + k * 256;
        if (e < EDGES) atomicAdd(&hist[ei[EDGES + e] >> 8], 1);
    }
    __syncthreads();
    {
        int c0 = hist[t];       if (c0) gbase[t]       = atomicAdd(&bcur[t], c0);
        int c1 = hist[t + 256]; if (c1) gbase[t + 256] = atomicAdd(&bcur[t + 256], c1);
    }
    __syncthreads();
#pragma unroll
    for (int k = 0; k < 16; ++k) {
        int e = e0 + t + k * 256;
        if (e < EDGES) {
            int src = ei[e];
            int dst = ei[EDGES + e];
            int b = dst >> 8;
            int slot = atomicAdd(&cur[b], 1);
            tmp2[gbase[b] + slot] = make_int2(src, dst);
        }
    }
}

__global__ __launch_bounds__(256) void s4_fill(const int2* __restrict__ tmp2,
                                               const int* __restrict__ bcnt,
                                               const int* __restrict__ bbase,
                                               int* __restrict__ rowptr,
                                               int* __restrict__ col) {
    __shared__ int hist[256], scan[256];
    int b = blockIdx.x, t = threadIdx.x;
    int cnt = bcnt[b], base = bbase[b];
    hist[t] = 0;
    __syncthreads();
    for (int i = t; i < cnt; i += 256)
        atomicAdd(&hist[tmp2[base + i].y & 255], 1);
    __syncthreads();
    int v = hist[t];
    scan[t] = v;
    __syncthreads();
    int run = v;
    for (int d = 1; d < 256; d <<= 1) {
        int a = (t >= d) ? scan[t - d] : 0;
        __syncthreads();
        run += a; scan[t] = run;
        __syncthreads();
    }
    int excl = run - v;
    int ng = b * 256 + t;
    if (ng <= NODES) rowptr[ng] = base + excl;
    __syncthreads();
    scan[t] = excl;
    __syncthreads();
    for (int i = t; i < cnt; i += 256) {
        int2 p = tmp2[base + i];
        int pos = atomicAdd(&scan[p.y & 255], 1);
        col[base + pos] = p.x;
    }
}

// ---------------------------------------------------------------------------
// v[n] = x[n] + sum_{src in N(n)} x[src], all bf16 rows (128B), fp32 accum.
// ---------------------------------------------------------------------------
__global__ __launch_bounds__(256) void gather_agg_bf(const unsigned short* __restrict__ xbf,
                                                     const int* __restrict__ rowptr,
                                                     const int* __restrict__ col,
                                                     unsigned short* __restrict__ vbf) {
    const int n  = blockIdx.x * 32 + (threadIdx.x >> 3);
    const int fq = threadIdx.x & 7;
    const uint4* x4 = (const uint4*)xbf;
    const int beg = rowptr[n], end = rowptr[n + 1];
    float a0[8], a1[8], a2[8], a3[8];
#pragma unroll
    for (int j = 0; j < 8; ++j) { a0[j] = 0.f; a1[j] = 0.f; a2[j] = 0.f; a3[j] = 0.f; }
    acc_bf8(a0, x4[(size_t)n * 8 + fq]);
    int p = beg;
    for (; p + 3 < end; p += 4) {
        int c0 = col[p], c1 = col[p + 1], c2 = col[p + 2], c3 = col[p + 3];
        uint4 r0 = x4[(size_t)c0 * 8 + fq];
        uint4 r1 = x4[(size_t)c1 * 8 + fq];
        uint4 r2 = x4[(size_t)c2 * 8 + fq];
        uint4 r3 = x4[(size_t)c3 * 8 + fq];
        acc_bf8(a0, r0); acc_bf8(a1, r1); acc_bf8(a2, r2); acc_bf8(a3, r3);
    }
    for (; p < end; ++p) acc_bf8(a0, x4[(size_t)col[p] * 8 + fq]);
    union { uint4 u; unsigned short s[8]; } r;
#pragma unroll
    for (int j = 0; j < 8; ++j) r.s[j] = f2bf(a0[j] + a1[j] + a2[j] + a3[j]);
    ((uint4*)vbf)[(size_t)n * 8 + fq] = r.u;
}

// ---------------------------------------------------------------------------
// MFMA KAN layer: h[n] = KAN(v[n]).  bf16 in, bf16 out.
// ---------------------------------------------------------------------------
__global__ __launch_bounds__(512) void kan_layer_mfma(const unsigned short* __restrict__ vin,
                                                      const unsigned short* __restrict__ wt,
                                                      unsigned short* __restrict__ out) {
    __shared__ unsigned short wt_lds[32 * WT_STRIDE];   // 37376 B
    __shared__ unsigned short v_lds[128 * V_STRIDE];    // 18432 B

    const int t      = threadIdx.x;
    const int grp    = blockIdx.x >> 1;
    const int ohalf  = blockIdx.x & 1;
    const int nodeg0 = grp * 128;

    for (int ci = t; ci < 32 * 72; ci += 512) {
        int o = ci / 72, ch = ci % 72;
        uint4 val = *(const uint4*)(wt + (size_t)(ohalf * 32 + o) * KTOT + ch * 8);
        *(uint4*)(wt_lds + o * WT_STRIDE + ch * 8) = val;
    }
    const uint4* v4 = (const uint4*)vin;
#pragma unroll
    for (int it = 0; it < 2; ++it) {
        int ci = t + it * 512;
        int node = ci >> 3, c8 = ci & 7;
        int gnode = nodeg0 + node;
        uint4 val = make_uint4(0, 0, 0, 0);
        if (gnode < NODES) val = v4[(size_t)gnode * 8 + c8];
        *(uint4*)(v_lds + node * V_STRIDE + c8 * 8) = val;
    }
    __syncthreads();

    const int w  = t >> 6;
    const int l  = t & 63;
    const int q  = l >> 4;
    const int c  = l & 15;
    const unsigned short* vrow = v_lds + ((w << 4) + c) * V_STRIDE;
    const unsigned short* wrow = wt_lds + c * WT_STRIDE;

    frag_cd acc0 = {0.f, 0.f, 0.f, 0.f};
    frag_cd acc1 = {0.f, 0.f, 0.f, 0.f};

#pragma unroll
    for (int s = 0; s < 2; ++s) {
        float f[8];
#pragma unroll
        for (int j = 0; j < 8; ++j) {
            float xv = bf2f(vrow[32 * s + 8 * q + j]);
            f[j] = silu(xv);
        }
        frag_ab a  = pack8(f);
        frag_ab b0 = *(const frag_ab*)(wrow + 32 * s + 8 * q);
        frag_ab b1 = *(const frag_ab*)(wrow + 16 * WT_STRIDE + 32 * s + 8 * q);
        acc0 = __builtin_amdgcn_mfma_f32_16x16x32_bf16(a, b0, acc0, 0, 0, 0);
        acc1 = __builtin_amdgcn_mfma_f32_16x16x32_bf16(a, b1, acc1, 0, 0, 0);
    }

#pragma unroll 1
    for (int s = 2; s < 18; ++s) {
        int i = 4 * s + q - 8;
        float xv = bf2f(vrow[i]);
        float bb[8];
        spline_bases(xv, bb);
        frag_ab a  = pack8(bb);
        frag_ab b0 = *(const frag_ab*)(wrow + 32 * s + 8 * q);
        frag_ab b1 = *(const frag_ab*)(wrow + 16 * WT_STRIDE + 32 * s + 8 * q);
        acc0 = __builtin_amdgcn_mfma_f32_16x16x32_bf16(a, b0, acc0, 0, 0, 0);
        acc1 = __builtin_amdgcn_mfma_f32_16x16x32_bf16(a, b1, acc1, 0, 0, 0);
    }

    const int n0   = nodeg0 + (w << 4) + (q << 2);
    const int ocol = (ohalf << 5) + c;
#pragma unroll
    for (int r = 0; r < 4; ++r) {
        int n = n0 + r;
        if (n < NODES) {
            out[(size_t)n * DIM + ocol]      = f2bf(acc0[r]);
            out[(size_t)n * DIM + ocol + 16] = f2bf(acc1[r]);
        }
    }
}

// ---------------------------------------------------------------------------
// pooled[batch[n]] += h[n] (bf16 h, fp32 accum/output).
// ---------------------------------------------------------------------------
__global__ void pool_bf(const unsigned short* __restrict__ h, const int* __restrict__ batch,
                        float* __restrict__ pooled) {
    int f  = threadIdx.x & 63;
    int g4 = threadIdx.x >> 6;
    int n0 = blockIdx.x * 64 + g4 * 16;
    float sum = 0.f;
    int cur = -1;
    for (int k = 0; k < 16; ++k) {
        int n = n0 + k;
        if (n >= NODES) break;
        int bb = batch[n];
        if (bb != cur) {
            if (cur >= 0) atomicAdd(&pooled[cur * DIM + f], sum);
            cur = bb;
            sum = 0.f;
        }
        sum += bf2f(h[(size_t)n * DIM + f]);
    }
    if (cur >= 0) atomicAdd(&pooled[cur * DIM + f], sum);
}

// ---------------------------------------------------------------------------
// Head: one wave per graph, lane = input dim.  Each lane computes its dim's
// contribution to all 10 outputs, then 10 wave-wide shuffle reductions.
// 512 blocks -> latency hidden by TLP (vs 8 blocks / 0.08% occupancy before).
// ---------------------------------------------------------------------------
__global__ __launch_bounds__(64) void head_kernel(const float* __restrict__ pooled,
                                                  const float* __restrict__ bwh,
                                                  const float* __restrict__ swh,
                                                  const float* __restrict__ sch,
                                                  float* __restrict__ out) {
    const int g = blockIdx.x;
    const int i = threadIdx.x;          // input dim 0..63
    float xv = pooled[g * DIM + i];
    float s  = silu(xv);
    float b[8];
    spline_bases(xv, b);

    float part[NT];
#pragma unroll
    for (int o = 0; o < NT; ++o) {
        const float* sp = swh + (o * DIM + i) * 8;
        float sb = 0.f;
#pragma unroll
        for (int q = 0; q < 8; ++q) sb = fmaf(b[q], sp[q], sb);
        part[o] = fmaf(s, bwh[o * DIM + i], sb * sch[o * DIM + i]);
    }

#pragma unroll
    for (int o = 0; o < NT; ++o) {
        float v = part[o];
#pragma unroll
        for (int off = 32; off > 0; off >>= 1) v += __shfl_down(v, off, 64);
        if (i == 0) out[g * NT + o] = v;
    }
}

// ---------------------------------------------------------------------------
extern "C" void kernel_launch(void* const* d_in, const int* in_sizes, int n_in,
                              void* d_out, int out_size, void* d_ws, size_t ws_size,
                              hipStream_t stream) {
    const float* x   = (const float*)d_in[0];
    const int*   ei  = (const int*)d_in[1];
    const int*   bat = (const int*)d_in[2];
    const float* bw0 = (const float*)d_in[3];
    const float* sw0 = (const float*)d_in[4];
    const float* sc0 = (const float*)d_in[5];
    const float* bw1 = (const float*)d_in[6];
    const float* sw1 = (const float*)d_in[7];
    const float* sc1 = (const float*)d_in[8];
    const float* bwh = (const float*)d_in[9];
    const float* swh = (const float*)d_in[10];
    const float* sch = (const float*)d_in[11];
    float* out = (float*)d_out;

    // ---- workspace layout (all sections 16B-aligned) ----
    unsigned short* wt0 = (unsigned short*)d_ws;                 // 36864
    unsigned short* wt1 = wt0 + DIM * KTOT;                      // 36864
    unsigned short* xbf = wt1 + DIM * KTOT;                      // 6.4M
    unsigned short* vbf = xbf + (size_t)NODES * DIM;             // 6.4M
    unsigned short* hbf = vbf + (size_t)NODES * DIM;             // 6.4M
    float* pooled = (float*)(hbf + (size_t)NODES * DIM);         // 32768 f
    int* rowptr   = (int*)(pooled + GRAPHS * DIM);               // 100004 i
    int* col      = rowptr + NODES + 4;                          // 1200000 i
    int* bcnt     = col + EDGES;                                 // 512 i
    int* bbase    = bcnt + NB;                                   // 512 i
    int* bcur     = bbase + NB;                                  // 512 i
    int2* tmp2    = (int2*)(bcur + NB);                          // 1.2M int2

    prep_wt2<<<(2 * DIM * KTOT + 255) / 256, 256, 0, stream>>>(
        bw0, sw0, sc0, bw1, sw1, sc1, wt0, wt1);
    conv_bf16<<<(NODES * DIM / 4 + 255) / 256, 256, 0, stream>>>(x, xbf);

    // ---- CSR via bucketed counting sort ----
    hipMemsetAsync(bcnt, 0, NB * sizeof(int), stream);
    const int part_blocks = (EDGES + EPB - 1) / EPB;   // 293
    s1_count<<<part_blocks, 256, 0, stream>>>(ei, bcnt);
    s2_scan<<<1, 512, 0, stream>>>(bcnt, bbase, bcur);
    s3_partition<<<part_blocks, 256, 0, stream>>>(ei, bcur, tmp2);
    s4_fill<<<NB, 256, 0, stream>>>(tmp2, bcnt, bbase, rowptr, col);

    const int agg_blocks = NODES / 32;                  // 3125
    const int kan_blocks = 2 * ((NODES + 127) / 128);   // 1564

    // layer 0
    gather_agg_bf<<<agg_blocks, 256, 0, stream>>>(xbf, rowptr, col, vbf);
    kan_layer_mfma<<<kan_blocks, 512, 0, stream>>>(vbf, wt0, hbf);

    // layer 1
    gather_agg_bf<<<agg_blocks, 256, 0, stream>>>(hbf, rowptr, col, vbf);
    kan_layer_mfma<<<kan_blocks, 512, 0, stream>>>(vbf, wt1, hbf);

    // pool + head
    hipMemsetAsync(pooled, 0, (size_t)GRAPHS * DIM * sizeof(float), stream);
    pool_bf<<<(NODES + 63) / 64, 256, 0, stream>>>(hbf, bat, pooled);
    head_kernel<<<GRAPHS, 64, 0, stream>>>(pooled, bwh, swh, sch, out);
}

// Round 7
// 303.820 us; speedup vs baseline: 5.2024x; 1.1156x over previous
//
#include <hip/hip_runtime.h>
#include <math.h>

#define NODES   100000
#define EDGES   1200000
#define GRAPHS  512
#define DIM     64
#define NT      10
#define KTOT    576     // 64 base + 64*8 spline features

#define NB      512     // sort buckets: bucket = dst >> 8 (256 nodes each)
#define EPB     4096    // edges per partition block

#define WTL_STRIDE 296  // shorts per wt_lds row: 288 K-half + 8 pad (16B aligned, banks spread)
#define V_STRIDE   72   // padded bf16 row stride for v in LDS (16B-aligned)

typedef __attribute__((ext_vector_type(8))) short  frag_ab;  // 8 bf16
typedef __attribute__((ext_vector_type(4))) float  frag_cd;  // 4 fp32 acc

__device__ __forceinline__ float silu(float x) {
    return x / (1.f + __expf(-x));
}

__device__ __forceinline__ unsigned short f2bf(float f) {   // RNE round
    unsigned x = __builtin_bit_cast(unsigned, f);
    x += 0x7fffu + ((x >> 16) & 1u);
    return (unsigned short)(x >> 16);
}

__device__ __forceinline__ float bf2f(unsigned short u) {
    return __builtin_bit_cast(float, ((unsigned)u) << 16);
}

// fast bf16 pack (round-to-nearest, ties away): 2 floats -> 1 dword
__device__ __forceinline__ unsigned packbf2(float a, float b) {
    unsigned lo = __builtin_bit_cast(unsigned, a) + 0x8000u;
    unsigned hi = __builtin_bit_cast(unsigned, b) + 0x8000u;
    return (lo >> 16) | (hi & 0xffff0000u);
}

__device__ __forceinline__ frag_ab pack8_fast(const float* f) {
    union { frag_ab v; unsigned u[4]; } r;
#pragma unroll
    for (int j = 0; j < 4; ++j) r.u[j] = packbf2(f[2 * j], f[2 * j + 1]);
    return r.v;
}

// add 8 bf16 (one uint4) into float acc[8]
__device__ __forceinline__ void acc_bf8(float* a, uint4 p) {
    unsigned w0 = p.x, w1 = p.y, w2 = p.z, w3 = p.w;
    a[0] += __builtin_bit_cast(float, w0 << 16);
    a[1] += __builtin_bit_cast(float, w0 & 0xffff0000u);
    a[2] += __builtin_bit_cast(float, w1 << 16);
    a[3] += __builtin_bit_cast(float, w1 & 0xffff0000u);
    a[4] += __builtin_bit_cast(float, w2 << 16);
    a[5] += __builtin_bit_cast(float, w2 & 0xffff0000u);
    a[6] += __builtin_bit_cast(float, w3 << 16);
    a[7] += __builtin_bit_cast(float, w3 & 0xffff0000u);
}

// ---------------------------------------------------------------------------
// Cubic B-spline bases for one dim, directly as a packed bf16x8 A-fragment.
// v0..v3 are the 4 nonzero values; window start p = m-3 is placed by a
// halfword shift (alignbit) + dword selects -- no 8x4 cndmask scatter.
// Out-of-range x falls out of the window automatically (all-zero).
// ---------------------------------------------------------------------------
__device__ __forceinline__ frag_ab bases_frag(float xv) {
    float tt  = fmaf(xv, 2.5f, 5.5f);
    float fm  = floorf(tt);
    int   m   = (int)fm;
    float u   = tt - fm;
    float um1 = 1.f - u;
    float v3  = u * u * u * (1.f / 6.f);
    float v0  = um1 * um1 * um1 * (1.f / 6.f);
    float B2m1 = 0.5f * ((u + 1.f) * um1 + (2.f - u) * u);
    float v1  = ((u + 2.f) * um1 * um1 * 0.5f + (2.f - u) * B2m1) * (1.f / 3.f);
    float v2  = ((u + 1.f) * B2m1 + (3.f - u) * u * u * 0.5f) * (1.f / 3.f);

    unsigned d0 = packbf2(v0, v1);
    unsigned d1 = packbf2(v2, v3);
    int p = m - 3;           // window start slot, in [-3,7] for in-range x
    int B = p >> 1;          // floor(p/2)
    bool odd = (p & 1) != 0;
    unsigned e1 = __builtin_amdgcn_alignbit(d1, d0, 16);   // [v1,v2]
    unsigned W0 = odd ? (d0 << 16) : d0;                   // [.,v0] / [v0,v1]
    unsigned W1 = odd ? e1 : d1;                           // [v1,v2] / [v2,v3]
    unsigned W2 = odd ? (d1 >> 16) : 0u;                   // [v3,0] / 0
    union { frag_ab f; unsigned u[4]; } r;
    r.u[0] = (B == 0) ? W0 : ((B == -1) ? W1 : ((B == -2) ? W2 : 0u));
    r.u[1] = (B == 1) ? W0 : ((B ==  0) ? W1 : ((B == -1) ? W2 : 0u));
    r.u[2] = (B == 2) ? W0 : ((B ==  1) ? W1 : ((B ==  0) ? W2 : 0u));
    r.u[3] = (B == 3) ? W0 : ((B ==  2) ? W1 : ((B ==  1) ? W2 : 0u));
    return r.f;
}

// ---------------------------------------------------------------------------
// Fused weight prep for BOTH layers -> bf16 W_T[o][k].
// ---------------------------------------------------------------------------
__global__ void prep_wt2(const float* __restrict__ bw0, const float* __restrict__ sw0,
                         const float* __restrict__ sc0,
                         const float* __restrict__ bw1, const float* __restrict__ sw1,
                         const float* __restrict__ sc1,
                         unsigned short* __restrict__ wt0,
                         unsigned short* __restrict__ wt1) {
    int idx = blockIdx.x * 256 + threadIdx.x;
    if (idx >= 2 * DIM * KTOT) return;
    int layer = idx >= DIM * KTOT;
    int li = layer ? idx - DIM * KTOT : idx;
    const float* bw = layer ? bw1 : bw0;
    const float* sw = layer ? sw1 : sw0;
    const float* sc = layer ? sc1 : sc0;
    unsigned short* wt = layer ? wt1 : wt0;
    int o = li / KTOT, k = li % KTOT;
    float v;
    if (k < DIM) {
        v = bw[o * DIM + k];
    } else {
        int i = (k - DIM) >> 3, g = (k - DIM) & 7;
        v = sw[(o * DIM + i) * 8 + g] * sc[o * DIM + i];
    }
    wt[li] = f2bf(v);
}

// ---------------------------------------------------------------------------
// x (fp32) -> xbf (bf16), 4 elements per thread.
// ---------------------------------------------------------------------------
__global__ void conv_bf16(const float* __restrict__ x, unsigned short* __restrict__ xb) {
    int i = blockIdx.x * 256 + threadIdx.x;
    if (i >= NODES * DIM / 4) return;
    float4 v = ((const float4*)x)[i];
    unsigned lo = (unsigned)f2bf(v.x) | ((unsigned)f2bf(v.y) << 16);
    unsigned hi = (unsigned)f2bf(v.z) | ((unsigned)f2bf(v.w) << 16);
    ((uint2*)xb)[i] = make_uint2(lo, hi);
}

// ===========================================================================
// Bucketed counting sort of edges by dst -> CSR (rowptr, col).
// ===========================================================================
__global__ __launch_bounds__(256) void s1_count(const int* __restrict__ ei,
                                                int* __restrict__ bcnt) {
    __shared__ int hist[NB];
    int t = threadIdx.x;
    hist[t] = 0; hist[t + 256] = 0;
    __syncthreads();
    int e0 = blockIdx.x * EPB;
#pragma unroll
    for (int k = 0; k < 16; ++k) {
        int e = e0 + t + k * 256;
        if (e < EDGES) atomicAdd(&hist[ei[EDGES + e] >> 8], 1);
    }
    __syncthreads();
    int c0 = hist[t];       if (c0) atomicAdd(&bcnt[t], c0);
    int c1 = hist[t + 256]; if (c1) atomicAdd(&bcnt[t + 256], c1);
}

__global__ __launch_bounds__(512) void s2_scan(const int* __restrict__ bcnt,
                                               int* __restrict__ bbase,
                                               int* __restrict__ bcur) {
    __shared__ int s[NB];
    int t = threadIdx.x;
    int v = bcnt[t];
    s[t] = v;
    __syncthreads();
    int run = v;
    for (int d = 1; d < NB; d <<= 1) {
        int a = (t >= d) ? s[t - d] : 0;
        __syncthreads();
        run += a; s[t] = run;
        __syncthreads();
    }
    int excl = run - v;
    bbase[t] = excl;
    bcur[t]  = excl;
}

__global__ __launch_bounds__(256) void s3_partition(const int* __restrict__ ei,
                                                    int* __restrict__ bcur,
                                                    int2* __restrict__ tmp2) {
    __shared__ int hist[NB], gbase[NB], cur[NB];
    int t = threadIdx.x;
    hist[t] = 0; hist[t + 256] = 0;
    cur[t]  = 0; cur[t + 256]  = 0;
    __syncthreads();
    int e0 = blockIdx.x * EPB;
#pragma unroll
    for (int k = 0; k < 16; ++k) {
        int e = e0 + t + k * 256;
        if (e < EDGES) atomicAdd(&hist[ei[EDGES + e] >> 8], 1);
    }
    __syncthreads();
    {
        int c0 = hist[t];       if (c0) gbase[t]       = atomicAdd(&bcur[t], c0);
        int c1 = hist[t + 256]; if (c1) gbase[t + 256] = atomicAdd(&bcur[t + 256], c1);
    }
    __syncthreads();
#pragma unroll
    for (int k = 0; k < 16; ++k) {
        int e = e0 + t + k * 256;
        if (e < EDGES) {
            int src = ei[e];
            int dst = ei[EDGES + e];
            int b = dst >> 8;
            int slot = atomicAdd(&cur[b], 1);
            tmp2[gbase[b] + slot] = make_int2(src, dst);
        }
    }
}

__global__ __launch_bounds__(256) void s4_fill(const int2* __restrict__ tmp2,
                                               const int* __restrict__ bcnt,
                                               const int* __restrict__ bbase,
                                               int* __restrict__ rowptr,
                                               int* __restrict__ col) {
    __shared__ int hist[256], scan[256];
    int b = blockIdx.x, t = threadIdx.x;
    int cnt = bcnt[b], base = bbase[b];
    hist[t] = 0;
    __syncthreads();
    for (int i = t; i < cnt; i += 256)
        atomicAdd(&hist[tmp2[base + i].y & 255], 1);
    __syncthreads();
    int v = hist[t];
    scan[t] = v;
    __syncthreads();
    int run = v;
    for (int d = 1; d < 256; d <<= 1) {
        int a = (t >= d) ? scan[t - d] : 0;
        __syncthreads();
        run += a; scan[t] = run;
        __syncthreads();
    }
    int excl = run - v;
    int ng = b * 256 + t;
    if (ng <= NODES) rowptr[ng] = base + excl;
    __syncthreads();
    scan[t] = excl;
    __syncthreads();
    for (int i = t; i < cnt; i += 256) {
        int2 p = tmp2[base + i];
        int pos = atomicAdd(&scan[p.y & 255], 1);
        col[base + pos] = p.x;
    }
}

// ===========================================================================
// Fused GIN layer: gather (x[n] + sum neighbors) -> LDS, then MFMA KAN with
// all 64 outputs per block.  W_T is staged by K-halves (k<288, then k>=288)
// so each (node,dim) basis expansion happens exactly once.
// Block: 256 threads = 4 waves, 64 nodes.  LDS 47.1 KB -> 3 blocks/CU;
// gather latency of one block overlaps expansion VALU of its neighbors.
// ===========================================================================
__global__ __launch_bounds__(256) void fused_layer(const unsigned short* __restrict__ xin,
                                                   const int* __restrict__ rowptr,
                                                   const int* __restrict__ col,
                                                   const unsigned short* __restrict__ wt,
                                                   unsigned short* __restrict__ out) {
    __shared__ unsigned short wt_lds[64 * WTL_STRIDE];  // 37888 B
    __shared__ unsigned short v_lds[64 * V_STRIDE];     //  9216 B

    const int t     = threadIdx.x;
    const int nbase = blockIdx.x * 64;

    // ---- stage W_T K-half 0 (k = 0..287 of all 64 rows) ----
    for (int ci = t; ci < 64 * 36; ci += 256) {
        int o = ci / 36, ch = ci - o * 36;
        *(uint4*)(wt_lds + o * WTL_STRIDE + ch * 8) =
            *(const uint4*)(wt + o * KTOT + ch * 8);
    }

    // ---- fused gather: v[node] = x[node] + sum_{src} x[src], bf16 -> LDS ----
    const uint4* x4 = (const uint4*)xin;
#pragma unroll
    for (int rd = 0; rd < 2; ++rd) {
        int idx  = t + rd * 256;
        int node = idx >> 3, c8 = idx & 7;
        int n = nbase + node;
        union { uint4 u; unsigned short s[8]; } r;
        if (n < NODES) {
            int beg = rowptr[n], end = rowptr[n + 1];
            float a0[8], a1[8], a2[8], a3[8];
#pragma unroll
            for (int j = 0; j < 8; ++j) { a0[j] = 0.f; a1[j] = 0.f; a2[j] = 0.f; a3[j] = 0.f; }
            acc_bf8(a0, x4[(size_t)n * 8 + c8]);
            int p = beg;
            for (; p + 3 < end; p += 4) {
                int c0 = col[p], c1 = col[p + 1], c2 = col[p + 2], c3 = col[p + 3];
                uint4 r0 = x4[(size_t)c0 * 8 + c8];
                uint4 r1 = x4[(size_t)c1 * 8 + c8];
                uint4 r2 = x4[(size_t)c2 * 8 + c8];
                uint4 r3 = x4[(size_t)c3 * 8 + c8];
                acc_bf8(a0, r0); acc_bf8(a1, r1); acc_bf8(a2, r2); acc_bf8(a3, r3);
            }
            for (; p < end; ++p) acc_bf8(a0, x4[(size_t)col[p] * 8 + c8]);
#pragma unroll
            for (int j = 0; j < 8; ++j) r.s[j] = f2bf(a0[j] + a1[j] + a2[j] + a3[j]);
        } else {
            r.u = make_uint4(0, 0, 0, 0);
        }
        *(uint4*)(v_lds + node * V_STRIDE + c8 * 8) = r.u;
    }
    __syncthreads();

    // ---- MFMA phase ----
    const int w = t >> 6;            // wave 0..3 -> nodes 16w..16w+15
    const int l = t & 63;
    const int q = l >> 4;            // k-quad
    const int c = l & 15;            // A row (node) / B row (output)
    const unsigned short* vrow = v_lds + ((w << 4) + c) * V_STRIDE;

    frag_cd ac0 = {0.f, 0.f, 0.f, 0.f};
    frag_cd ac1 = {0.f, 0.f, 0.f, 0.f};
    frag_cd ac2 = {0.f, 0.f, 0.f, 0.f};
    frag_cd ac3 = {0.f, 0.f, 0.f, 0.f};

#define MSTEP(OFF, A) {                                                          \
        frag_ab b0 = *(const frag_ab*)(wt_lds + (c     ) * WTL_STRIDE + (OFF));  \
        frag_ab b1 = *(const frag_ab*)(wt_lds + (c + 16) * WTL_STRIDE + (OFF));  \
        frag_ab b2 = *(const frag_ab*)(wt_lds + (c + 32) * WTL_STRIDE + (OFF));  \
        frag_ab b3 = *(const frag_ab*)(wt_lds + (c + 48) * WTL_STRIDE + (OFF));  \
        ac0 = __builtin_amdgcn_mfma_f32_16x16x32_bf16(A, b0, ac0, 0, 0, 0);      \
        ac1 = __builtin_amdgcn_mfma_f32_16x16x32_bf16(A, b1, ac1, 0, 0, 0);      \
        ac2 = __builtin_amdgcn_mfma_f32_16x16x32_bf16(A, b2, ac2, 0, 0, 0);      \
        ac3 = __builtin_amdgcn_mfma_f32_16x16x32_bf16(A, b3, ac3, 0, 0, 0); }

    // K-half 0: base branch (s=0,1) + spline s=2..8
#pragma unroll
    for (int s = 0; s < 2; ++s) {
        float f[8];
#pragma unroll
        for (int j = 0; j < 8; ++j) f[j] = silu(bf2f(vrow[32 * s + 8 * q + j]));
        frag_ab a = pack8_fast(f);
        MSTEP(32 * s + 8 * q, a);
    }
#pragma unroll 1
    for (int s = 2; s < 9; ++s) {
        frag_ab a = bases_frag(bf2f(vrow[4 * s + q - 8]));
        MSTEP(32 * s + 8 * q, a);
    }
    __syncthreads();

    // restage K-half 1 (k = 288..575)
    for (int ci = t; ci < 64 * 36; ci += 256) {
        int o = ci / 36, ch = ci - o * 36;
        *(uint4*)(wt_lds + o * WTL_STRIDE + ch * 8) =
            *(const uint4*)(wt + o * KTOT + 288 + ch * 8);
    }
    __syncthreads();

#pragma unroll 1
    for (int s = 9; s < 18; ++s) {
        frag_ab a = bases_frag(bf2f(vrow[4 * s + q - 8]));
        MSTEP(32 * s + 8 * q - 288, a);
    }
#undef MSTEP

    // ---- store: C/D rows = nodes (q*4+r), cols = c + 16*acc ----
    const int n0 = nbase + (w << 4) + (q << 2);
#pragma unroll
    for (int r = 0; r < 4; ++r) {
        int n = n0 + r;
        if (n < NODES) {
            unsigned short* o = out + (size_t)n * DIM + c;
            o[0]  = f2bf(ac0[r]);
            o[16] = f2bf(ac1[r]);
            o[32] = f2bf(ac2[r]);
            o[48] = f2bf(ac3[r]);
        }
    }
}

// ---------------------------------------------------------------------------
// pooled[batch[n]] += h[n] (bf16 h, fp32 accum/output).
// ---------------------------------------------------------------------------
__global__ void pool_bf(const unsigned short* __restrict__ h, const int* __restrict__ batch,
                        float* __restrict__ pooled) {
    int f  = threadIdx.x & 63;
    int g4 = threadIdx.x >> 6;
    int n0 = blockIdx.x * 64 + g4 * 16;
    float sum = 0.f;
    int cur = -1;
    for (int k = 0; k < 16; ++k) {
        int n = n0 + k;
        if (n >= NODES) break;
        int bb = batch[n];
        if (bb != cur) {
            if (cur >= 0) atomicAdd(&pooled[cur * DIM + f], sum);
            cur = bb;
            sum = 0.f;
        }
        sum += bf2f(h[(size_t)n * DIM + f]);
    }
    if (cur >= 0) atomicAdd(&pooled[cur * DIM + f], sum);
}

// ---------------------------------------------------------------------------
// Head: one wave per graph, lane = input dim; 10 wave-wide shuffle reductions.
// ---------------------------------------------------------------------------
__global__ __launch_bounds__(64) void head_kernel(const float* __restrict__ pooled,
                                                  const float* __restrict__ bwh,
                                                  const float* __restrict__ swh,
                                                  const float* __restrict__ sch,
                                                  float* __restrict__ out) {
    const int g = blockIdx.x;
    const int i = threadIdx.x;
    float xv = pooled[g * DIM + i];
    float s  = silu(xv);

    // full-precision bases for the head (fp32 path, matches reference closely)
    float tt  = fmaf(xv, 2.5f, 5.5f);
    float fm  = floorf(tt);
    int   m   = (int)fm;
    float u   = tt - fm;
    float um1 = 1.f - u;
    float v3  = u * u * u * (1.f / 6.f);
    float v0  = um1 * um1 * um1 * (1.f / 6.f);
    float B2m1 = 0.5f * ((u + 1.f) * um1 + (2.f - u) * u);
    float v1  = ((u + 2.f) * um1 * um1 * 0.5f + (2.f - u) * B2m1) * (1.f / 3.f);
    float v2  = ((u + 1.f) * B2m1 + (3.f - u) * u * u * 0.5f) * (1.f / 3.f);
    bool inr  = (m >= 0) && (m <= 10);
    float b[8];
#pragma unroll
    for (int j = 0; j < 8; ++j) {
        float bv = 0.f;
        bv = (j == m - 3) ? v0 : bv;
        bv = (j == m - 2) ? v1 : bv;
        bv = (j == m - 1) ? v2 : bv;
        bv = (j == m)     ? v3 : bv;
        b[j] = inr ? bv : 0.f;
    }

    float part[NT];
#pragma unroll
    for (int o = 0; o < NT; ++o) {
        const float* sp = swh + (o * DIM + i) * 8;
        float sb = 0.f;
#pragma unroll
        for (int qq = 0; qq < 8; ++qq) sb = fmaf(b[qq], sp[qq], sb);
        part[o] = fmaf(s, bwh[o * DIM + i], sb * sch[o * DIM + i]);
    }

#pragma unroll
    for (int o = 0; o < NT; ++o) {
        float v = part[o];
#pragma unroll
        for (int off = 32; off > 0; off >>= 1) v += __shfl_down(v, off, 64);
        if (i == 0) out[g * NT + o] = v;
    }
}

// ---------------------------------------------------------------------------
extern "C" void kernel_launch(void* const* d_in, const int* in_sizes, int n_in,
                              void* d_out, int out_size, void* d_ws, size_t ws_size,
                              hipStream_t stream) {
    const float* x   = (const float*)d_in[0];
    const int*   ei  = (const int*)d_in[1];
    const int*   bat = (const int*)d_in[2];
    const float* bw0 = (const float*)d_in[3];
    const float* sw0 = (const float*)d_in[4];
    const float* sc0 = (const float*)d_in[5];
    const float* bw1 = (const float*)d_in[6];
    const float* sw1 = (const float*)d_in[7];
    const float* sc1 = (const float*)d_in[8];
    const float* bwh = (const float*)d_in[9];
    const float* swh = (const float*)d_in[10];
    const float* sch = (const float*)d_in[11];
    float* out = (float*)d_out;

    // ---- workspace layout (all sections 16B-aligned) ----
    unsigned short* wt0 = (unsigned short*)d_ws;                 // 36864
    unsigned short* wt1 = wt0 + DIM * KTOT;                      // 36864
    unsigned short* xbf = wt1 + DIM * KTOT;                      // 6.4M
    unsigned short* hbf = xbf + (size_t)NODES * DIM;             // 6.4M (layer0 out)
    unsigned short* h2  = hbf + (size_t)NODES * DIM;             // 6.4M (layer1 out)
    float* pooled = (float*)(h2 + (size_t)NODES * DIM);          // 32768 f
    int* rowptr   = (int*)(pooled + GRAPHS * DIM);               // 100004 i
    int* col      = rowptr + NODES + 4;                          // 1200000 i
    int* bcnt     = col + EDGES;                                 // 512 i
    int* bbase    = bcnt + NB;                                   // 512 i
    int* bcur     = bbase + NB;                                  // 512 i
    int2* tmp2    = (int2*)(bcur + NB);                          // 1.2M int2

    prep_wt2<<<(2 * DIM * KTOT + 255) / 256, 256, 0, stream>>>(
        bw0, sw0, sc0, bw1, sw1, sc1, wt0, wt1);
    conv_bf16<<<(NODES * DIM / 4 + 255) / 256, 256, 0, stream>>>(x, xbf);

    // ---- CSR via bucketed counting sort ----
    hipMemsetAsync(bcnt, 0, NB * sizeof(int), stream);
    const int part_blocks = (EDGES + EPB - 1) / EPB;   // 293
    s1_count<<<part_blocks, 256, 0, stream>>>(ei, bcnt);
    s2_scan<<<1, 512, 0, stream>>>(bcnt, bbase, bcur);
    s3_partition<<<part_blocks, 256, 0, stream>>>(ei, bcur, tmp2);
    s4_fill<<<NB, 256, 0, stream>>>(tmp2, bcnt, bbase, rowptr, col);

    const int layer_blocks = (NODES + 63) / 64;        // 1563

    fused_layer<<<layer_blocks, 256, 0, stream>>>(xbf, rowptr, col, wt0, hbf);
    fused_layer<<<layer_blocks, 256, 0, stream>>>(hbf, rowptr, col, wt1, h2);

    hipMemsetAsync(pooled, 0, (size_t)GRAPHS * DIM * sizeof(float), stream);
    pool_bf<<<(NODES + 63) / 64, 256, 0, stream>>>(h2, bat, pooled);
    head_kernel<<<GRAPHS, 64, 0, stream>>>(pooled, bwh, swh, sch, out);
}

// Round 8
// 280.151 us; speedup vs baseline: 5.6420x; 1.0845x over previous
//
#include <hip/hip_runtime.h>
#include <math.h>

#define NODES   100000
#define EDGES   1200000
#define GRAPHS  512
#define DIM     64
#define NT      10
#define KTOT    576     // 64 base + 64*8 spline features

#define NB      512     // sort buckets: bucket = dst >> 8 (256 nodes each)
#define EPB     4096    // edges per partition block

// K-chunked weight staging: 6 stages x 96 k-values (3 MFMA steps each)
#define KSTAGE     96
#define WTL_STRIDE 104  // 96 shorts + 8 pad (16B aligned; 2-way banks only)
#define V_STRIDE   72   // padded bf16 row stride for v in LDS (16B-aligned)

typedef __attribute__((ext_vector_type(8))) short  frag_ab;  // 8 bf16
typedef __attribute__((ext_vector_type(4))) float  frag_cd;  // 4 fp32 acc

__device__ __forceinline__ float silu(float x) {
    return x / (1.f + __expf(-x));
}

__device__ __forceinline__ unsigned short f2bf(float f) {   // RNE round
    unsigned x = __builtin_bit_cast(unsigned, f);
    x += 0x7fffu + ((x >> 16) & 1u);
    return (unsigned short)(x >> 16);
}

__device__ __forceinline__ float bf2f(unsigned short u) {
    return __builtin_bit_cast(float, ((unsigned)u) << 16);
}

// fast bf16 pack: 2 floats -> 1 dword
__device__ __forceinline__ unsigned packbf2(float a, float b) {
    unsigned lo = __builtin_bit_cast(unsigned, a) + 0x8000u;
    unsigned hi = __builtin_bit_cast(unsigned, b) + 0x8000u;
    return (lo >> 16) | (hi & 0xffff0000u);
}

__device__ __forceinline__ frag_ab pack8_fast(const float* f) {
    union { frag_ab v; unsigned u[4]; } r;
#pragma unroll
    for (int j = 0; j < 4; ++j) r.u[j] = packbf2(f[2 * j], f[2 * j + 1]);
    return r.v;
}

// add 8 bf16 (one uint4) into float acc[8]
__device__ __forceinline__ void acc_bf8(float* a, uint4 p) {
    unsigned w0 = p.x, w1 = p.y, w2 = p.z, w3 = p.w;
    a[0] += __builtin_bit_cast(float, w0 << 16);
    a[1] += __builtin_bit_cast(float, w0 & 0xffff0000u);
    a[2] += __builtin_bit_cast(float, w1 << 16);
    a[3] += __builtin_bit_cast(float, w1 & 0xffff0000u);
    a[4] += __builtin_bit_cast(float, w2 << 16);
    a[5] += __builtin_bit_cast(float, w2 & 0xffff0000u);
    a[6] += __builtin_bit_cast(float, w3 << 16);
    a[7] += __builtin_bit_cast(float, w3 & 0xffff0000u);
}

// ---------------------------------------------------------------------------
// Cubic B-spline bases for one dim as a packed bf16x8 A-fragment (window
// placement via alignbit + dword selects; out-of-range -> all zero).
// ---------------------------------------------------------------------------
__device__ __forceinline__ frag_ab bases_frag(float xv) {
    float tt  = fmaf(xv, 2.5f, 5.5f);
    float fm  = floorf(tt);
    int   m   = (int)fm;
    float u   = tt - fm;
    float um1 = 1.f - u;
    float v3  = u * u * u * (1.f / 6.f);
    float v0  = um1 * um1 * um1 * (1.f / 6.f);
    float B2m1 = 0.5f * ((u + 1.f) * um1 + (2.f - u) * u);
    float v1  = ((u + 2.f) * um1 * um1 * 0.5f + (2.f - u) * B2m1) * (1.f / 3.f);
    float v2  = ((u + 1.f) * B2m1 + (3.f - u) * u * u * 0.5f) * (1.f / 3.f);

    unsigned d0 = packbf2(v0, v1);
    unsigned d1 = packbf2(v2, v3);
    int p = m - 3;
    int B = p >> 1;
    bool odd = (p & 1) != 0;
    unsigned e1 = __builtin_amdgcn_alignbit(d1, d0, 16);   // [v1,v2]
    unsigned W0 = odd ? (d0 << 16) : d0;
    unsigned W1 = odd ? e1 : d1;
    unsigned W2 = odd ? (d1 >> 16) : 0u;
    union { frag_ab f; unsigned u[4]; } r;
    r.u[0] = (B == 0) ? W0 : ((B == -1) ? W1 : ((B == -2) ? W2 : 0u));
    r.u[1] = (B == 1) ? W0 : ((B ==  0) ? W1 : ((B == -1) ? W2 : 0u));
    r.u[2] = (B == 2) ? W0 : ((B ==  1) ? W1 : ((B ==  0) ? W2 : 0u));
    r.u[3] = (B == 3) ? W0 : ((B ==  2) ? W1 : ((B ==  1) ? W2 : 0u));
    return r.f;
}

// ---------------------------------------------------------------------------
// Fused weight prep for BOTH layers -> bf16 W_T[o][k].
// ---------------------------------------------------------------------------
__global__ void prep_wt2(const float* __restrict__ bw0, const float* __restrict__ sw0,
                         const float* __restrict__ sc0,
                         const float* __restrict__ bw1, const float* __restrict__ sw1,
                         const float* __restrict__ sc1,
                         unsigned short* __restrict__ wt0,
                         unsigned short* __restrict__ wt1) {
    int idx = blockIdx.x * 256 + threadIdx.x;
    if (idx >= 2 * DIM * KTOT) return;
    int layer = idx >= DIM * KTOT;
    int li = layer ? idx - DIM * KTOT : idx;
    const float* bw = layer ? bw1 : bw0;
    const float* sw = layer ? sw1 : sw0;
    const float* sc = layer ? sc1 : sc0;
    unsigned short* wt = layer ? wt1 : wt0;
    int o = li / KTOT, k = li % KTOT;
    float v;
    if (k < DIM) {
        v = bw[o * DIM + k];
    } else {
        int i = (k - DIM) >> 3, g = (k - DIM) & 7;
        v = sw[(o * DIM + i) * 8 + g] * sc[o * DIM + i];
    }
    wt[li] = f2bf(v);
}

// ---------------------------------------------------------------------------
// x (fp32) -> xbf (bf16), 4 elements per thread.
// ---------------------------------------------------------------------------
__global__ void conv_bf16(const float* __restrict__ x, unsigned short* __restrict__ xb) {
    int i = blockIdx.x * 256 + threadIdx.x;
    if (i >= NODES * DIM / 4) return;
    float4 v = ((const float4*)x)[i];
    unsigned lo = (unsigned)f2bf(v.x) | ((unsigned)f2bf(v.y) << 16);
    unsigned hi = (unsigned)f2bf(v.z) | ((unsigned)f2bf(v.w) << 16);
    ((uint2*)xb)[i] = make_uint2(lo, hi);
}

// ===========================================================================
// Bucketed counting sort of edges by dst -> CSR (rowptr, col).
// tmp entries are packed: src (bits 0..16) | dst&255 (bits 24..31).
// ===========================================================================
__global__ __launch_bounds__(256) void s1_count(const int* __restrict__ ei,
                                                int* __restrict__ bcnt) {
    __shared__ int hist[NB];
    int t = threadIdx.x;
    hist[t] = 0; hist[t + 256] = 0;
    __syncthreads();
    int e0 = blockIdx.x * EPB;
#pragma unroll
    for (int k = 0; k < 16; ++k) {
        int e = e0 + t + k * 256;
        if (e < EDGES) atomicAdd(&hist[ei[EDGES + e] >> 8], 1);
    }
    __syncthreads();
    int c0 = hist[t];       if (c0) atomicAdd(&bcnt[t], c0);
    int c1 = hist[t + 256]; if (c1) atomicAdd(&bcnt[t + 256], c1);
}

__global__ __launch_bounds__(512) void s2_scan(const int* __restrict__ bcnt,
                                               int* __restrict__ bbase,
                                               int* __restrict__ bcur) {
    __shared__ int s[NB];
    int t = threadIdx.x;
    int v = bcnt[t];
    s[t] = v;
    __syncthreads();
    int run = v;
    for (int d = 1; d < NB; d <<= 1) {
        int a = (t >= d) ? s[t - d] : 0;
        __syncthreads();
        run += a; s[t] = run;
        __syncthreads();
    }
    int excl = run - v;
    bbase[t] = excl;
    bcur[t]  = excl;
}

__global__ __launch_bounds__(256) void s3_partition(const int* __restrict__ ei,
                                                    int* __restrict__ bcur,
                                                    unsigned* __restrict__ tmp) {
    __shared__ int hist[NB], gbase[NB], cur[NB];
    int t = threadIdx.x;
    hist[t] = 0; hist[t + 256] = 0;
    cur[t]  = 0; cur[t + 256]  = 0;
    __syncthreads();
    int e0 = blockIdx.x * EPB;
#pragma unroll
    for (int k = 0; k < 16; ++k) {
        int e = e0 + t + k * 256;
        if (e < EDGES) atomicAdd(&hist[ei[EDGES + e] >> 8], 1);
    }
    __syncthreads();
    {
        int c0 = hist[t];       if (c0) gbase[t]       = atomicAdd(&bcur[t], c0);
        int c1 = hist[t + 256]; if (c1) gbase[t + 256] = atomicAdd(&bcur[t + 256], c1);
    }
    __syncthreads();
#pragma unroll
    for (int k = 0; k < 16; ++k) {
        int e = e0 + t + k * 256;
        if (e < EDGES) {
            unsigned src = (unsigned)ei[e];
            int dst = ei[EDGES + e];
            int b = dst >> 8;
            int slot = atomicAdd(&cur[b], 1);
            tmp[gbase[b] + slot] = src | ((unsigned)(dst & 255) << 24);
        }
    }
}

__global__ __launch_bounds__(256) void s4_fill(const unsigned* __restrict__ tmp,
                                               const int* __restrict__ bcnt,
                                               const int* __restrict__ bbase,
                                               int* __restrict__ rowptr,
                                               int* __restrict__ col) {
    __shared__ int hist[256], scan[256];
    int b = blockIdx.x, t = threadIdx.x;
    int cnt = bcnt[b], base = bbase[b];
    hist[t] = 0;
    __syncthreads();
    for (int i = t; i < cnt; i += 256)
        atomicAdd(&hist[tmp[base + i] >> 24], 1);
    __syncthreads();
    int v = hist[t];
    scan[t] = v;
    __syncthreads();
    int run = v;
    for (int d = 1; d < 256; d <<= 1) {
        int a = (t >= d) ? scan[t - d] : 0;
        __syncthreads();
        run += a; scan[t] = run;
        __syncthreads();
    }
    int excl = run - v;
    int ng = b * 256 + t;
    if (ng <= NODES) rowptr[ng] = base + excl;
    __syncthreads();
    scan[t] = excl;
    __syncthreads();
    for (int i = t; i < cnt; i += 256) {
        unsigned p = tmp[base + i];
        int pos = atomicAdd(&scan[p >> 24], 1);
        col[base + pos] = (int)(p & 0xFFFFFFu);
    }
}

// ===========================================================================
// Fused GIN layer: branchless gather -> LDS, then MFMA KAN (all 64 outputs).
// W_T staged in 6 K-chunks of 96 -> LDS 22.5 KB -> 7 blocks/CU (28 waves/CU).
// xin must have a zero row at index NODES (branchless gather padding).
// ===========================================================================
__global__ __launch_bounds__(256) void fused_layer(const unsigned short* __restrict__ xin,
                                                   const int* __restrict__ rowptr,
                                                   const int* __restrict__ col,
                                                   const unsigned short* __restrict__ wt,
                                                   unsigned short* __restrict__ out) {
    __shared__ unsigned short wt_lds[64 * WTL_STRIDE];  // 13312 B
    __shared__ unsigned short v_lds[64 * V_STRIDE];     //  9216 B

    const int t     = threadIdx.x;
    const int nbase = blockIdx.x * 64;

    // ---- stage W_T chunk 0 (k = 0..95) ----
    for (int ci = t; ci < 64 * 12; ci += 256) {
        int o = ci / 12, ch = ci - o * 12;
        *(uint4*)(wt_lds + o * WTL_STRIDE + ch * 8) =
            *(const uint4*)(wt + o * KTOT + ch * 8);
    }

    // ---- fused gather: v[node] = x[node] + sum_{src} x[src] (branchless) ----
    const uint4* x4 = (const uint4*)xin;
#pragma unroll
    for (int rd = 0; rd < 2; ++rd) {
        int idx  = t + rd * 256;
        int node = idx >> 3, c8 = idx & 7;
        int n = nbase + node;
        union { uint4 u; unsigned short s[8]; } r;
        if (n < NODES) {
            int beg = rowptr[n], end = rowptr[n + 1];
            float a0[8], a1[8], a2[8], a3[8];
#pragma unroll
            for (int j = 0; j < 8; ++j) { a0[j] = 0.f; a1[j] = 0.f; a2[j] = 0.f; a3[j] = 0.f; }
            acc_bf8(a0, x4[(size_t)n * 8 + c8]);
            for (int p = beg; p < end; p += 4) {
                int c0 = col[p];                                   // always valid
                int c1 = (p + 1 < end) ? col[p + 1] : NODES;       // zero row
                int c2 = (p + 2 < end) ? col[p + 2] : NODES;
                int c3 = (p + 3 < end) ? col[p + 3] : NODES;
                uint4 r0 = x4[(size_t)c0 * 8 + c8];
                uint4 r1 = x4[(size_t)c1 * 8 + c8];
                uint4 r2 = x4[(size_t)c2 * 8 + c8];
                uint4 r3 = x4[(size_t)c3 * 8 + c8];
                acc_bf8(a0, r0); acc_bf8(a1, r1); acc_bf8(a2, r2); acc_bf8(a3, r3);
            }
#pragma unroll
            for (int j = 0; j < 8; ++j) r.s[j] = f2bf(a0[j] + a1[j] + a2[j] + a3[j]);
        } else {
            r.u = make_uint4(0, 0, 0, 0);
        }
        *(uint4*)(v_lds + node * V_STRIDE + c8 * 8) = r.u;
    }
    __syncthreads();

    // ---- MFMA phase ----
    const int w = t >> 6;            // wave 0..3 -> nodes 16w..16w+15
    const int l = t & 63;
    const int q = l >> 4;            // k-quad
    const int c = l & 15;            // A row (node) / B row (output)
    const unsigned short* vrow = v_lds + ((w << 4) + c) * V_STRIDE;

    frag_cd ac0 = {0.f, 0.f, 0.f, 0.f};
    frag_cd ac1 = {0.f, 0.f, 0.f, 0.f};
    frag_cd ac2 = {0.f, 0.f, 0.f, 0.f};
    frag_cd ac3 = {0.f, 0.f, 0.f, 0.f};

#define MSTEP(OFF, A) {                                                          \
        frag_ab b0 = *(const frag_ab*)(wt_lds + (c     ) * WTL_STRIDE + (OFF));  \
        frag_ab b1 = *(const frag_ab*)(wt_lds + (c + 16) * WTL_STRIDE + (OFF));  \
        frag_ab b2 = *(const frag_ab*)(wt_lds + (c + 32) * WTL_STRIDE + (OFF));  \
        frag_ab b3 = *(const frag_ab*)(wt_lds + (c + 48) * WTL_STRIDE + (OFF));  \
        ac0 = __builtin_amdgcn_mfma_f32_16x16x32_bf16(A, b0, ac0, 0, 0, 0);      \
        ac1 = __builtin_amdgcn_mfma_f32_16x16x32_bf16(A, b1, ac1, 0, 0, 0);      \
        ac2 = __builtin_amdgcn_mfma_f32_16x16x32_bf16(A, b2, ac2, 0, 0, 0);      \
        ac3 = __builtin_amdgcn_mfma_f32_16x16x32_bf16(A, b3, ac3, 0, 0, 0); }

    // chunk 0: silu steps s=0,1 + spline step s=2 (dim i = q)
#pragma unroll
    for (int s = 0; s < 2; ++s) {
        float f[8];
#pragma unroll
        for (int j = 0; j < 8; ++j) f[j] = silu(bf2f(vrow[32 * s + 8 * q + j]));
        frag_ab a = pack8_fast(f);
        MSTEP(32 * s + 8 * q, a);
    }
    {
        frag_ab a = bases_frag(bf2f(vrow[q]));
        MSTEP(64 + 8 * q, a);
    }

    // chunks 1..5: restage + 3 spline steps each
#pragma unroll
    for (int st = 1; st < 6; ++st) {
        __syncthreads();
        for (int ci = t; ci < 64 * 12; ci += 256) {
            int o = ci / 12, ch = ci - o * 12;
            *(uint4*)(wt_lds + o * WTL_STRIDE + ch * 8) =
                *(const uint4*)(wt + o * KTOT + st * KSTAGE + ch * 8);
        }
        __syncthreads();
#pragma unroll
        for (int k = 0; k < 3; ++k) {
            int s = 3 * st + k;
            frag_ab a = bases_frag(bf2f(vrow[4 * s + q - 8]));
            MSTEP(32 * k + 8 * q, a);
        }
    }
#undef MSTEP

    // ---- store: C/D rows = nodes, cols = c + 16*acc ----
    const int n0 = nbase + (w << 4) + (q << 2);
#pragma unroll
    for (int r = 0; r < 4; ++r) {
        int n = n0 + r;
        if (n < NODES) {
            unsigned short* o = out + (size_t)n * DIM + c;
            o[0]  = f2bf(ac0[r]);
            o[16] = f2bf(ac1[r]);
            o[32] = f2bf(ac2[r]);
            o[48] = f2bf(ac3[r]);
        }
    }
}

// ---------------------------------------------------------------------------
// pooled[batch[n]] += h[n] (bf16 h, fp32 accum/output).
// ---------------------------------------------------------------------------
__global__ void pool_bf(const unsigned short* __restrict__ h, const int* __restrict__ batch,
                        float* __restrict__ pooled) {
    int f  = threadIdx.x & 63;
    int g4 = threadIdx.x >> 6;
    int n0 = blockIdx.x * 64 + g4 * 16;
    float sum = 0.f;
    int cur = -1;
    for (int k = 0; k < 16; ++k) {
        int n = n0 + k;
        if (n >= NODES) break;
        int bb = batch[n];
        if (bb != cur) {
            if (cur >= 0) atomicAdd(&pooled[cur * DIM + f], sum);
            cur = bb;
            sum = 0.f;
        }
        sum += bf2f(h[(size_t)n * DIM + f]);
    }
    if (cur >= 0) atomicAdd(&pooled[cur * DIM + f], sum);
}

// ---------------------------------------------------------------------------
// Head: one wave per graph, lane = input dim; 10 wave-wide shuffle reductions.
// ---------------------------------------------------------------------------
__global__ __launch_bounds__(64) void head_kernel(const float* __restrict__ pooled,
                                                  const float* __restrict__ bwh,
                                                  const float* __restrict__ swh,
                                                  const float* __restrict__ sch,
                                                  float* __restrict__ out) {
    const int g = blockIdx.x;
    const int i = threadIdx.x;
    float xv = pooled[g * DIM + i];
    float s  = silu(xv);

    float tt  = fmaf(xv, 2.5f, 5.5f);
    float fm  = floorf(tt);
    int   m   = (int)fm;
    float u   = tt - fm;
    float um1 = 1.f - u;
    float v3  = u * u * u * (1.f / 6.f);
    float v0  = um1 * um1 * um1 * (1.f / 6.f);
    float B2m1 = 0.5f * ((u + 1.f) * um1 + (2.f - u) * u);
    float v1  = ((u + 2.f) * um1 * um1 * 0.5f + (2.f - u) * B2m1) * (1.f / 3.f);
    float v2  = ((u + 1.f) * B2m1 + (3.f - u) * u * u * 0.5f) * (1.f / 3.f);
    bool inr  = (m >= 0) && (m <= 10);
    float b[8];
#pragma unroll
    for (int j = 0; j < 8; ++j) {
        float bv = 0.f;
        bv = (j == m - 3) ? v0 : bv;
        bv = (j == m - 2) ? v1 : bv;
        bv = (j == m - 1) ? v2 : bv;
        bv = (j == m)     ? v3 : bv;
        b[j] = inr ? bv : 0.f;
    }

    float part[NT];
#pragma unroll
    for (int o = 0; o < NT; ++o) {
        const float* sp = swh + (o * DIM + i) * 8;
        float sb = 0.f;
#pragma unroll
        for (int qq = 0; qq < 8; ++qq) sb = fmaf(b[qq], sp[qq], sb);
        part[o] = fmaf(s, bwh[o * DIM + i], sb * sch[o * DIM + i]);
    }

#pragma unroll
    for (int o = 0; o < NT; ++o) {
        float v = part[o];
#pragma unroll
        for (int off = 32; off > 0; off >>= 1) v += __shfl_down(v, off, 64);
        if (i == 0) out[g * NT + o] = v;
    }
}

// ---------------------------------------------------------------------------
extern "C" void kernel_launch(void* const* d_in, const int* in_sizes, int n_in,
                              void* d_out, int out_size, void* d_ws, size_t ws_size,
                              hipStream_t stream) {
    const float* x   = (const float*)d_in[0];
    const int*   ei  = (const int*)d_in[1];
    const int*   bat = (const int*)d_in[2];
    const float* bw0 = (const float*)d_in[3];
    const float* sw0 = (const float*)d_in[4];
    const float* sc0 = (const float*)d_in[5];
    const float* bw1 = (const float*)d_in[6];
    const float* sw1 = (const float*)d_in[7];
    const float* sc1 = (const float*)d_in[8];
    const float* bwh = (const float*)d_in[9];
    const float* swh = (const float*)d_in[10];
    const float* sch = (const float*)d_in[11];
    float* out = (float*)d_out;

    const size_t ROW = (size_t)(NODES + 1) * DIM;   // +1 zero row for gather pad

    // ---- workspace layout (all sections 16B-aligned) ----
    unsigned short* wt0 = (unsigned short*)d_ws;                 // 36864
    unsigned short* wt1 = wt0 + DIM * KTOT;                      // 36864
    unsigned short* xbf = wt1 + DIM * KTOT;                      // ROW
    unsigned short* hbf = xbf + ROW;                             // ROW (layer0 out)
    unsigned short* h2  = hbf + ROW;                             // ROW (layer1 out)
    float* pooled = (float*)(h2 + ROW);                          // 32768 f
    int* rowptr   = (int*)(pooled + GRAPHS * DIM);               // 100004 i
    int* col      = rowptr + NODES + 4;                          // EDGES+4 i
    int* bcnt     = col + EDGES + 4;                             // 512 i
    int* bbase    = bcnt + NB;                                   // 512 i
    int* bcur     = bbase + NB;                                  // 512 i
    unsigned* tmp = (unsigned*)(bcur + NB);                      // 1.2M u32

    prep_wt2<<<(2 * DIM * KTOT + 255) / 256, 256, 0, stream>>>(
        bw0, sw0, sc0, bw1, sw1, sc1, wt0, wt1);
    conv_bf16<<<(NODES * DIM / 4 + 255) / 256, 256, 0, stream>>>(x, xbf);
    // zero rows for branchless gather padding (ws re-poisoned every launch)
    hipMemsetAsync(xbf + (size_t)NODES * DIM, 0, DIM * sizeof(unsigned short), stream);
    hipMemsetAsync(hbf + (size_t)NODES * DIM, 0, DIM * sizeof(unsigned short), stream);

    // ---- CSR via bucketed counting sort ----
    hipMemsetAsync(bcnt, 0, NB * sizeof(int), stream);
    const int part_blocks = (EDGES + EPB - 1) / EPB;   // 293
    s1_count<<<part_blocks, 256, 0, stream>>>(ei, bcnt);
    s2_scan<<<1, 512, 0, stream>>>(bcnt, bbase, bcur);
    s3_partition<<<part_blocks, 256, 0, stream>>>(ei, bcur, tmp);
    s4_fill<<<NB, 256, 0, stream>>>(tmp, bcnt, bbase, rowptr, col);

    const int layer_blocks = (NODES + 63) / 64;        // 1563

    fused_layer<<<layer_blocks, 256, 0, stream>>>(xbf, rowptr, col, wt0, hbf);
    fused_layer<<<layer_blocks, 256, 0, stream>>>(hbf, rowptr, col, wt1, h2);

    hipMemsetAsync(pooled, 0, (size_t)GRAPHS * DIM * sizeof(float), stream);
    pool_bf<<<(NODES + 63) / 64, 256, 0, stream>>>(h2, bat, pooled);
    head_kernel<<<GRAPHS, 64, 0, stream>>>(pooled, bwh, swh, sch, out);
}

// Round 12
// 249.182 us; speedup vs baseline: 6.3432x; 1.1243x over previous
//
#include <hip/hip_runtime.h>
#include <hip/hip_fp16.h>
#include <math.h>

#define NODES   100000
#define EDGES   1200000
#define GRAPHS  512
#define DIM     64
#define NT      10
#define KTOT    576     // 64 base + 64*8 spline features

#define NB      512     // sort buckets: bucket = dst >> 8; only 391 populated!
#define EPB     4096    // edges per partition block
// CAP sizing: populated buckets = ceil(100000/256) = 391 -> mean = 1.2M/391
// = 3070, sigma = sqrt(3070) ~ 55.  CAP=4096 is ~18 sigma.  (CAP=3072 was the
// round-9..11 corruption bug: half the buckets overflowed into the next slab.)
#define CAP     4096

// K-chunked weight staging: 6 stages x 96 k-values (3 MFMA steps each)
#define KSTAGE     96
#define WTL_STRIDE 104  // 96 shorts + 8 pad
#define V_STRIDE   72   // padded fp16 row stride for v in LDS

typedef _Float16 f16x8  __attribute__((ext_vector_type(8)));   // MFMA A/B frag
typedef __fp16   fp16x2 __attribute__((ext_vector_type(2)));   // cvt_pkrtz result
typedef __attribute__((ext_vector_type(4))) float frag_cd;     // 4 fp32 acc

__device__ __forceinline__ float silu(float x) {
    return x / (1.f + __expf(-x));
}

// pack 2 floats -> fp16x2 dword (v_cvt_pkrtz, 1 instr)
__device__ __forceinline__ unsigned packh2(float a, float b) {
    fp16x2 h = __builtin_amdgcn_cvt_pkrtz(a, b);
    return __builtin_bit_cast(unsigned, h);
}

// add 8 packed fp16 (one uint4) into float acc[8] -- fp32 accumulation
__device__ __forceinline__ void acc_h8(float* a, uint4 p) {
    union { uint4 u; __half2 h[4]; } up; up.u = p;
#pragma unroll
    for (int j = 0; j < 4; ++j) {
        float2 f = __half22float2(up.h[j]);
        a[2 * j]     += f.x;
        a[2 * j + 1] += f.y;
    }
}

// ---------------------------------------------------------------------------
// Cubic B-spline bases for one dim as packed fp16x8 A-fragment (window
// placement via alignbit + dword selects; out-of-range -> all zero).
// ---------------------------------------------------------------------------
__device__ __forceinline__ f16x8 bases_frag(float xv) {
    float tt  = fmaf(xv, 2.5f, 5.5f);
    float fm  = floorf(tt);
    int   m   = (int)fm;
    float u   = tt - fm;
    float um1 = 1.f - u;
    float v3  = u * u * u * (1.f / 6.f);
    float v0  = um1 * um1 * um1 * (1.f / 6.f);
    float B2m1 = 0.5f * ((u + 1.f) * um1 + (2.f - u) * u);
    float v1  = ((u + 2.f) * um1 * um1 * 0.5f + (2.f - u) * B2m1) * (1.f / 3.f);
    float v2  = ((u + 1.f) * B2m1 + (3.f - u) * u * u * 0.5f) * (1.f / 3.f);

    unsigned d0 = packh2(v0, v1);
    unsigned d1 = packh2(v2, v3);
    int p = m - 3;
    int B = p >> 1;
    bool odd = (p & 1) != 0;
    unsigned e1 = __builtin_amdgcn_alignbit(d1, d0, 16);   // [v1,v2]
    unsigned W0 = odd ? (d0 << 16) : d0;
    unsigned W1 = odd ? e1 : d1;
    unsigned W2 = odd ? (d1 >> 16) : 0u;
    union { f16x8 f; unsigned u[4]; } r;
    r.u[0] = (B == 0) ? W0 : ((B == -1) ? W1 : ((B == -2) ? W2 : 0u));
    r.u[1] = (B == 1) ? W0 : ((B ==  0) ? W1 : ((B == -1) ? W2 : 0u));
    r.u[2] = (B == 2) ? W0 : ((B ==  1) ? W1 : ((B ==  0) ? W2 : 0u));
    r.u[3] = (B == 3) ? W0 : ((B ==  2) ? W1 : ((B ==  1) ? W2 : 0u));
    return r.f;
}

// ---------------------------------------------------------------------------
// Fused weight prep for BOTH layers -> fp16 W_T[o][k] (RNE).
// ---------------------------------------------------------------------------
__global__ void prep_wt2(const float* __restrict__ bw0, const float* __restrict__ sw0,
                         const float* __restrict__ sc0,
                         const float* __restrict__ bw1, const float* __restrict__ sw1,
                         const float* __restrict__ sc1,
                         unsigned short* __restrict__ wt0,
                         unsigned short* __restrict__ wt1) {
    int idx = blockIdx.x * 256 + threadIdx.x;
    if (idx >= 2 * DIM * KTOT) return;
    int layer = idx >= DIM * KTOT;
    int li = layer ? idx - DIM * KTOT : idx;
    const float* bw = layer ? bw1 : bw0;
    const float* sw = layer ? sw1 : sw0;
    const float* sc = layer ? sc1 : sc0;
    unsigned short* wt = layer ? wt1 : wt0;
    int o = li / KTOT, k = li % KTOT;
    float v;
    if (k < DIM) {
        v = bw[o * DIM + k];
    } else {
        int i = (k - DIM) >> 3, g = (k - DIM) & 7;
        v = sw[(o * DIM + i) * 8 + g] * sc[o * DIM + i];
    }
    wt[li] = __half_as_ushort(__float2half(v));
}

// ---------------------------------------------------------------------------
// conv: x (fp32) -> fp16; + zero pad rows for xbf/hbf; + graph offsets goff
// (batch is sorted; goff[g] = first node with batch >= g, goff[GRAPHS]=NODES).
// ---------------------------------------------------------------------------
__global__ void conv_h(const float* __restrict__ x, const int* __restrict__ bat,
                       unsigned short* __restrict__ xb, unsigned short* __restrict__ hpad,
                       int* __restrict__ goff) {
    int i = blockIdx.x * 256 + threadIdx.x;
    if (i < NODES * 16) {
        float4 v = ((const float4*)x)[i];
        unsigned lo = packh2(v.x, v.y);
        unsigned hi = packh2(v.z, v.w);
        ((uint2*)xb)[i] = make_uint2(lo, hi);
        if ((i & 15) == 0) {
            int n = i >> 4;
            int b  = bat[n];
            int bp = (n == 0) ? -1 : bat[n - 1];
            for (int g = bp + 1; g <= b; ++g) goff[g] = n;
        }
        if (i == 0) {
            int blast = bat[NODES - 1];
            for (int g = blast + 1; g <= GRAPHS; ++g) goff[g] = NODES;
        }
    } else {
        int j = i - NODES * 16;
        if (j < 16)      ((uint2*)xb)[NODES * 16 + j] = make_uint2(0, 0);
        else if (j < 32) ((uint2*)hpad)[j - 16]       = make_uint2(0, 0);
    }
}

// ===========================================================================
// CSR via bucketed counting sort with FIXED bucket capacity (no global scan).
// tmp/col live in bucket-padded slabs of CAP entries each.
// tmp entry: src (bits 0..16) | dst&255 (bits 24..31).
// ===========================================================================
__global__ __launch_bounds__(256) void s3_partition(const int* __restrict__ ei,
                                                    int* __restrict__ bcur,
                                                    unsigned* __restrict__ tmp) {
    __shared__ int hist[NB], gbase[NB], cur[NB];
    int t = threadIdx.x;
    hist[t] = 0; hist[t + 256] = 0;
    cur[t]  = 0; cur[t + 256]  = 0;
    __syncthreads();
    int e0 = blockIdx.x * EPB;
#pragma unroll
    for (int k = 0; k < 16; ++k) {
        int e = e0 + t + k * 256;
        if (e < EDGES) atomicAdd(&hist[ei[EDGES + e] >> 8], 1);
    }
    __syncthreads();
    {
        int c0 = hist[t];       if (c0) gbase[t]       = atomicAdd(&bcur[t], c0);
        int c1 = hist[t + 256]; if (c1) gbase[t + 256] = atomicAdd(&bcur[t + 256], c1);
    }
    __syncthreads();
#pragma unroll
    for (int k = 0; k < 16; ++k) {
        int e = e0 + t + k * 256;
        if (e < EDGES) {
            unsigned src = (unsigned)ei[e];
            int dst = ei[EDGES + e];
            int b = dst >> 8;
            int slot = atomicAdd(&cur[b], 1);
            tmp[(size_t)b * CAP + gbase[b] + slot] = src | ((unsigned)(dst & 255) << 24);
        }
    }
}

__global__ __launch_bounds__(256) void s4_fill(const unsigned* __restrict__ tmp,
                                               const int* __restrict__ bcur,
                                               int2* __restrict__ rowp,
                                               int* __restrict__ col) {
    __shared__ int hist[256], scan[256];
    int b = blockIdx.x, t = threadIdx.x;
    int cnt = bcur[b];
    int base = b * CAP;
    hist[t] = 0;
    __syncthreads();
    for (int i = t; i < cnt; i += 256)
        atomicAdd(&hist[tmp[base + i] >> 24], 1);
    __syncthreads();
    int v = hist[t];
    scan[t] = v;
    __syncthreads();
    int run = v;
    for (int d = 1; d < 256; d <<= 1) {
        int a = (t >= d) ? scan[t - d] : 0;
        __syncthreads();
        run += a; scan[t] = run;
        __syncthreads();
    }
    int excl = run - v;
    int ng = b * 256 + t;
    if (ng < NODES) rowp[ng] = make_int2(base + excl, base + excl + v);
    __syncthreads();
    scan[t] = excl;
    __syncthreads();
    for (int i = t; i < cnt; i += 256) {
        unsigned p = tmp[base + i];
        int pos = atomicAdd(&scan[p >> 24], 1);
        col[base + pos] = (int)(p & 0xFFFFFFu);
    }
}

// ===========================================================================
// Fused GIN layer (fp16 storage, fp32 gather accum): branchless gather -> LDS,
// MFMA KAN with all 64 outputs, W_T staged in 6 K-chunks with REGISTER
// PREFETCH of the next chunk.  LDS 22.5 KB -> 7 blocks/CU.
// xin must have a zero row at index NODES.
// ===========================================================================
__global__ __launch_bounds__(256) void fused_layer(const unsigned short* __restrict__ xin,
                                                   const int2* __restrict__ rowp,
                                                   const int* __restrict__ col,
                                                   const unsigned short* __restrict__ wt,
                                                   unsigned short* __restrict__ out) {
    __shared__ unsigned short wt_lds[64 * WTL_STRIDE];  // 13312 B
    __shared__ unsigned short v_lds[64 * V_STRIDE];     //  9216 B

    const int t     = threadIdx.x;
    const int nbase = blockIdx.x * 64;

    // ---- prefetch W chunk 0 into registers ----
    uint4 p0, p1, p2;
    {
        int c0 = t, c1 = t + 256, c2 = t + 512;
        p0 = *(const uint4*)(wt + (c0 / 12) * KTOT + (c0 % 12) * 8);
        p1 = *(const uint4*)(wt + (c1 / 12) * KTOT + (c1 % 12) * 8);
        p2 = *(const uint4*)(wt + (c2 / 12) * KTOT + (c2 % 12) * 8);
    }

    // ---- fused gather: v[node] = x[node] + sum_{src} x[src] ----
    // fp16 rows, fp32 accumulation, branchless via zero row.
    const uint4* x4 = (const uint4*)xin;
#pragma unroll
    for (int rd = 0; rd < 2; ++rd) {
        int idx  = t + rd * 256;
        int node = idx >> 3, c8 = idx & 7;
        int n = nbase + node;
        uint4 res = make_uint4(0, 0, 0, 0);
        if (n < NODES) {
            int2 be = rowp[n];
            float a0[8], a1[8], a2[8], a3[8];
#pragma unroll
            for (int j = 0; j < 8; ++j) { a0[j] = 0.f; a1[j] = 0.f; a2[j] = 0.f; a3[j] = 0.f; }
            acc_h8(a0, x4[(size_t)n * 8 + c8]);                // self term
            for (int p = be.x; p < be.y; p += 4) {
                int c0 = col[p];                               // always valid
                int c1 = (p + 1 < be.y) ? col[p + 1] : NODES;  // zero row
                int c2 = (p + 2 < be.y) ? col[p + 2] : NODES;
                int c3 = (p + 3 < be.y) ? col[p + 3] : NODES;
                uint4 r0 = x4[(size_t)c0 * 8 + c8];
                uint4 r1 = x4[(size_t)c1 * 8 + c8];
                uint4 r2 = x4[(size_t)c2 * 8 + c8];
                uint4 r3 = x4[(size_t)c3 * 8 + c8];
                acc_h8(a0, r0); acc_h8(a1, r1); acc_h8(a2, r2); acc_h8(a3, r3);
            }
            union { uint4 u; unsigned w[4]; } rr;
#pragma unroll
            for (int j = 0; j < 4; ++j) {
                float lo = a0[2 * j]     + a1[2 * j]     + a2[2 * j]     + a3[2 * j];
                float hi = a0[2 * j + 1] + a1[2 * j + 1] + a2[2 * j + 1] + a3[2 * j + 1];
                rr.w[j] = packh2(lo, hi);
            }
            res = rr.u;
        }
        *(uint4*)(v_lds + node * V_STRIDE + c8 * 8) = res;
    }
    // write chunk 0 to LDS
    {
        int c0 = t, c1 = t + 256, c2 = t + 512;
        *(uint4*)(wt_lds + (c0 / 12) * WTL_STRIDE + (c0 % 12) * 8) = p0;
        *(uint4*)(wt_lds + (c1 / 12) * WTL_STRIDE + (c1 % 12) * 8) = p1;
        *(uint4*)(wt_lds + (c2 / 12) * WTL_STRIDE + (c2 % 12) * 8) = p2;
    }
    __syncthreads();

    // ---- MFMA phase ----
    const int w = t >> 6;            // wave 0..3 -> nodes 16w..16w+15
    const int l = t & 63;
    const int q = l >> 4;            // k-quad
    const int c = l & 15;            // A row (node) / B row (output)
    const unsigned short* vrow = v_lds + ((w << 4) + c) * V_STRIDE;

    frag_cd ac0 = {0.f, 0.f, 0.f, 0.f};
    frag_cd ac1 = {0.f, 0.f, 0.f, 0.f};
    frag_cd ac2 = {0.f, 0.f, 0.f, 0.f};
    frag_cd ac3 = {0.f, 0.f, 0.f, 0.f};

#define MSTEP(OFF, A) {                                                          \
        f16x8 b0 = *(const f16x8*)(wt_lds + (c     ) * WTL_STRIDE + (OFF));      \
        f16x8 b1 = *(const f16x8*)(wt_lds + (c + 16) * WTL_STRIDE + (OFF));      \
        f16x8 b2 = *(const f16x8*)(wt_lds + (c + 32) * WTL_STRIDE + (OFF));      \
        f16x8 b3 = *(const f16x8*)(wt_lds + (c + 48) * WTL_STRIDE + (OFF));      \
        ac0 = __builtin_amdgcn_mfma_f32_16x16x32_f16(A, b0, ac0, 0, 0, 0);       \
        ac1 = __builtin_amdgcn_mfma_f32_16x16x32_f16(A, b1, ac1, 0, 0, 0);       \
        ac2 = __builtin_amdgcn_mfma_f32_16x16x32_f16(A, b2, ac2, 0, 0, 0);       \
        ac3 = __builtin_amdgcn_mfma_f32_16x16x32_f16(A, b3, ac3, 0, 0, 0); }

    // prefetch chunk 1 (in flight during chunk-0 compute)
    {
        int c0 = t, c1 = t + 256, c2 = t + 512;
        p0 = *(const uint4*)(wt + (c0 / 12) * KTOT + KSTAGE + (c0 % 12) * 8);
        p1 = *(const uint4*)(wt + (c1 / 12) * KTOT + KSTAGE + (c1 % 12) * 8);
        p2 = *(const uint4*)(wt + (c2 / 12) * KTOT + KSTAGE + (c2 % 12) * 8);
    }

    // chunk 0: silu steps s=0,1 + spline step s=2 (dim i = q)
#pragma unroll
    for (int s = 0; s < 2; ++s) {
        f16x8 hv = *(const f16x8*)(vrow + 32 * s + 8 * q);
        float f[8];
#pragma unroll
        for (int j = 0; j < 8; ++j) f[j] = silu((float)hv[j]);
        union { f16x8 v; unsigned u[4]; } a;
#pragma unroll
        for (int j = 0; j < 4; ++j) a.u[j] = packh2(f[2 * j], f[2 * j + 1]);
        MSTEP(32 * s + 8 * q, a.v);
    }
    {
        f16x8 a = bases_frag((float)(*(const _Float16*)(vrow + q)));
        MSTEP(64 + 8 * q, a);
    }

    // chunks 1..5: barrier, commit prefetched chunk, prefetch next, 3 steps
#pragma unroll
    for (int st = 1; st < 6; ++st) {
        __syncthreads();
        {
            int c0 = t, c1 = t + 256, c2 = t + 512;
            *(uint4*)(wt_lds + (c0 / 12) * WTL_STRIDE + (c0 % 12) * 8) = p0;
            *(uint4*)(wt_lds + (c1 / 12) * WTL_STRIDE + (c1 % 12) * 8) = p1;
            *(uint4*)(wt_lds + (c2 / 12) * WTL_STRIDE + (c2 % 12) * 8) = p2;
        }
        __syncthreads();
        if (st < 5) {
            int c0 = t, c1 = t + 256, c2 = t + 512;
            p0 = *(const uint4*)(wt + (c0 / 12) * KTOT + (st + 1) * KSTAGE + (c0 % 12) * 8);
            p1 = *(const uint4*)(wt + (c1 / 12) * KTOT + (st + 1) * KSTAGE + (c1 % 12) * 8);
            p2 = *(const uint4*)(wt + (c2 / 12) * KTOT + (st + 1) * KSTAGE + (c2 % 12) * 8);
        }
#pragma unroll
        for (int k = 0; k < 3; ++k) {
            int s = 3 * st + k;
            f16x8 a = bases_frag((float)(*(const _Float16*)(vrow + 4 * s + q - 8)));
            MSTEP(32 * k + 8 * q, a);
        }
    }
#undef MSTEP

    // ---- store fp16: C/D rows = nodes, cols = c + 16*acc ----
    const int n0 = nbase + (w << 4) + (q << 2);
#pragma unroll
    for (int r = 0; r < 4; ++r) {
        int n = n0 + r;
        if (n < NODES) {
            unsigned short* o = out + (size_t)n * DIM + c;
            o[0]  = __half_as_ushort(__float2half(ac0[r]));
            o[16] = __half_as_ushort(__float2half(ac1[r]));
            o[32] = __half_as_ushort(__float2half(ac2[r]));
            o[48] = __half_as_ushort(__float2half(ac3[r]));
        }
    }
}

// ---------------------------------------------------------------------------
// Fused pool + head: one block per graph.  Phase 1: 8 node-groups x 32 half2
// dims accumulate fp32 partials; phase 2: wave 0 reduces and runs the KAN
// head (fp32) with 10 wave-wide shuffle reductions.  No atomics, no memset.
// ---------------------------------------------------------------------------
__global__ __launch_bounds__(256) void pool_head(const unsigned short* __restrict__ h,
                                                 const int* __restrict__ goff,
                                                 const float* __restrict__ bwh,
                                                 const float* __restrict__ swh,
                                                 const float* __restrict__ sch,
                                                 float* __restrict__ out) {
    __shared__ float ps[8][64];
    const int g = blockIdx.x, t = threadIdx.x;
    const int start = goff[g], end = goff[g + 1];
    const int d2 = t & 31, grp = t >> 5;
    float s0 = 0.f, s1 = 0.f;
    for (int n = start + grp; n < end; n += 8) {
        __half2 hv = *(const __half2*)(h + (size_t)n * DIM + 2 * d2);
        float2 f = __half22float2(hv);
        s0 += f.x;
        s1 += f.y;
    }
    ps[grp][2 * d2]     = s0;
    ps[grp][2 * d2 + 1] = s1;
    __syncthreads();

    if (t < 64) {
        const int i = t;
        float xv = 0.f;
#pragma unroll
        for (int k = 0; k < 8; ++k) xv += ps[k][i];

        float s  = silu(xv);
        float tt  = fmaf(xv, 2.5f, 5.5f);
        float fm  = floorf(tt);
        int   m   = (int)fm;
        float u   = tt - fm;
        float um1 = 1.f - u;
        float v3  = u * u * u * (1.f / 6.f);
        float v0  = um1 * um1 * um1 * (1.f / 6.f);
        float B2m1 = 0.5f * ((u + 1.f) * um1 + (2.f - u) * u);
        float v1  = ((u + 2.f) * um1 * um1 * 0.5f + (2.f - u) * B2m1) * (1.f / 3.f);
        float v2  = ((u + 1.f) * B2m1 + (3.f - u) * u * u * 0.5f) * (1.f / 3.f);
        bool inr  = (m >= 0) && (m <= 10);
        float b[8];
#pragma unroll
        for (int j = 0; j < 8; ++j) {
            float bv = 0.f;
            bv = (j == m - 3) ? v0 : bv;
            bv = (j == m - 2) ? v1 : bv;
            bv = (j == m - 1) ? v2 : bv;
            bv = (j == m)     ? v3 : bv;
            b[j] = inr ? bv : 0.f;
        }

        float part[NT];
#pragma unroll
        for (int o = 0; o < NT; ++o) {
            const float* sp = swh + (o * DIM + i) * 8;
            float sb = 0.f;
#pragma unroll
            for (int qq = 0; qq < 8; ++qq) sb = fmaf(b[qq], sp[qq], sb);
            part[o] = fmaf(s, bwh[o * DIM + i], sb * sch[o * DIM + i]);
        }
#pragma unroll
        for (int o = 0; o < NT; ++o) {
            float v = part[o];
#pragma unroll
            for (int off = 32; off > 0; off >>= 1) v += __shfl_down(v, off, 64);
            if (i == 0) out[g * NT + o] = v;
        }
    }
}

// ---------------------------------------------------------------------------
extern "C" void kernel_launch(void* const* d_in, const int* in_sizes, int n_in,
                              void* d_out, int out_size, void* d_ws, size_t ws_size,
                              hipStream_t stream) {
    const float* x   = (const float*)d_in[0];
    const int*   ei  = (const int*)d_in[1];
    const int*   bat = (const int*)d_in[2];
    const float* bw0 = (const float*)d_in[3];
    const float* sw0 = (const float*)d_in[4];
    const float* sc0 = (const float*)d_in[5];
    const float* bw1 = (const float*)d_in[6];
    const float* sw1 = (const float*)d_in[7];
    const float* sc1 = (const float*)d_in[8];
    const float* bwh = (const float*)d_in[9];
    const float* swh = (const float*)d_in[10];
    const float* sch = (const float*)d_in[11];
    float* out = (float*)d_out;

    const size_t ROW = (size_t)(NODES + 1) * DIM;   // +1 zero row for gather pad

    // ---- workspace layout (16B-aligned sections) ----
    unsigned short* wt0 = (unsigned short*)d_ws;                 // 36864 fp16
    unsigned short* wt1 = wt0 + DIM * KTOT;                      // 36864 fp16
    unsigned short* xbf = wt1 + DIM * KTOT;                      // ROW fp16
    unsigned short* hbf = xbf + ROW;                             // ROW fp16 (layer0 out)
    unsigned short* h2  = hbf + ROW;                             // NODES*DIM fp16
    int* goff     = (int*)(h2 + (size_t)NODES * DIM);            // 514 i (padded)
    int2* rowp    = (int2*)(goff + 514);                         // NODES int2
    int* col      = (int*)(rowp + NODES);                        // NB*CAP i
    int* bcur     = col + (size_t)NB * CAP;                      // NB i
    unsigned* tmp = (unsigned*)(bcur + NB);                      // NB*CAP u32

    prep_wt2<<<(2 * DIM * KTOT + 255) / 256, 256, 0, stream>>>(
        bw0, sw0, sc0, bw1, sw1, sc1, wt0, wt1);
    conv_h<<<(NODES * 16 + 32 + 255) / 256, 256, 0, stream>>>(
        x, bat, xbf, hbf + (size_t)NODES * DIM, goff);

    // ---- CSR via fixed-capacity bucket sort (no global scan) ----
    (void)hipMemsetAsync(bcur, 0, NB * sizeof(int), stream);
    const int part_blocks = (EDGES + EPB - 1) / EPB;   // 293
    s3_partition<<<part_blocks, 256, 0, stream>>>(ei, bcur, tmp);
    s4_fill<<<NB, 256, 0, stream>>>(tmp, bcur, rowp, col);

    const int layer_blocks = (NODES + 63) / 64;        // 1563
    fused_layer<<<layer_blocks, 256, 0, stream>>>(xbf, rowp, col, wt0, hbf);
    fused_layer<<<layer_blocks, 256, 0, stream>>>(hbf, rowp, col, wt1, h2);

    pool_head<<<GRAPHS, 256, 0, stream>>>(h2, goff, bwh, swh, sch, out);
}

// Round 13
// 232.569 us; speedup vs baseline: 6.7963x; 1.0714x over previous
//
#include <hip/hip_runtime.h>
#include <hip/hip_fp16.h>
#include <math.h>

#define NODES   100000
#define EDGES   1200000
#define GRAPHS  512
#define DIM     64
#define NT      10
#define KTOT    576     // 64 base + 64*8 spline features

#define NB      512     // sort buckets: bucket = dst >> 8; 391 populated
#define NBUSED  391     // populated buckets = ceil(NODES/256)
#define EPB     4096    // edges per partition block
// CAP: populated-bucket mean = 1.2M/391 = 3070 (sigma ~55) + per-node x4
// padding (<= 768) -> 4608 gives ~10 sigma headroom.
#define CAP     4608

// K-chunked weight staging: 6 stages x 96 k-values (3 MFMA steps each)
#define KSTAGE     96
#define WTL_STRIDE 104  // 96 shorts + 8 pad
#define V_STRIDE   72   // padded fp16 row stride for v in LDS

#define PREP_BLOCKS 288 // (2*DIM*KTOT)/256, exact

typedef _Float16 f16x8  __attribute__((ext_vector_type(8)));   // MFMA A/B frag
typedef __fp16   fp16x2 __attribute__((ext_vector_type(2)));   // cvt_pkrtz result
typedef __attribute__((ext_vector_type(4))) float frag_cd;     // 4 fp32 acc

__device__ __forceinline__ float silu(float x) {
    return x / (1.f + __expf(-x));
}

// pack 2 floats -> fp16x2 dword (v_cvt_pkrtz, 1 instr)
__device__ __forceinline__ unsigned packh2(float a, float b) {
    fp16x2 h = __builtin_amdgcn_cvt_pkrtz(a, b);
    return __builtin_bit_cast(unsigned, h);
}

// add 8 packed fp16 (one uint4) into float acc[8] -- fp32 accumulation
__device__ __forceinline__ void acc_h8(float* a, uint4 p) {
    union { uint4 u; __half2 h[4]; } up; up.u = p;
#pragma unroll
    for (int j = 0; j < 4; ++j) {
        float2 f = __half22float2(up.h[j]);
        a[2 * j]     += f.x;
        a[2 * j + 1] += f.y;
    }
}

// ---------------------------------------------------------------------------
// Cubic B-spline bases for one dim as packed fp16x8 A-fragment (window
// placement via alignbit + dword selects; out-of-range -> all zero).
// ---------------------------------------------------------------------------
__device__ __forceinline__ f16x8 bases_frag(float xv) {
    float tt  = fmaf(xv, 2.5f, 5.5f);
    float fm  = floorf(tt);
    int   m   = (int)fm;
    float u   = tt - fm;
    float um1 = 1.f - u;
    float v3  = u * u * u * (1.f / 6.f);
    float v0  = um1 * um1 * um1 * (1.f / 6.f);
    float B2m1 = 0.5f * ((u + 1.f) * um1 + (2.f - u) * u);
    float v1  = ((u + 2.f) * um1 * um1 * 0.5f + (2.f - u) * B2m1) * (1.f / 3.f);
    float v2  = ((u + 1.f) * B2m1 + (3.f - u) * u * u * 0.5f) * (1.f / 3.f);

    unsigned d0 = packh2(v0, v1);
    unsigned d1 = packh2(v2, v3);
    int p = m - 3;
    int B = p >> 1;
    bool odd = (p & 1) != 0;
    unsigned e1 = __builtin_amdgcn_alignbit(d1, d0, 16);   // [v1,v2]
    unsigned W0 = odd ? (d0 << 16) : d0;
    unsigned W1 = odd ? e1 : d1;
    unsigned W2 = odd ? (d1 >> 16) : 0u;
    union { f16x8 f; unsigned u[4]; } r;
    r.u[0] = (B == 0) ? W0 : ((B == -1) ? W1 : ((B == -2) ? W2 : 0u));
    r.u[1] = (B == 1) ? W0 : ((B ==  0) ? W1 : ((B == -1) ? W2 : 0u));
    r.u[2] = (B == 2) ? W0 : ((B ==  1) ? W1 : ((B ==  0) ? W2 : 0u));
    r.u[3] = (B == 3) ? W0 : ((B ==  2) ? W1 : ((B ==  1) ? W2 : 0u));
    return r.f;
}

// ---------------------------------------------------------------------------
// Merged prep + conv kernel:
//   blocks [0, PREP_BLOCKS): fp16 W_T[o][k] for both layers (fused scaler).
//   blocks [PREP_BLOCKS, ..): x fp32->fp16, zero pad rows, graph offsets.
// ---------------------------------------------------------------------------
__global__ void prep_conv(const float* __restrict__ bw0, const float* __restrict__ sw0,
                          const float* __restrict__ sc0,
                          const float* __restrict__ bw1, const float* __restrict__ sw1,
                          const float* __restrict__ sc1,
                          unsigned short* __restrict__ wt0,
                          unsigned short* __restrict__ wt1,
                          const float* __restrict__ x, const int* __restrict__ bat,
                          unsigned short* __restrict__ xb,
                          unsigned short* __restrict__ hpad,
                          int* __restrict__ goff) {
    int bx = blockIdx.x;
    if (bx < PREP_BLOCKS) {
        int idx = bx * 256 + threadIdx.x;
        int layer = idx >= DIM * KTOT;
        int li = layer ? idx - DIM * KTOT : idx;
        const float* bw = layer ? bw1 : bw0;
        const float* sw = layer ? sw1 : sw0;
        const float* sc = layer ? sc1 : sc0;
        unsigned short* wt = layer ? wt1 : wt0;
        int o = li / KTOT, k = li % KTOT;
        float v;
        if (k < DIM) {
            v = bw[o * DIM + k];
        } else {
            int i = (k - DIM) >> 3, g = (k - DIM) & 7;
            v = sw[(o * DIM + i) * 8 + g] * sc[o * DIM + i];
        }
        wt[li] = __half_as_ushort(__float2half(v));
        return;
    }
    int i = (bx - PREP_BLOCKS) * 256 + threadIdx.x;
    if (i < NODES * 16) {
        float4 v = ((const float4*)x)[i];
        unsigned lo = packh2(v.x, v.y);
        unsigned hi = packh2(v.z, v.w);
        ((uint2*)xb)[i] = make_uint2(lo, hi);
        if ((i & 15) == 0) {
            int n = i >> 4;
            int b  = bat[n];
            int bp = (n == 0) ? -1 : bat[n - 1];
            for (int g = bp + 1; g <= b; ++g) goff[g] = n;
        }
        if (i == 0) {
            int blast = bat[NODES - 1];
            for (int g = blast + 1; g <= GRAPHS; ++g) goff[g] = NODES;
        }
    } else {
        int j = i - NODES * 16;
        if (j < 16)      ((uint2*)xb)[NODES * 16 + j] = make_uint2(0, 0);
        else if (j < 32) ((uint2*)hpad)[j - 16]       = make_uint2(0, 0);
    }
}

// ===========================================================================
// CSR via bucketed counting sort, fixed bucket slabs of CAP entries.
// tmp entry: src (bits 0..16) | dst&255 (bits 24..31).
// s4 pads each node's col segment to a multiple of 4 using the zero-row
// sentinel (NODES) -> guard-free gather inner loop.
// ===========================================================================
__global__ __launch_bounds__(256) void s3_partition(const int* __restrict__ ei,
                                                    int* __restrict__ bcur,
                                                    unsigned* __restrict__ tmp) {
    __shared__ int hist[NB], gbase[NB], cur[NB];
    int t = threadIdx.x;
    hist[t] = 0; hist[t + 256] = 0;
    cur[t]  = 0; cur[t + 256]  = 0;
    __syncthreads();
    int e0 = blockIdx.x * EPB;
#pragma unroll
    for (int k = 0; k < 16; ++k) {
        int e = e0 + t + k * 256;
        if (e < EDGES) atomicAdd(&hist[ei[EDGES + e] >> 8], 1);
    }
    __syncthreads();
    {
        int c0 = hist[t];       if (c0) gbase[t]       = atomicAdd(&bcur[t], c0);
        int c1 = hist[t + 256]; if (c1) gbase[t + 256] = atomicAdd(&bcur[t + 256], c1);
    }
    __syncthreads();
#pragma unroll
    for (int k = 0; k < 16; ++k) {
        int e = e0 + t + k * 256;
        if (e < EDGES) {
            unsigned src = (unsigned)ei[e];
            int dst = ei[EDGES + e];
            int b = dst >> 8;
            int slot = atomicAdd(&cur[b], 1);
            tmp[(size_t)b * CAP + gbase[b] + slot] = src | ((unsigned)(dst & 255) << 24);
        }
    }
}

__global__ __launch_bounds__(256) void s4_fill(const unsigned* __restrict__ tmp,
                                               const int* __restrict__ bcur,
                                               int2* __restrict__ rowp,
                                               int* __restrict__ col) {
    __shared__ int hist[256], scan[256], startsh[256];
    int b = blockIdx.x, t = threadIdx.x;
    int cnt = bcur[b];
    int base = b * CAP;
    hist[t] = 0;
    __syncthreads();
    for (int i = t; i < cnt; i += 256)
        atomicAdd(&hist[tmp[base + i] >> 24], 1);
    __syncthreads();
    int deg = hist[t];
    int pad = (deg + 3) & ~3;          // segment rounded to x4
    scan[t] = pad;
    __syncthreads();
    int run = pad;
    for (int d = 1; d < 256; d <<= 1) {
        int a = (t >= d) ? scan[t - d] : 0;
        __syncthreads();
        run += a; scan[t] = run;
        __syncthreads();
    }
    int start = base + run - pad;
    int ng = b * 256 + t;
    if (ng < NODES) rowp[ng] = make_int2(start, start + pad);   // padded end
    __syncthreads();
    scan[t]    = start;   // absolute scatter cursor
    startsh[t] = start;
    __syncthreads();
    for (int i = t; i < cnt; i += 256) {
        unsigned p = tmp[base + i];
        int pos = atomicAdd(&scan[p >> 24], 1);
        col[pos] = (int)(p & 0xFFFFFFu);
    }
    __syncthreads();
    // sentinel-fill the pad gap (scan[t] == start+deg now)
    for (int k = scan[t]; k < startsh[t] + pad; ++k) col[k] = NODES;
}

// ===========================================================================
// Fused GIN layer (fp16 storage, fp32 gather accum): guard-free gather -> LDS,
// MFMA KAN with all 64 outputs, W_T staged in 6 K-chunks with register
// prefetch.  LDS 22.5 KB -> 7 blocks/CU.  col is x4-padded with NODES
// sentinels; xin has a zero row at index NODES.
// ===========================================================================
__global__ __launch_bounds__(256) void fused_layer(const unsigned short* __restrict__ xin,
                                                   const int2* __restrict__ rowp,
                                                   const int* __restrict__ col,
                                                   const unsigned short* __restrict__ wt,
                                                   unsigned short* __restrict__ out) {
    __shared__ unsigned short wt_lds[64 * WTL_STRIDE];  // 13312 B
    __shared__ unsigned short v_lds[64 * V_STRIDE];     //  9216 B

    const int t     = threadIdx.x;
    const int nbase = blockIdx.x * 64;

    // ---- prefetch W chunk 0 into registers ----
    uint4 p0, p1, p2;
    {
        int c0 = t, c1 = t + 256, c2 = t + 512;
        p0 = *(const uint4*)(wt + (c0 / 12) * KTOT + (c0 % 12) * 8);
        p1 = *(const uint4*)(wt + (c1 / 12) * KTOT + (c1 % 12) * 8);
        p2 = *(const uint4*)(wt + (c2 / 12) * KTOT + (c2 % 12) * 8);
    }

    // ---- fused gather: v[node] = x[node] + sum_{src} x[src] ----
    // fp16 rows, fp32 accumulation, guard-free (col padded with zero-row).
    const uint4* x4 = (const uint4*)xin;
#pragma unroll
    for (int rd = 0; rd < 2; ++rd) {
        int idx  = t + rd * 256;
        int node = idx >> 3, c8 = idx & 7;
        int n = nbase + node;
        uint4 res = make_uint4(0, 0, 0, 0);
        if (n < NODES) {
            int2 be = rowp[n];
            float a0[8], a1[8], a2[8], a3[8];
#pragma unroll
            for (int j = 0; j < 8; ++j) { a0[j] = 0.f; a1[j] = 0.f; a2[j] = 0.f; a3[j] = 0.f; }
            acc_h8(a0, x4[(size_t)n * 8 + c8]);                // self term
            for (int p = be.x; p < be.y; p += 4) {
                int c0 = col[p];
                int c1 = col[p + 1];
                int c2 = col[p + 2];
                int c3 = col[p + 3];
                uint4 r0 = x4[(size_t)c0 * 8 + c8];
                uint4 r1 = x4[(size_t)c1 * 8 + c8];
                uint4 r2 = x4[(size_t)c2 * 8 + c8];
                uint4 r3 = x4[(size_t)c3 * 8 + c8];
                acc_h8(a0, r0); acc_h8(a1, r1); acc_h8(a2, r2); acc_h8(a3, r3);
            }
            union { uint4 u; unsigned w[4]; } rr;
#pragma unroll
            for (int j = 0; j < 4; ++j) {
                float lo = a0[2 * j]     + a1[2 * j]     + a2[2 * j]     + a3[2 * j];
                float hi = a0[2 * j + 1] + a1[2 * j + 1] + a2[2 * j + 1] + a3[2 * j + 1];
                rr.w[j] = packh2(lo, hi);
            }
            res = rr.u;
        }
        *(uint4*)(v_lds + node * V_STRIDE + c8 * 8) = res;
    }
    // write chunk 0 to LDS
    {
        int c0 = t, c1 = t + 256, c2 = t + 512;
        *(uint4*)(wt_lds + (c0 / 12) * WTL_STRIDE + (c0 % 12) * 8) = p0;
        *(uint4*)(wt_lds + (c1 / 12) * WTL_STRIDE + (c1 % 12) * 8) = p1;
        *(uint4*)(wt_lds + (c2 / 12) * WTL_STRIDE + (c2 % 12) * 8) = p2;
    }
    __syncthreads();

    // ---- MFMA phase ----
    const int w = t >> 6;            // wave 0..3 -> nodes 16w..16w+15
    const int l = t & 63;
    const int q = l >> 4;            // k-quad
    const int c = l & 15;            // A row (node) / B row (output)
    const unsigned short* vrow = v_lds + ((w << 4) + c) * V_STRIDE;

    frag_cd ac0 = {0.f, 0.f, 0.f, 0.f};
    frag_cd ac1 = {0.f, 0.f, 0.f, 0.f};
    frag_cd ac2 = {0.f, 0.f, 0.f, 0.f};
    frag_cd ac3 = {0.f, 0.f, 0.f, 0.f};

#define MSTEP(OFF, A) {                                                          \
        f16x8 b0 = *(const f16x8*)(wt_lds + (c     ) * WTL_STRIDE + (OFF));      \
        f16x8 b1 = *(const f16x8*)(wt_lds + (c + 16) * WTL_STRIDE + (OFF));      \
        f16x8 b2 = *(const f16x8*)(wt_lds + (c + 32) * WTL_STRIDE + (OFF));      \
        f16x8 b3 = *(const f16x8*)(wt_lds + (c + 48) * WTL_STRIDE + (OFF));      \
        ac0 = __builtin_amdgcn_mfma_f32_16x16x32_f16(A, b0, ac0, 0, 0, 0);       \
        ac1 = __builtin_amdgcn_mfma_f32_16x16x32_f16(A, b1, ac1, 0, 0, 0);       \
        ac2 = __builtin_amdgcn_mfma_f32_16x16x32_f16(A, b2, ac2, 0, 0, 0);       \
        ac3 = __builtin_amdgcn_mfma_f32_16x16x32_f16(A, b3, ac3, 0, 0, 0); }

    // prefetch chunk 1 (in flight during chunk-0 compute)
    {
        int c0 = t, c1 = t + 256, c2 = t + 512;
        p0 = *(const uint4*)(wt + (c0 / 12) * KTOT + KSTAGE + (c0 % 12) * 8);
        p1 = *(const uint4*)(wt + (c1 / 12) * KTOT + KSTAGE + (c1 % 12) * 8);
        p2 = *(const uint4*)(wt + (c2 / 12) * KTOT + KSTAGE + (c2 % 12) * 8);
    }

    // chunk 0: silu steps s=0,1 + spline step s=2 (dim i = q)
#pragma unroll
    for (int s = 0; s < 2; ++s) {
        f16x8 hv = *(const f16x8*)(vrow + 32 * s + 8 * q);
        float f[8];
#pragma unroll
        for (int j = 0; j < 8; ++j) f[j] = silu((float)hv[j]);
        union { f16x8 v; unsigned u[4]; } a;
#pragma unroll
        for (int j = 0; j < 4; ++j) a.u[j] = packh2(f[2 * j], f[2 * j + 1]);
        MSTEP(32 * s + 8 * q, a.v);
    }
    {
        f16x8 a = bases_frag((float)(*(const _Float16*)(vrow + q)));
        MSTEP(64 + 8 * q, a);
    }

    // chunks 1..5: barrier, commit prefetched chunk, prefetch next, 3 steps
#pragma unroll
    for (int st = 1; st < 6; ++st) {
        __syncthreads();
        {
            int c0 = t, c1 = t + 256, c2 = t + 512;
            *(uint4*)(wt_lds + (c0 / 12) * WTL_STRIDE + (c0 % 12) * 8) = p0;
            *(uint4*)(wt_lds + (c1 / 12) * WTL_STRIDE + (c1 % 12) * 8) = p1;
            *(uint4*)(wt_lds + (c2 / 12) * WTL_STRIDE + (c2 % 12) * 8) = p2;
        }
        __syncthreads();
        if (st < 5) {
            int c0 = t, c1 = t + 256, c2 = t + 512;
            p0 = *(const uint4*)(wt + (c0 / 12) * KTOT + (st + 1) * KSTAGE + (c0 % 12) * 8);
            p1 = *(const uint4*)(wt + (c1 / 12) * KTOT + (st + 1) * KSTAGE + (c1 % 12) * 8);
            p2 = *(const uint4*)(wt + (c2 / 12) * KTOT + (st + 1) * KSTAGE + (c2 % 12) * 8);
        }
#pragma unroll
        for (int k = 0; k < 3; ++k) {
            int s = 3 * st + k;
            f16x8 a = bases_frag((float)(*(const _Float16*)(vrow + 4 * s + q - 8)));
            MSTEP(32 * k + 8 * q, a);
        }
    }
#undef MSTEP

    // ---- store fp16: C/D rows = nodes, cols = c + 16*acc ----
    const int n0 = nbase + (w << 4) + (q << 2);
#pragma unroll
    for (int r = 0; r < 4; ++r) {
        int n = n0 + r;
        if (n < NODES) {
            unsigned short* o = out + (size_t)n * DIM + c;
            o[0]  = __half_as_ushort(__float2half(ac0[r]));
            o[16] = __half_as_ushort(__float2half(ac1[r]));
            o[32] = __half_as_ushort(__float2half(ac2[r]));
            o[48] = __half_as_ushort(__float2half(ac3[r]));
        }
    }
}

// ---------------------------------------------------------------------------
// Fused pool + head: one block per graph (no atomics, no memset).
// ---------------------------------------------------------------------------
__global__ __launch_bounds__(256) void pool_head(const unsigned short* __restrict__ h,
                                                 const int* __restrict__ goff,
                                                 const float* __restrict__ bwh,
                                                 const float* __restrict__ swh,
                                                 const float* __restrict__ sch,
                                                 float* __restrict__ out) {
    __shared__ float ps[8][64];
    const int g = blockIdx.x, t = threadIdx.x;
    const int start = goff[g], end = goff[g + 1];
    const int d2 = t & 31, grp = t >> 5;
    float s0 = 0.f, s1 = 0.f;
    for (int n = start + grp; n < end; n += 8) {
        __half2 hv = *(const __half2*)(h + (size_t)n * DIM + 2 * d2);
        float2 f = __half22float2(hv);
        s0 += f.x;
        s1 += f.y;
    }
    ps[grp][2 * d2]     = s0;
    ps[grp][2 * d2 + 1] = s1;
    __syncthreads();

    if (t < 64) {
        const int i = t;
        float xv = 0.f;
#pragma unroll
        for (int k = 0; k < 8; ++k) xv += ps[k][i];

        float s  = silu(xv);
        float tt  = fmaf(xv, 2.5f, 5.5f);
        float fm  = floorf(tt);
        int   m   = (int)fm;
        float u   = tt - fm;
        float um1 = 1.f - u;
        float v3  = u * u * u * (1.f / 6.f);
        float v0  = um1 * um1 * um1 * (1.f / 6.f);
        float B2m1 = 0.5f * ((u + 1.f) * um1 + (2.f - u) * u);
        float v1  = ((u + 2.f) * um1 * um1 * 0.5f + (2.f - u) * B2m1) * (1.f / 3.f);
        float v2  = ((u + 1.f) * B2m1 + (3.f - u) * u * u * 0.5f) * (1.f / 3.f);
        bool inr  = (m >= 0) && (m <= 10);
        float b[8];
#pragma unroll
        for (int j = 0; j < 8; ++j) {
            float bv = 0.f;
            bv = (j == m - 3) ? v0 : bv;
            bv = (j == m - 2) ? v1 : bv;
            bv = (j == m - 1) ? v2 : bv;
            bv = (j == m)     ? v3 : bv;
            b[j] = inr ? bv : 0.f;
        }

        float part[NT];
#pragma unroll
        for (int o = 0; o < NT; ++o) {
            const float* sp = swh + (o * DIM + i) * 8;
            float sb = 0.f;
#pragma unroll
            for (int qq = 0; qq < 8; ++qq) sb = fmaf(b[qq], sp[qq], sb);
            part[o] = fmaf(s, bwh[o * DIM + i], sb * sch[o * DIM + i]);
        }
#pragma unroll
        for (int o = 0; o < NT; ++o) {
            float v = part[o];
#pragma unroll
            for (int off = 32; off > 0; off >>= 1) v += __shfl_down(v, off, 64);
            if (i == 0) out[g * NT + o] = v;
        }
    }
}

// ---------------------------------------------------------------------------
extern "C" void kernel_launch(void* const* d_in, const int* in_sizes, int n_in,
                              void* d_out, int out_size, void* d_ws, size_t ws_size,
                              hipStream_t stream) {
    const float* x   = (const float*)d_in[0];
    const int*   ei  = (const int*)d_in[1];
    const int*   bat = (const int*)d_in[2];
    const float* bw0 = (const float*)d_in[3];
    const float* sw0 = (const float*)d_in[4];
    const float* sc0 = (const float*)d_in[5];
    const float* bw1 = (const float*)d_in[6];
    const float* sw1 = (const float*)d_in[7];
    const float* sc1 = (const float*)d_in[8];
    const float* bwh = (const float*)d_in[9];
    const float* swh = (const float*)d_in[10];
    const float* sch = (const float*)d_in[11];
    float* out = (float*)d_out;

    const size_t ROW = (size_t)(NODES + 1) * DIM;   // +1 zero row for gather pad

    // ---- workspace layout (16B-aligned sections) ----
    unsigned short* wt0 = (unsigned short*)d_ws;                 // 36864 fp16
    unsigned short* wt1 = wt0 + DIM * KTOT;                      // 36864 fp16
    unsigned short* xbf = wt1 + DIM * KTOT;                      // ROW fp16
    unsigned short* hbf = xbf + ROW;                             // ROW fp16 (layer0 out)
    unsigned short* h2  = hbf + ROW;                             // NODES*DIM fp16
    int* goff     = (int*)(h2 + (size_t)NODES * DIM);            // 514 i (padded)
    int2* rowp    = (int2*)(goff + 514);                         // NODES int2
    int* col      = (int*)(rowp + NODES);                        // NB*CAP i
    int* bcur     = col + (size_t)NB * CAP;                      // NB i
    unsigned* tmp = (unsigned*)(bcur + NB);                      // NB*CAP u32

    const int conv_blocks = (NODES * 16 + 32 + 255) / 256;       // 6251
    prep_conv<<<PREP_BLOCKS + conv_blocks, 256, 0, stream>>>(
        bw0, sw0, sc0, bw1, sw1, sc1, wt0, wt1,
        x, bat, xbf, hbf + (size_t)NODES * DIM, goff);

    // ---- CSR via fixed-capacity bucket sort ----
    (void)hipMemsetAsync(bcur, 0, NB * sizeof(int), stream);
    const int part_blocks = (EDGES + EPB - 1) / EPB;   // 293
    s3_partition<<<part_blocks, 256, 0, stream>>>(ei, bcur, tmp);
    s4_fill<<<NBUSED, 256, 0, stream>>>(tmp, bcur, rowp, col);

    const int layer_blocks = (NODES + 63) / 64;        // 1563
    fused_layer<<<layer_blocks, 256, 0, stream>>>(xbf, rowp, col, wt0, hbf);
    fused_layer<<<layer_blocks, 256, 0, stream>>>(hbf, rowp, col, wt1, h2);

    pool_head<<<GRAPHS, 256, 0, stream>>>(h2, goff, bwh, swh, sch, out);
}

// Round 14
// 224.665 us; speedup vs baseline: 7.0354x; 1.0352x over previous
//
#include <hip/hip_runtime.h>
#include <hip/hip_fp16.h>
#include <math.h>

#define NODES   100000
#define EDGES   1200000
#define GRAPHS  512
#define DIM     64
#define NT      10
#define KTOT    576     // 64 base + 64*8 spline features

#define NB      512     // sort buckets: bucket = dst >> 8; 391 populated
#define NBUSED  391     // populated buckets = ceil(NODES/256)
#define EPB     4096    // edges per partition block
// CAP: populated-bucket mean = 1.2M/391 = 3070 (sigma ~55) + per-node x4
// padding (<= 768) -> 4608 gives ~10 sigma headroom.
#define CAP     4608
#define COLBUF  2048    // per-64-node col span buffer (mean ~870, 42 sigma)

// K-chunked weight staging: 6 stages x 96 k-values (3 MFMA steps each)
#define KSTAGE     96
#define WTL_STRIDE 104  // 96 shorts + 8 pad
#define V_STRIDE   72   // padded fp16 row stride for v in LDS

#define PREP_BLOCKS 288 // (2*DIM*KTOT)/256, exact

typedef _Float16 f16x8  __attribute__((ext_vector_type(8)));   // MFMA A/B frag
typedef __fp16   fp16x2 __attribute__((ext_vector_type(2)));   // cvt_pkrtz result
typedef __attribute__((ext_vector_type(4))) float frag_cd;     // 4 fp32 acc

__device__ __forceinline__ float silu(float x) {
    return x / (1.f + __expf(-x));
}

// pack 2 floats -> fp16x2 dword (v_cvt_pkrtz, 1 instr)
__device__ __forceinline__ unsigned packh2(float a, float b) {
    fp16x2 h = __builtin_amdgcn_cvt_pkrtz(a, b);
    return __builtin_bit_cast(unsigned, h);
}

// add 8 packed fp16 (one uint4) into float acc[8] -- fp32 accumulation
__device__ __forceinline__ void acc_h8(float* a, uint4 p) {
    union { uint4 u; __half2 h[4]; } up; up.u = p;
#pragma unroll
    for (int j = 0; j < 4; ++j) {
        float2 f = __half22float2(up.h[j]);
        a[2 * j]     += f.x;
        a[2 * j + 1] += f.y;
    }
}

// ---------------------------------------------------------------------------
// Cubic B-spline bases for one dim as packed fp16x8 A-fragment.
// ---------------------------------------------------------------------------
__device__ __forceinline__ f16x8 bases_frag(float xv) {
    float tt  = fmaf(xv, 2.5f, 5.5f);
    float fm  = floorf(tt);
    int   m   = (int)fm;
    float u   = tt - fm;
    float um1 = 1.f - u;
    float v3  = u * u * u * (1.f / 6.f);
    float v0  = um1 * um1 * um1 * (1.f / 6.f);
    float B2m1 = 0.5f * ((u + 1.f) * um1 + (2.f - u) * u);
    float v1  = ((u + 2.f) * um1 * um1 * 0.5f + (2.f - u) * B2m1) * (1.f / 3.f);
    float v2  = ((u + 1.f) * B2m1 + (3.f - u) * u * u * 0.5f) * (1.f / 3.f);

    unsigned d0 = packh2(v0, v1);
    unsigned d1 = packh2(v2, v3);
    int p = m - 3;
    int B = p >> 1;
    bool odd = (p & 1) != 0;
    unsigned e1 = __builtin_amdgcn_alignbit(d1, d0, 16);   // [v1,v2]
    unsigned W0 = odd ? (d0 << 16) : d0;
    unsigned W1 = odd ? e1 : d1;
    unsigned W2 = odd ? (d1 >> 16) : 0u;
    union { f16x8 f; unsigned u[4]; } r;
    r.u[0] = (B == 0) ? W0 : ((B == -1) ? W1 : ((B == -2) ? W2 : 0u));
    r.u[1] = (B == 1) ? W0 : ((B ==  0) ? W1 : ((B == -1) ? W2 : 0u));
    r.u[2] = (B == 2) ? W0 : ((B ==  1) ? W1 : ((B ==  0) ? W2 : 0u));
    r.u[3] = (B == 3) ? W0 : ((B ==  2) ? W1 : ((B ==  1) ? W2 : 0u));
    return r.f;
}

// ---------------------------------------------------------------------------
// Merged prep + conv kernel.
// ---------------------------------------------------------------------------
__global__ void prep_conv(const float* __restrict__ bw0, const float* __restrict__ sw0,
                          const float* __restrict__ sc0,
                          const float* __restrict__ bw1, const float* __restrict__ sw1,
                          const float* __restrict__ sc1,
                          unsigned short* __restrict__ wt0,
                          unsigned short* __restrict__ wt1,
                          const float* __restrict__ x, const int* __restrict__ bat,
                          unsigned short* __restrict__ xb,
                          unsigned short* __restrict__ hpad,
                          int* __restrict__ goff) {
    int bx = blockIdx.x;
    if (bx < PREP_BLOCKS) {
        int idx = bx * 256 + threadIdx.x;
        int layer = idx >= DIM * KTOT;
        int li = layer ? idx - DIM * KTOT : idx;
        const float* bw = layer ? bw1 : bw0;
        const float* sw = layer ? sw1 : sw0;
        const float* sc = layer ? sc1 : sc0;
        unsigned short* wt = layer ? wt1 : wt0;
        int o = li / KTOT, k = li % KTOT;
        float v;
        if (k < DIM) {
            v = bw[o * DIM + k];
        } else {
            int i = (k - DIM) >> 3, g = (k - DIM) & 7;
            v = sw[(o * DIM + i) * 8 + g] * sc[o * DIM + i];
        }
        wt[li] = __half_as_ushort(__float2half(v));
        return;
    }
    int i = (bx - PREP_BLOCKS) * 256 + threadIdx.x;
    if (i < NODES * 16) {
        float4 v = ((const float4*)x)[i];
        unsigned lo = packh2(v.x, v.y);
        unsigned hi = packh2(v.z, v.w);
        ((uint2*)xb)[i] = make_uint2(lo, hi);
        if ((i & 15) == 0) {
            int n = i >> 4;
            int b  = bat[n];
            int bp = (n == 0) ? -1 : bat[n - 1];
            for (int g = bp + 1; g <= b; ++g) goff[g] = n;
        }
        if (i == 0) {
            int blast = bat[NODES - 1];
            for (int g = blast + 1; g <= GRAPHS; ++g) goff[g] = NODES;
        }
    } else {
        int j = i - NODES * 16;
        if (j < 16)      ((uint2*)xb)[NODES * 16 + j] = make_uint2(0, 0);
        else if (j < 32) ((uint2*)hpad)[j - 16]       = make_uint2(0, 0);
    }
}

// ===========================================================================
// CSR via bucketed counting sort, fixed bucket slabs of CAP entries.
// s3: SINGLE PASS -- 16 edges buffered in registers (hist + scatter, one
// global read of ei).  tmp entry: src | (dst&255)<<24.
// ===========================================================================
__global__ __launch_bounds__(256) void s3_partition(const int* __restrict__ ei,
                                                    int* __restrict__ bcur,
                                                    unsigned* __restrict__ tmp) {
    __shared__ int hist[NB], gbase[NB], cur[NB];
    int t = threadIdx.x;
    hist[t] = 0; hist[t + 256] = 0;
    cur[t]  = 0; cur[t + 256]  = 0;
    __syncthreads();
    int e0 = blockIdx.x * EPB;
    int src[16], dst[16];
#pragma unroll
    for (int k = 0; k < 16; ++k) {
        int e = e0 + t + k * 256;
        bool valid = e < EDGES;
        src[k] = valid ? ei[e] : 0;
        dst[k] = valid ? ei[EDGES + e] : -1;
        if (valid) atomicAdd(&hist[dst[k] >> 8], 1);
    }
    __syncthreads();
    {
        int c0 = hist[t];       if (c0) gbase[t]       = atomicAdd(&bcur[t], c0);
        int c1 = hist[t + 256]; if (c1) gbase[t + 256] = atomicAdd(&bcur[t + 256], c1);
    }
    __syncthreads();
#pragma unroll
    for (int k = 0; k < 16; ++k) {
        if (dst[k] >= 0) {
            int b = dst[k] >> 8;
            int slot = atomicAdd(&cur[b], 1);
            tmp[(size_t)b * CAP + gbase[b] + slot] =
                (unsigned)src[k] | ((unsigned)(dst[k] & 255) << 24);
        }
    }
}

// s4: build the bucket's padded col slab in LDS, then write out fully
// coalesced int4 (kills the random 4B global scatter).  Segments padded to
// x4 with zero-row sentinels (NODES) for the guard-free gather.
__global__ __launch_bounds__(256) void s4_fill(const unsigned* __restrict__ tmp,
                                               const int* __restrict__ bcur,
                                               int2* __restrict__ rowp,
                                               int* __restrict__ col) {
    __shared__ int hist[256], scan[256], tot;
    __shared__ int4 colbuf4[CAP / 4];
    int* colbuf = (int*)colbuf4;
    int b = blockIdx.x, t = threadIdx.x;
    int cnt = bcur[b];
    int base = b * CAP;
    hist[t] = 0;
    __syncthreads();
    for (int i = t; i < cnt; i += 256)
        atomicAdd(&hist[tmp[base + i] >> 24], 1);
    __syncthreads();
    int deg = hist[t];
    int pad = (deg + 3) & ~3;          // segment rounded to x4
    scan[t] = pad;
    __syncthreads();
    int run = pad;
    for (int d = 1; d < 256; d <<= 1) {
        int a = (t >= d) ? scan[t - d] : 0;
        __syncthreads();
        run += a; scan[t] = run;
        __syncthreads();
    }
    int start = run - pad;             // relative to slab base
    int ng = b * 256 + t;
    if (ng < NODES) rowp[ng] = make_int2(base + start, base + start + pad);
    if (t == 255) tot = run;           // padded slab total (multiple of 4)
    __syncthreads();
    scan[t] = start;                   // scatter cursor (relative)
    __syncthreads();
    for (int i = t; i < cnt; i += 256) {
        unsigned p = tmp[base + i];
        int pos = atomicAdd(&scan[p >> 24], 1);
        colbuf[pos] = (int)(p & 0xFFFFFFu);
    }
    __syncthreads();
    // sentinel-fill the pad gap (scan[t] == start+deg now)
    for (int k = scan[t]; k < start + pad; ++k) colbuf[k] = NODES;
    __syncthreads();
    // coalesced write-out
    int nq = tot >> 2;
    int4* out4 = (int4*)(col + base);
    for (int i = t; i < nq; i += 256) out4[i] = colbuf4[i];
}

// ===========================================================================
// Fused GIN layer (fp16 storage, fp32 gather accum).  A 64-node block's col
// segments are contiguous in the slab -> staged into LDS once (coalesced);
// per-lane col reads become broadcast ds_read_b128.  W_T staged in 6 K-chunks
// with register prefetch.  LDS ~30.7 KB -> 5 blocks/CU.
// col is x4-padded with NODES sentinels; xin has a zero row at index NODES.
// ===========================================================================
__global__ __launch_bounds__(256) void fused_layer(const unsigned short* __restrict__ xin,
                                                   const int2* __restrict__ rowp,
                                                   const int* __restrict__ col,
                                                   const unsigned short* __restrict__ wt,
                                                   unsigned short* __restrict__ out) {
    __shared__ unsigned short wt_lds[64 * WTL_STRIDE];  // 13312 B
    __shared__ unsigned short v_lds[64 * V_STRIDE];     //  9216 B
    __shared__ int4 col4_lds[COLBUF / 4];               //  8192 B
    __shared__ int cinfo[2];                            // {cbeg, span}

    const int t     = threadIdx.x;
    const int nbase = blockIdx.x * 64;

    // ---- prefetch W chunk 0 into registers ----
    uint4 p0, p1, p2;
    {
        int c0 = t, c1 = t + 256, c2 = t + 512;
        p0 = *(const uint4*)(wt + (c0 / 12) * KTOT + (c0 % 12) * 8);
        p1 = *(const uint4*)(wt + (c1 / 12) * KTOT + (c1 % 12) * 8);
        p2 = *(const uint4*)(wt + (c2 / 12) * KTOT + (c2 % 12) * 8);
    }

    // ---- stage this block's col span into LDS (contiguous in slab) ----
    if (t == 0) {
        int cbeg = rowp[nbase].x;
        int last = nbase + 63 < NODES ? nbase + 63 : NODES - 1;
        int cend = rowp[last].y;
        cinfo[0] = cbeg;
        cinfo[1] = cend - cbeg;
    }
    __syncthreads();
    const int cbeg = cinfo[0];
    const int span = cinfo[1];
    const bool lds_cols = (span <= COLBUF);
    if (lds_cols) {
        const int4* g4 = (const int4*)(col + cbeg);
        for (int i = t; i < (span >> 2); i += 256) col4_lds[i] = g4[i];
    }
    __syncthreads();

    // ---- fused gather: v[node] = x[node] + sum_{src} x[src] ----
    const uint4* x4 = (const uint4*)xin;
#pragma unroll
    for (int rd = 0; rd < 2; ++rd) {
        int idx  = t + rd * 256;
        int node = idx >> 3, c8 = idx & 7;
        int n = nbase + node;
        uint4 res = make_uint4(0, 0, 0, 0);
        if (n < NODES) {
            int2 be = rowp[n];
            float a0[8], a1[8], a2[8], a3[8];
#pragma unroll
            for (int j = 0; j < 8; ++j) { a0[j] = 0.f; a1[j] = 0.f; a2[j] = 0.f; a3[j] = 0.f; }
            acc_h8(a0, x4[n * 8 + c8]);                        // self term
            if (lds_cols) {
                for (int p = be.x; p < be.y; p += 4) {
                    int4 c4 = *(const int4*)((const int*)col4_lds + (p - cbeg));
                    uint4 r0 = x4[c4.x * 8 + c8];
                    uint4 r1 = x4[c4.y * 8 + c8];
                    uint4 r2 = x4[c4.z * 8 + c8];
                    uint4 r3 = x4[c4.w * 8 + c8];
                    acc_h8(a0, r0); acc_h8(a1, r1); acc_h8(a2, r2); acc_h8(a3, r3);
                }
            } else {
                for (int p = be.x; p < be.y; p += 4) {
                    int4 c4 = *(const int4*)(col + p);
                    uint4 r0 = x4[c4.x * 8 + c8];
                    uint4 r1 = x4[c4.y * 8 + c8];
                    uint4 r2 = x4[c4.z * 8 + c8];
                    uint4 r3 = x4[c4.w * 8 + c8];
                    acc_h8(a0, r0); acc_h8(a1, r1); acc_h8(a2, r2); acc_h8(a3, r3);
                }
            }
            union { uint4 u; unsigned w[4]; } rr;
#pragma unroll
            for (int j = 0; j < 4; ++j) {
                float lo = a0[2 * j]     + a1[2 * j]     + a2[2 * j]     + a3[2 * j];
                float hi = a0[2 * j + 1] + a1[2 * j + 1] + a2[2 * j + 1] + a3[2 * j + 1];
                rr.w[j] = packh2(lo, hi);
            }
            res = rr.u;
        }
        *(uint4*)(v_lds + node * V_STRIDE + c8 * 8) = res;
    }
    // write chunk 0 to LDS
    {
        int c0 = t, c1 = t + 256, c2 = t + 512;
        *(uint4*)(wt_lds + (c0 / 12) * WTL_STRIDE + (c0 % 12) * 8) = p0;
        *(uint4*)(wt_lds + (c1 / 12) * WTL_STRIDE + (c1 % 12) * 8) = p1;
        *(uint4*)(wt_lds + (c2 / 12) * WTL_STRIDE + (c2 % 12) * 8) = p2;
    }
    __syncthreads();

    // ---- MFMA phase ----
    const int w = t >> 6;            // wave 0..3 -> nodes 16w..16w+15
    const int l = t & 63;
    const int q = l >> 4;            // k-quad
    const int c = l & 15;            // A row (node) / B row (output)
    const unsigned short* vrow = v_lds + ((w << 4) + c) * V_STRIDE;

    frag_cd ac0 = {0.f, 0.f, 0.f, 0.f};
    frag_cd ac1 = {0.f, 0.f, 0.f, 0.f};
    frag_cd ac2 = {0.f, 0.f, 0.f, 0.f};
    frag_cd ac3 = {0.f, 0.f, 0.f, 0.f};

#define MSTEP(OFF, A) {                                                          \
        f16x8 b0 = *(const f16x8*)(wt_lds + (c     ) * WTL_STRIDE + (OFF));      \
        f16x8 b1 = *(const f16x8*)(wt_lds + (c + 16) * WTL_STRIDE + (OFF));      \
        f16x8 b2 = *(const f16x8*)(wt_lds + (c + 32) * WTL_STRIDE + (OFF));      \
        f16x8 b3 = *(const f16x8*)(wt_lds + (c + 48) * WTL_STRIDE + (OFF));      \
        ac0 = __builtin_amdgcn_mfma_f32_16x16x32_f16(A, b0, ac0, 0, 0, 0);       \
        ac1 = __builtin_amdgcn_mfma_f32_16x16x32_f16(A, b1, ac1, 0, 0, 0);       \
        ac2 = __builtin_amdgcn_mfma_f32_16x16x32_f16(A, b2, ac2, 0, 0, 0);       \
        ac3 = __builtin_amdgcn_mfma_f32_16x16x32_f16(A, b3, ac3, 0, 0, 0); }

    // prefetch chunk 1 (in flight during chunk-0 compute)
    {
        int c0 = t, c1 = t + 256, c2 = t + 512;
        p0 = *(const uint4*)(wt + (c0 / 12) * KTOT + KSTAGE + (c0 % 12) * 8);
        p1 = *(const uint4*)(wt + (c1 / 12) * KTOT + KSTAGE + (c1 % 12) * 8);
        p2 = *(const uint4*)(wt + (c2 / 12) * KTOT + KSTAGE + (c2 % 12) * 8);
    }

    // chunk 0: silu steps s=0,1 + spline step s=2 (dim i = q)
#pragma unroll
    for (int s = 0; s < 2; ++s) {
        f16x8 hv = *(const f16x8*)(vrow + 32 * s + 8 * q);
        float f[8];
#pragma unroll
        for (int j = 0; j < 8; ++j) f[j] = silu((float)hv[j]);
        union { f16x8 v; unsigned u[4]; } a;
#pragma unroll
        for (int j = 0; j < 4; ++j) a.u[j] = packh2(f[2 * j], f[2 * j + 1]);
        MSTEP(32 * s + 8 * q, a.v);
    }
    {
        f16x8 a = bases_frag((float)(*(const _Float16*)(vrow + q)));
        MSTEP(64 + 8 * q, a);
    }

    // chunks 1..5: barrier, commit prefetched chunk, prefetch next, 3 steps
#pragma unroll
    for (int st = 1; st < 6; ++st) {
        __syncthreads();
        {
            int c0 = t, c1 = t + 256, c2 = t + 512;
            *(uint4*)(wt_lds + (c0 / 12) * WTL_STRIDE + (c0 % 12) * 8) = p0;
            *(uint4*)(wt_lds + (c1 / 12) * WTL_STRIDE + (c1 % 12) * 8) = p1;
            *(uint4*)(wt_lds + (c2 / 12) * WTL_STRIDE + (c2 % 12) * 8) = p2;
        }
        __syncthreads();
        if (st < 5) {
            int c0 = t, c1 = t + 256, c2 = t + 512;
            p0 = *(const uint4*)(wt + (c0 / 12) * KTOT + (st + 1) * KSTAGE + (c0 % 12) * 8);
            p1 = *(const uint4*)(wt + (c1 / 12) * KTOT + (st + 1) * KSTAGE + (c1 % 12) * 8);
            p2 = *(const uint4*)(wt + (c2 / 12) * KTOT + (st + 1) * KSTAGE + (c2 % 12) * 8);
        }
#pragma unroll
        for (int k = 0; k < 3; ++k) {
            int s = 3 * st + k;
            f16x8 a = bases_frag((float)(*(const _Float16*)(vrow + 4 * s + q - 8)));
            MSTEP(32 * k + 8 * q, a);
        }
    }
#undef MSTEP

    // ---- store fp16: C/D rows = nodes, cols = c + 16*acc ----
    const int n0 = nbase + (w << 4) + (q << 2);
#pragma unroll
    for (int r = 0; r < 4; ++r) {
        int n = n0 + r;
        if (n < NODES) {
            unsigned short* o = out + (size_t)n * DIM + c;
            o[0]  = __half_as_ushort(__float2half(ac0[r]));
            o[16] = __half_as_ushort(__float2half(ac1[r]));
            o[32] = __half_as_ushort(__float2half(ac2[r]));
            o[48] = __half_as_ushort(__float2half(ac3[r]));
        }
    }
}

// ---------------------------------------------------------------------------
// Fused pool + head: one block per graph (no atomics, no memset).
// ---------------------------------------------------------------------------
__global__ __launch_bounds__(256) void pool_head(const unsigned short* __restrict__ h,
                                                 const int* __restrict__ goff,
                                                 const float* __restrict__ bwh,
                                                 const float* __restrict__ swh,
                                                 const float* __restrict__ sch,
                                                 float* __restrict__ out) {
    __shared__ float ps[8][64];
    const int g = blockIdx.x, t = threadIdx.x;
    const int start = goff[g], end = goff[g + 1];
    const int d2 = t & 31, grp = t >> 5;
    float s0 = 0.f, s1 = 0.f;
    for (int n = start + grp; n < end; n += 8) {
        __half2 hv = *(const __half2*)(h + (size_t)n * DIM + 2 * d2);
        float2 f = __half22float2(hv);
        s0 += f.x;
        s1 += f.y;
    }
    ps[grp][2 * d2]     = s0;
    ps[grp][2 * d2 + 1] = s1;
    __syncthreads();

    if (t < 64) {
        const int i = t;
        float xv = 0.f;
#pragma unroll
        for (int k = 0; k < 8; ++k) xv += ps[k][i];

        float s  = silu(xv);
        float tt  = fmaf(xv, 2.5f, 5.5f);
        float fm  = floorf(tt);
        int   m   = (int)fm;
        float u   = tt - fm;
        float um1 = 1.f - u;
        float v3  = u * u * u * (1.f / 6.f);
        float v0  = um1 * um1 * um1 * (1.f / 6.f);
        float B2m1 = 0.5f * ((u + 1.f) * um1 + (2.f - u) * u);
        float v1  = ((u + 2.f) * um1 * um1 * 0.5f + (2.f - u) * B2m1) * (1.f / 3.f);
        float v2  = ((u + 1.f) * B2m1 + (3.f - u) * u * u * 0.5f) * (1.f / 3.f);
        bool inr  = (m >= 0) && (m <= 10);
        float b[8];
#pragma unroll
        for (int j = 0; j < 8; ++j) {
            float bv = 0.f;
            bv = (j == m - 3) ? v0 : bv;
            bv = (j == m - 2) ? v1 : bv;
            bv = (j == m - 1) ? v2 : bv;
            bv = (j == m)     ? v3 : bv;
            b[j] = inr ? bv : 0.f;
        }

        float part[NT];
#pragma unroll
        for (int o = 0; o < NT; ++o) {
            const float* sp = swh + (o * DIM + i) * 8;
            float sb = 0.f;
#pragma unroll
            for (int qq = 0; qq < 8; ++qq) sb = fmaf(b[qq], sp[qq], sb);
            part[o] = fmaf(s, bwh[o * DIM + i], sb * sch[o * DIM + i]);
        }
#pragma unroll
        for (int o = 0; o < NT; ++o) {
            float v = part[o];
#pragma unroll
            for (int off = 32; off > 0; off >>= 1) v += __shfl_down(v, off, 64);
            if (i == 0) out[g * NT + o] = v;
        }
    }
}

// ---------------------------------------------------------------------------
extern "C" void kernel_launch(void* const* d_in, const int* in_sizes, int n_in,
                              void* d_out, int out_size, void* d_ws, size_t ws_size,
                              hipStream_t stream) {
    const float* x   = (const float*)d_in[0];
    const int*   ei  = (const int*)d_in[1];
    const int*   bat = (const int*)d_in[2];
    const float* bw0 = (const float*)d_in[3];
    const float* sw0 = (const float*)d_in[4];
    const float* sc0 = (const float*)d_in[5];
    const float* bw1 = (const float*)d_in[6];
    const float* sw1 = (const float*)d_in[7];
    const float* sc1 = (const float*)d_in[8];
    const float* bwh = (const float*)d_in[9];
    const float* swh = (const float*)d_in[10];
    const float* sch = (const float*)d_in[11];
    float* out = (float*)d_out;

    const size_t ROW = (size_t)(NODES + 1) * DIM;   // +1 zero row for gather pad

    // ---- workspace layout (16B-aligned sections) ----
    unsigned short* wt0 = (unsigned short*)d_ws;                 // 36864 fp16
    unsigned short* wt1 = wt0 + DIM * KTOT;                      // 36864 fp16
    unsigned short* xbf = wt1 + DIM * KTOT;                      // ROW fp16
    unsigned short* hbf = xbf + ROW;                             // ROW fp16 (layer0 out)
    unsigned short* h2  = hbf + ROW;                             // NODES*DIM fp16
    int* goff     = (int*)(h2 + (size_t)NODES * DIM);            // 514 i (padded)
    int2* rowp    = (int2*)(goff + 514);                         // NODES int2
    int* col      = (int*)(rowp + NODES);                        // NB*CAP i
    int* bcur     = col + (size_t)NB * CAP;                      // NB i
    unsigned* tmp = (unsigned*)(bcur + NB);                      // NB*CAP u32

    const int conv_blocks = (NODES * 16 + 32 + 255) / 256;       // 6251
    prep_conv<<<PREP_BLOCKS + conv_blocks, 256, 0, stream>>>(
        bw0, sw0, sc0, bw1, sw1, sc1, wt0, wt1,
        x, bat, xbf, hbf + (size_t)NODES * DIM, goff);

    // ---- CSR via fixed-capacity bucket sort ----
    (void)hipMemsetAsync(bcur, 0, NB * sizeof(int), stream);
    const int part_blocks = (EDGES + EPB - 1) / EPB;   // 293
    s3_partition<<<part_blocks, 256, 0, stream>>>(ei, bcur, tmp);
    s4_fill<<<NBUSED, 256, 0, stream>>>(tmp, bcur, rowp, col);

    const int layer_blocks = (NODES + 63) / 64;        // 1563
    fused_layer<<<layer_blocks, 256, 0, stream>>>(xbf, rowp, col, wt0, hbf);
    fused_layer<<<layer_blocks, 256, 0, stream>>>(hbf, rowp, col, wt1, h2);

    pool_head<<<GRAPHS, 256, 0, stream>>>(h2, goff, bwh, swh, sch, out);
}

// Round 15
// 214.296 us; speedup vs baseline: 7.3758x; 1.0484x over previous
//
#include <hip/hip_runtime.h>
#include <hip/hip_fp16.h>
#include <math.h>

#define NODES   100000
#define EDGES   1200000
#define GRAPHS  512
#define DIM     64
#define NT      10
#define KTOT    576     // 64 base + 64*8 spline features

#define NB      512     // sort buckets: bucket = dst >> 8; 391 populated
#define NBUSED  391     // populated buckets = ceil(NODES/256)
#define EPB     4096    // edges per s3 block
// CAP: populated-bucket mean = 1.2M/391 = 3070 (sigma ~55) + per-node x4
// padding (<= 768) -> 4608 gives ~10 sigma headroom.
#define CAP     4608

// K-chunked weight staging: 6 stages x 96 k-values (3 MFMA steps each)
#define KSTAGE     96
#define WTL_STRIDE 104  // 96 shorts + 8 pad
#define V_STRIDE   72   // padded fp16 row stride for v in LDS

// mega-kernel block ranges (512 threads each)
#define S3B     ((EDGES + EPB - 1) / EPB)              // 293
#define PREPB   ((2 * DIM * KTOT) / 512)               // 144
#define CONVB   ((NODES * 16 + 32 + 511) / 512)        // 3126

typedef _Float16 f16x8  __attribute__((ext_vector_type(8)));   // MFMA A/B frag
typedef __fp16   fp16x2 __attribute__((ext_vector_type(2)));   // cvt_pkrtz result
typedef __attribute__((ext_vector_type(4))) float frag_cd;     // 4 fp32 acc

__device__ __forceinline__ float silu(float x) {
    return x / (1.f + __expf(-x));
}

__device__ __forceinline__ unsigned packh2(float a, float b) {
    fp16x2 h = __builtin_amdgcn_cvt_pkrtz(a, b);
    return __builtin_bit_cast(unsigned, h);
}

// add 8 packed fp16 (one uint4) into float acc[8] -- fp32 accumulation
__device__ __forceinline__ void acc_h8(float* a, uint4 p) {
    union { uint4 u; __half2 h[4]; } up; up.u = p;
#pragma unroll
    for (int j = 0; j < 4; ++j) {
        float2 f = __half22float2(up.h[j]);
        a[2 * j]     += f.x;
        a[2 * j + 1] += f.y;
    }
}

// ---------------------------------------------------------------------------
// Cubic B-spline bases for one dim as packed fp16x8 A-fragment.
// ---------------------------------------------------------------------------
__device__ __forceinline__ f16x8 bases_frag(float xv) {
    float tt  = fmaf(xv, 2.5f, 5.5f);
    float fm  = floorf(tt);
    int   m   = (int)fm;
    float u   = tt - fm;
    float um1 = 1.f - u;
    float v3  = u * u * u * (1.f / 6.f);
    float v0  = um1 * um1 * um1 * (1.f / 6.f);
    float B2m1 = 0.5f * ((u + 1.f) * um1 + (2.f - u) * u);
    float v1  = ((u + 2.f) * um1 * um1 * 0.5f + (2.f - u) * B2m1) * (1.f / 3.f);
    float v2  = ((u + 1.f) * B2m1 + (3.f - u) * u * u * 0.5f) * (1.f / 3.f);

    unsigned d0 = packh2(v0, v1);
    unsigned d1 = packh2(v2, v3);
    int p = m - 3;
    int B = p >> 1;
    bool odd = (p & 1) != 0;
    unsigned e1 = __builtin_amdgcn_alignbit(d1, d0, 16);   // [v1,v2]
    unsigned W0 = odd ? (d0 << 16) : d0;
    unsigned W1 = odd ? e1 : d1;
    unsigned W2 = odd ? (d1 >> 16) : 0u;
    union { f16x8 f; unsigned u[4]; } r;
    r.u[0] = (B == 0) ? W0 : ((B == -1) ? W1 : ((B == -2) ? W2 : 0u));
    r.u[1] = (B == 1) ? W0 : ((B ==  0) ? W1 : ((B == -1) ? W2 : 0u));
    r.u[2] = (B == 2) ? W0 : ((B ==  1) ? W1 : ((B ==  0) ? W2 : 0u));
    r.u[3] = (B == 3) ? W0 : ((B ==  2) ? W1 : ((B ==  1) ? W2 : 0u));
    return r.f;
}

// ===========================================================================
// Mega kernel: three independent phases by block range (512 threads each).
//   [0, S3B)               : s3 edge partition with LDS local sort
//   [S3B, S3B+PREPB)       : fp16 W_T prep for both layers
//   [S3B+PREPB, +CONVB)    : x fp32->fp16 conv + pad rows + graph offsets
// ===========================================================================
__global__ __launch_bounds__(512) void mega(const int* __restrict__ ei,
                                            int* __restrict__ bcur,
                                            unsigned* __restrict__ tmp,
                                            const float* __restrict__ bw0,
                                            const float* __restrict__ sw0,
                                            const float* __restrict__ sc0,
                                            const float* __restrict__ bw1,
                                            const float* __restrict__ sw1,
                                            const float* __restrict__ sc1,
                                            unsigned short* __restrict__ wt0,
                                            unsigned short* __restrict__ wt1,
                                            const float* __restrict__ x,
                                            const int* __restrict__ bat,
                                            unsigned short* __restrict__ xb,
                                            unsigned short* __restrict__ hpad,
                                            int* __restrict__ goff) {
    __shared__ int hist[NB], lstart[NB], gbase[NB], cur[NB];   // 8 KB
    __shared__ unsigned ebuf[EPB];                             // 16 KB
    __shared__ unsigned short bk[EPB];                         //  8 KB
    const int bx = blockIdx.x;
    const int t  = threadIdx.x;

    if (bx < S3B) {
        // ---- s3: partition EPB edges into bucket slabs, LDS-local sort ----
        hist[t] = 0; cur[t] = 0;
        __syncthreads();
        const int e0 = bx * EPB;
        int src[8], dst[8];
#pragma unroll
        for (int k = 0; k < 8; ++k) {
            int e = e0 + t + k * 512;
            bool valid = e < EDGES;
            src[k] = valid ? ei[e] : 0;
            dst[k] = valid ? ei[EDGES + e] : -1;
            if (valid) atomicAdd(&hist[dst[k] >> 8], 1);
        }
        __syncthreads();
        // exclusive scan of hist -> lstart (chunk start within ebuf)
        int v = hist[t];
        lstart[t] = v;
        __syncthreads();
        int run = v;
        for (int d = 1; d < NB; d <<= 1) {
            int a = (t >= d) ? lstart[t - d] : 0;
            __syncthreads();
            run += a; lstart[t] = run;
            __syncthreads();
        }
        lstart[t] = run - v;          // own-element only; barrier below
        // global reservation
        if (v) gbase[t] = atomicAdd(&bcur[t], v);
        __syncthreads();
        // scatter regs -> LDS (bucket-contiguous)
#pragma unroll
        for (int k = 0; k < 8; ++k) {
            if (dst[k] >= 0) {
                int b = dst[k] >> 8;
                int pos = lstart[b] + atomicAdd(&cur[b], 1);
                ebuf[pos] = (unsigned)src[k] | ((unsigned)(dst[k] & 255) << 24);
                bk[pos] = (unsigned short)b;
            }
        }
        __syncthreads();
        // linear sweep: consecutive i -> consecutive slab addresses
        int total = EDGES - e0; if (total > EPB) total = EPB;
        for (int i = t; i < total; i += 512) {
            int b = bk[i];
            tmp[(size_t)b * CAP + gbase[b] + (i - lstart[b])] = ebuf[i];
        }
        return;
    }

    if (bx < S3B + PREPB) {
        // ---- weight prep ----
        int idx = (bx - S3B) * 512 + t;
        int layer = idx >= DIM * KTOT;
        int li = layer ? idx - DIM * KTOT : idx;
        const float* bw = layer ? bw1 : bw0;
        const float* sw = layer ? sw1 : sw0;
        const float* sc = layer ? sc1 : sc0;
        unsigned short* wt = layer ? wt1 : wt0;
        int o = li / KTOT, k = li % KTOT;
        float v;
        if (k < DIM) {
            v = bw[o * DIM + k];
        } else {
            int i = (k - DIM) >> 3, g = (k - DIM) & 7;
            v = sw[(o * DIM + i) * 8 + g] * sc[o * DIM + i];
        }
        wt[li] = __half_as_ushort(__float2half(v));
        return;
    }

    // ---- conv: x fp32 -> fp16, pad rows, graph offsets ----
    int i = (bx - S3B - PREPB) * 512 + t;
    if (i < NODES * 16) {
        float4 v = ((const float4*)x)[i];
        unsigned lo = packh2(v.x, v.y);
        unsigned hi = packh2(v.z, v.w);
        ((uint2*)xb)[i] = make_uint2(lo, hi);
        if ((i & 15) == 0) {
            int n = i >> 4;
            int b  = bat[n];
            int bp = (n == 0) ? -1 : bat[n - 1];
            for (int g = bp + 1; g <= b; ++g) goff[g] = n;
        }
        if (i == 0) {
            int blast = bat[NODES - 1];
            for (int g = blast + 1; g <= GRAPHS; ++g) goff[g] = NODES;
        }
    } else {
        int j = i - NODES * 16;
        if (j < 16)      ((uint2*)xb)[NODES * 16 + j] = make_uint2(0, 0);
        else if (j < 32) ((uint2*)hpad)[j - 16]       = make_uint2(0, 0);
    }
}

// ===========================================================================
// s4: per-bucket node-level counting sort -> rowp + padded col (sentinel
// NODES, segments x4).  1024 threads for latency depth (grid is only 391).
// Colbuf built in LDS, written out coalesced int4.
// ===========================================================================
__global__ __launch_bounds__(1024) void s4_fill(const unsigned* __restrict__ tmp,
                                                const int* __restrict__ bcur,
                                                int2* __restrict__ rowp,
                                                int* __restrict__ col) {
    __shared__ int deg[256], scanI[256], cur[256];
    __shared__ int tot;
    __shared__ int4 colbuf4[CAP / 4];          // 18.4 KB
    int* colbuf = (int*)colbuf4;
    const int b = blockIdx.x, t = threadIdx.x;
    const int cnt = bcur[b];
    const int base = b * CAP;
    if (t < 256) deg[t] = 0;
    __syncthreads();
    for (int i = t; i < cnt; i += 1024)
        atomicAdd(&deg[tmp[base + i] >> 24], 1);
    __syncthreads();
    if (t < 256) scanI[t] = (deg[t] + 3) & ~3;
    __syncthreads();
    for (int d = 1; d < 256; d <<= 1) {
        int a = 0;
        if (t < 256 && t >= d) a = scanI[t - d];
        __syncthreads();
        if (t < 256) scanI[t] += a;
        __syncthreads();
    }
    if (t < 256) {
        int pad = (deg[t] + 3) & ~3;
        int start = scanI[t] - pad;
        int ng = b * 256 + t;
        if (ng < NODES) rowp[ng] = make_int2(base + start, base + start + pad);
        cur[t] = start;
        if (t == 255) tot = scanI[255];
    }
    __syncthreads();
    for (int i = t; i < cnt; i += 1024) {
        unsigned p = tmp[base + i];
        int pos = atomicAdd(&cur[p >> 24], 1);
        colbuf[pos] = (int)(p & 0xFFFFFFu);
    }
    __syncthreads();
    if (t < 256) {
        int pad = (deg[t] + 3) & ~3;
        int end = scanI[t] - pad + pad;        // = scanI[t]
        for (int k = cur[t]; k < end; ++k) colbuf[k] = NODES;
    }
    __syncthreads();
    int nq = tot >> 2;
    int4* out4 = (int4*)(col + base);
    for (int i = t; i < nq; i += 1024) out4[i] = colbuf4[i];
}

// ===========================================================================
// Fused GIN layer (fp16 storage, fp32 gather accum): guard-free gather with
// int4 col loads, MFMA KAN all 64 outputs, W_T in 6 K-chunks with register
// prefetch.  LDS 22.5 KB -> 7 blocks/CU.
// ===========================================================================
__global__ __launch_bounds__(256) void fused_layer(const unsigned short* __restrict__ xin,
                                                   const int2* __restrict__ rowp,
                                                   const int* __restrict__ col,
                                                   const unsigned short* __restrict__ wt,
                                                   unsigned short* __restrict__ out) {
    __shared__ unsigned short wt_lds[64 * WTL_STRIDE];  // 13312 B
    __shared__ unsigned short v_lds[64 * V_STRIDE];     //  9216 B

    const int t     = threadIdx.x;
    const int nbase = blockIdx.x * 64;

    // ---- prefetch W chunk 0 into registers ----
    uint4 p0, p1, p2;
    {
        int c0 = t, c1 = t + 256, c2 = t + 512;
        p0 = *(const uint4*)(wt + (c0 / 12) * KTOT + (c0 % 12) * 8);
        p1 = *(const uint4*)(wt + (c1 / 12) * KTOT + (c1 % 12) * 8);
        p2 = *(const uint4*)(wt + (c2 / 12) * KTOT + (c2 % 12) * 8);
    }

    // ---- fused gather: v[node] = x[node] + sum_{src} x[src] ----
    const uint4* x4 = (const uint4*)xin;
#pragma unroll
    for (int rd = 0; rd < 2; ++rd) {
        int idx  = t + rd * 256;
        int node = idx >> 3, c8 = idx & 7;
        int n = nbase + node;
        uint4 res = make_uint4(0, 0, 0, 0);
        if (n < NODES) {
            int2 be = rowp[n];
            float a0[8], a1[8], a2[8], a3[8];
#pragma unroll
            for (int j = 0; j < 8; ++j) { a0[j] = 0.f; a1[j] = 0.f; a2[j] = 0.f; a3[j] = 0.f; }
            acc_h8(a0, x4[n * 8 + c8]);                        // self term
            for (int p = be.x; p < be.y; p += 4) {
                int4 c4 = *(const int4*)(col + p);
                uint4 r0 = x4[c4.x * 8 + c8];
                uint4 r1 = x4[c4.y * 8 + c8];
                uint4 r2 = x4[c4.z * 8 + c8];
                uint4 r3 = x4[c4.w * 8 + c8];
                acc_h8(a0, r0); acc_h8(a1, r1); acc_h8(a2, r2); acc_h8(a3, r3);
            }
            union { uint4 u; unsigned w[4]; } rr;
#pragma unroll
            for (int j = 0; j < 4; ++j) {
                float lo = a0[2 * j]     + a1[2 * j]     + a2[2 * j]     + a3[2 * j];
                float hi = a0[2 * j + 1] + a1[2 * j + 1] + a2[2 * j + 1] + a3[2 * j + 1];
                rr.w[j] = packh2(lo, hi);
            }
            res = rr.u;
        }
        *(uint4*)(v_lds + node * V_STRIDE + c8 * 8) = res;
    }
    // write chunk 0 to LDS
    {
        int c0 = t, c1 = t + 256, c2 = t + 512;
        *(uint4*)(wt_lds + (c0 / 12) * WTL_STRIDE + (c0 % 12) * 8) = p0;
        *(uint4*)(wt_lds + (c1 / 12) * WTL_STRIDE + (c1 % 12) * 8) = p1;
        *(uint4*)(wt_lds + (c2 / 12) * WTL_STRIDE + (c2 % 12) * 8) = p2;
    }
    __syncthreads();

    // ---- MFMA phase ----
    const int w = t >> 6;            // wave 0..3 -> nodes 16w..16w+15
    const int l = t & 63;
    const int q = l >> 4;            // k-quad
    const int c = l & 15;            // A row (node) / B row (output)
    const unsigned short* vrow = v_lds + ((w << 4) + c) * V_STRIDE;

    frag_cd ac0 = {0.f, 0.f, 0.f, 0.f};
    frag_cd ac1 = {0.f, 0.f, 0.f, 0.f};
    frag_cd ac2 = {0.f, 0.f, 0.f, 0.f};
    frag_cd ac3 = {0.f, 0.f, 0.f, 0.f};

#define MSTEP(OFF, A) {                                                          \
        f16x8 b0 = *(const f16x8*)(wt_lds + (c     ) * WTL_STRIDE + (OFF));      \
        f16x8 b1 = *(const f16x8*)(wt_lds + (c + 16) * WTL_STRIDE + (OFF));      \
        f16x8 b2 = *(const f16x8*)(wt_lds + (c + 32) * WTL_STRIDE + (OFF));      \
        f16x8 b3 = *(const f16x8*)(wt_lds + (c + 48) * WTL_STRIDE + (OFF));      \
        ac0 = __builtin_amdgcn_mfma_f32_16x16x32_f16(A, b0, ac0, 0, 0, 0);       \
        ac1 = __builtin_amdgcn_mfma_f32_16x16x32_f16(A, b1, ac1, 0, 0, 0);       \
        ac2 = __builtin_amdgcn_mfma_f32_16x16x32_f16(A, b2, ac2, 0, 0, 0);       \
        ac3 = __builtin_amdgcn_mfma_f32_16x16x32_f16(A, b3, ac3, 0, 0, 0); }

    // prefetch chunk 1 (in flight during chunk-0 compute)
    {
        int c0 = t, c1 = t + 256, c2 = t + 512;
        p0 = *(const uint4*)(wt + (c0 / 12) * KTOT + KSTAGE + (c0 % 12) * 8);
        p1 = *(const uint4*)(wt + (c1 / 12) * KTOT + KSTAGE + (c1 % 12) * 8);
        p2 = *(const uint4*)(wt + (c2 / 12) * KTOT + KSTAGE + (c2 % 12) * 8);
    }

    // chunk 0: silu steps s=0,1 + spline step s=2 (dim i = q)
#pragma unroll
    for (int s = 0; s < 2; ++s) {
        f16x8 hv = *(const f16x8*)(vrow + 32 * s + 8 * q);
        float f[8];
#pragma unroll
        for (int j = 0; j < 8; ++j) f[j] = silu((float)hv[j]);
        union { f16x8 v; unsigned u[4]; } a;
#pragma unroll
        for (int j = 0; j < 4; ++j) a.u[j] = packh2(f[2 * j], f[2 * j + 1]);
        MSTEP(32 * s + 8 * q, a.v);
    }
    {
        f16x8 a = bases_frag((float)(*(const _Float16*)(vrow + q)));
        MSTEP(64 + 8 * q, a);
    }

    // chunks 1..5: barrier, commit prefetched chunk, prefetch next, 3 steps
#pragma unroll
    for (int st = 1; st < 6; ++st) {
        __syncthreads();
        {
            int c0 = t, c1 = t + 256, c2 = t + 512;
            *(uint4*)(wt_lds + (c0 / 12) * WTL_STRIDE + (c0 % 12) * 8) = p0;
            *(uint4*)(wt_lds + (c1 / 12) * WTL_STRIDE + (c1 % 12) * 8) = p1;
            *(uint4*)(wt_lds + (c2 / 12) * WTL_STRIDE + (c2 % 12) * 8) = p2;
        }
        __syncthreads();
        if (st < 5) {
            int c0 = t, c1 = t + 256, c2 = t + 512;
            p0 = *(const uint4*)(wt + (c0 / 12) * KTOT + (st + 1) * KSTAGE + (c0 % 12) * 8);
            p1 = *(const uint4*)(wt + (c1 / 12) * KTOT + (st + 1) * KSTAGE + (c1 % 12) * 8);
            p2 = *(const uint4*)(wt + (c2 / 12) * KTOT + (st + 1) * KSTAGE + (c2 % 12) * 8);
        }
#pragma unroll
        for (int k = 0; k < 3; ++k) {
            int s = 3 * st + k;
            f16x8 a = bases_frag((float)(*(const _Float16*)(vrow + 4 * s + q - 8)));
            MSTEP(32 * k + 8 * q, a);
        }
    }
#undef MSTEP

    // ---- store fp16: C/D rows = nodes, cols = c + 16*acc ----
    const int n0 = nbase + (w << 4) + (q << 2);
#pragma unroll
    for (int r = 0; r < 4; ++r) {
        int n = n0 + r;
        if (n < NODES) {
            unsigned short* o = out + (size_t)n * DIM + c;
            o[0]  = __half_as_ushort(__float2half(ac0[r]));
            o[16] = __half_as_ushort(__float2half(ac1[r]));
            o[32] = __half_as_ushort(__float2half(ac2[r]));
            o[48] = __half_as_ushort(__float2half(ac3[r]));
        }
    }
}

// ---------------------------------------------------------------------------
// Fused pool + head: one block per graph (no atomics, no memset).
// ---------------------------------------------------------------------------
__global__ __launch_bounds__(256) void pool_head(const unsigned short* __restrict__ h,
                                                 const int* __restrict__ goff,
                                                 const float* __restrict__ bwh,
                                                 const float* __restrict__ swh,
                                                 const float* __restrict__ sch,
                                                 float* __restrict__ out) {
    __shared__ float ps[8][64];
    const int g = blockIdx.x, t = threadIdx.x;
    const int start = goff[g], end = goff[g + 1];
    const int d2 = t & 31, grp = t >> 5;
    float s0 = 0.f, s1 = 0.f;
    for (int n = start + grp; n < end; n += 8) {
        __half2 hv = *(const __half2*)(h + (size_t)n * DIM + 2 * d2);
        float2 f = __half22float2(hv);
        s0 += f.x;
        s1 += f.y;
    }
    ps[grp][2 * d2]     = s0;
    ps[grp][2 * d2 + 1] = s1;
    __syncthreads();

    if (t < 64) {
        const int i = t;
        float xv = 0.f;
#pragma unroll
        for (int k = 0; k < 8; ++k) xv += ps[k][i];

        float s  = silu(xv);
        float tt  = fmaf(xv, 2.5f, 5.5f);
        float fm  = floorf(tt);
        int   m   = (int)fm;
        float u   = tt - fm;
        float um1 = 1.f - u;
        float v3  = u * u * u * (1.f / 6.f);
        float v0  = um1 * um1 * um1 * (1.f / 6.f);
        float B2m1 = 0.5f * ((u + 1.f) * um1 + (2.f - u) * u);
        float v1  = ((u + 2.f) * um1 * um1 * 0.5f + (2.f - u) * B2m1) * (1.f / 3.f);
        float v2  = ((u + 1.f) * B2m1 + (3.f - u) * u * u * 0.5f) * (1.f / 3.f);
        bool inr  = (m >= 0) && (m <= 10);
        float b[8];
#pragma unroll
        for (int j = 0; j < 8; ++j) {
            float bv = 0.f;
            bv = (j == m - 3) ? v0 : bv;
            bv = (j == m - 2) ? v1 : bv;
            bv = (j == m - 1) ? v2 : bv;
            bv = (j == m)     ? v3 : bv;
            b[j] = inr ? bv : 0.f;
        }

        float part[NT];
#pragma unroll
        for (int o = 0; o < NT; ++o) {
            const float* sp = swh + (o * DIM + i) * 8;
            float sb = 0.f;
#pragma unroll
            for (int qq = 0; qq < 8; ++qq) sb = fmaf(b[qq], sp[qq], sb);
            part[o] = fmaf(s, bwh[o * DIM + i], sb * sch[o * DIM + i]);
        }
#pragma unroll
        for (int o = 0; o < NT; ++o) {
            float v = part[o];
#pragma unroll
            for (int off = 32; off > 0; off >>= 1) v += __shfl_down(v, off, 64);
            if (i == 0) out[g * NT + o] = v;
        }
    }
}

// ---------------------------------------------------------------------------
extern "C" void kernel_launch(void* const* d_in, const int* in_sizes, int n_in,
                              void* d_out, int out_size, void* d_ws, size_t ws_size,
                              hipStream_t stream) {
    const float* x   = (const float*)d_in[0];
    const int*   ei  = (const int*)d_in[1];
    const int*   bat = (const int*)d_in[2];
    const float* bw0 = (const float*)d_in[3];
    const float* sw0 = (const float*)d_in[4];
    const float* sc0 = (const float*)d_in[5];
    const float* bw1 = (const float*)d_in[6];
    const float* sw1 = (const float*)d_in[7];
    const float* sc1 = (const float*)d_in[8];
    const float* bwh = (const float*)d_in[9];
    const float* swh = (const float*)d_in[10];
    const float* sch = (const float*)d_in[11];
    float* out = (float*)d_out;

    const size_t ROW = (size_t)(NODES + 1) * DIM;   // +1 zero row for gather pad

    // ---- workspace layout (16B-aligned sections) ----
    unsigned short* wt0 = (unsigned short*)d_ws;                 // 36864 fp16
    unsigned short* wt1 = wt0 + DIM * KTOT;                      // 36864 fp16
    unsigned short* xbf = wt1 + DIM * KTOT;                      // ROW fp16
    unsigned short* hbf = xbf + ROW;                             // ROW fp16 (layer0 out)
    unsigned short* h2  = hbf + ROW;                             // NODES*DIM fp16
    int* goff     = (int*)(h2 + (size_t)NODES * DIM);            // 514 i (padded)
    int2* rowp    = (int2*)(goff + 514);                         // NODES int2
    int* col      = (int*)(rowp + NODES);                        // NB*CAP i
    int* bcur     = col + (size_t)NB * CAP;                      // NB i
    unsigned* tmp = (unsigned*)(bcur + NB);                      // NB*CAP u32

    (void)hipMemsetAsync(bcur, 0, NB * sizeof(int), stream);

    mega<<<S3B + PREPB + CONVB, 512, 0, stream>>>(
        ei, bcur, tmp,
        bw0, sw0, sc0, bw1, sw1, sc1, wt0, wt1,
        x, bat, xbf, hbf + (size_t)NODES * DIM, goff);

    s4_fill<<<NBUSED, 1024, 0, stream>>>(tmp, bcur, rowp, col);

    const int layer_blocks = (NODES + 63) / 64;        // 1563
    fused_layer<<<layer_blocks, 256, 0, stream>>>(xbf, rowp, col, wt0, hbf);
    fused_layer<<<layer_blocks, 256, 0, stream>>>(hbf, rowp, col, wt1, h2);

    pool_head<<<GRAPHS, 256, 0, stream>>>(h2, goff, bwh, swh, sch, out);
}